// Round 1
// baseline (686.529 us; speedup 1.0000x reference)
//
#include <hip/hip_runtime.h>
#include <math.h>

// Problem constants (match reference)
#define BB 4
#define LL 2048
#define HH 8
#define DD 64          // head dim
#define MM 256         // nb_features
#define DIMM 512
#define TT 64          // chunk length for linear-attention chunking
#define NCHUNK (LL/TT) // 32

constexpr float K_SCALE = 0.35355339059327379f; // 64^-0.25
constexpr float K_RATIO = 0.0625f;              // 256^-0.5
constexpr float K_EPS   = 1e-6f;

// ---------------------------------------------------------------------------
// Generic Y = X[MR,K] @ W[N,K]^T (+ bias) * postscale, with epilogue modes:
// MODE 0: out row-major [MR, ncols]
// MODE 1: v-scatter   out[((b*H+h)*L+l)*64+d],  r=b*L+l, c=h*64+d
// MODE 2: feat-scatter out[((b*H+h)*L+l)*256+m], r=(b*L+l)*H+h
// Tiles: BM=BN=128, BK=16, 256 threads, 8x8 micro-tile, transposed LDS so the
// inner loop is pure ds_read_b128.
// ---------------------------------------------------------------------------
template<int KDIM, int MODE>
__global__ __launch_bounds__(256)
void gemm_xwt(const float* __restrict__ X, const float* __restrict__ W,
              const float* __restrict__ bias, float* __restrict__ out,
              float postscale, int ncols)
{
    const int tid  = threadIdx.x;
    const int row0 = blockIdx.y * 128;
    const int col0 = blockIdx.x * 128;
    __shared__ float xT[16][132];
    __shared__ float wT[16][132];
    const int ty = tid >> 4, tx = tid & 15;
    float acc[8][8] = {};
    for (int k0 = 0; k0 < KDIM; k0 += 16) {
#pragma unroll
        for (int it = 0; it < 2; ++it) {
            int lin = (it*256 + tid) * 4;   // 0..2044
            int r = lin >> 4, kk = lin & 15;
            const float4 a = *reinterpret_cast<const float4*>(&X[(size_t)(row0 + r)*KDIM + k0 + kk]);
            xT[kk+0][r] = a.x; xT[kk+1][r] = a.y; xT[kk+2][r] = a.z; xT[kk+3][r] = a.w;
            const float4 b = *reinterpret_cast<const float4*>(&W[(size_t)(col0 + r)*KDIM + k0 + kk]);
            wT[kk+0][r] = b.x; wT[kk+1][r] = b.y; wT[kk+2][r] = b.z; wT[kk+3][r] = b.w;
        }
        __syncthreads();
#pragma unroll
        for (int kk = 0; kk < 16; ++kk) {
            float a[8], b[8];
            *(float4*)&a[0] = *(const float4*)&xT[kk][ty*8];
            *(float4*)&a[4] = *(const float4*)&xT[kk][ty*8+4];
            *(float4*)&b[0] = *(const float4*)&wT[kk][tx*8];
            *(float4*)&b[4] = *(const float4*)&wT[kk][tx*8+4];
#pragma unroll
            for (int i = 0; i < 8; ++i)
#pragma unroll
                for (int j = 0; j < 8; ++j)
                    acc[i][j] = fmaf(a[i], b[j], acc[i][j]);
        }
        __syncthreads();
    }
    const int r0 = row0 + ty*8;
    const int c0 = col0 + tx*8;
#pragma unroll
    for (int i = 0; i < 8; ++i) {
        const int r = r0 + i;
#pragma unroll
        for (int j = 0; j < 8; j += 4) {
            float vx[4];
#pragma unroll
            for (int q = 0; q < 4; ++q) {
                float val = acc[i][j+q];
                if (bias) val += bias[c0 + j + q];
                vx[q] = val * postscale;
            }
            float4 o; o.x = vx[0]; o.y = vx[1]; o.z = vx[2]; o.w = vx[3];
            if (MODE == 0) {
                *(float4*)(out + (size_t)r*ncols + c0 + j) = o;
            } else if (MODE == 1) {
                const int bidx = r / LL, l = r % LL;
                const int hh = (c0 + j) / DD, d = (c0 + j) % DD;
                *(float4*)(out + (((size_t)bidx*HH + hh)*LL + l)*DD + d) = o;
            } else {
                const int hh = r & 7; const int bl = r >> 3;
                const int bidx = bl / LL, l = bl % LL;
                *(float4*)(out + (((size_t)bidx*HH + hh)*LL + l)*MM + c0 + j) = o;
            }
        }
    }
}

// ---------------------------------------------------------------------------
// Feature post-process. One 64-lane wave per (b,l,h) row.
// fp holds dd (= data_scaled @ proj^T); data holds scaled projections
// (to recompute diag = 0.5*|x|^2). gmax==nullptr -> per-row max (query path),
// else global max scalar (key path). In-place:
// fp = RATIO*(exp(dd - diag - stab) + EPS)
// ---------------------------------------------------------------------------
__global__ __launch_bounds__(256)
void feat_post_kernel(float* __restrict__ fp, const float* __restrict__ data,
                      const float* __restrict__ gmax)
{
    const int wave = threadIdx.x >> 6, lane = threadIdx.x & 63;
    const int r = blockIdx.x*4 + wave;           // (b*L+l)*H + h
    const int h = r & 7; const int bl = r >> 3;  // bl = b*L + l
    float x = data[(size_t)bl*DIMM + h*DD + lane];
    float s = x * x;
#pragma unroll
    for (int off = 32; off > 0; off >>= 1) s += __shfl_xor(s, off);
    const float diag = 0.5f * s;
    const int bidx = bl / LL, l = bl % LL;
    const size_t rowbase = (((size_t)bidx*HH + h)*LL + l) * MM;
    float4 dd = *(const float4*)(fp + rowbase + lane*4);
    float stab;
    if (gmax) {
        stab = gmax[0];
    } else {
        float mx = fmaxf(fmaxf(dd.x, dd.y), fmaxf(dd.z, dd.w));
#pragma unroll
        for (int off = 32; off > 0; off >>= 1) mx = fmaxf(mx, __shfl_xor(mx, off));
        stab = mx;
    }
    const float cc = diag + stab;
    float4 o;
    o.x = K_RATIO * (__expf(dd.x - cc) + K_EPS);
    o.y = K_RATIO * (__expf(dd.y - cc) + K_EPS);
    o.z = K_RATIO * (__expf(dd.z - cc) + K_EPS);
    o.w = K_RATIO * (__expf(dd.w - cc) + K_EPS);
    *(float4*)(fp + rowbase + lane*4) = o;
}

// Global max over the key dd tensor (16,777,216 floats), two stages.
__global__ __launch_bounds__(256)
void kmax_part_kernel(const float* __restrict__ src, float* __restrict__ part)
{
    float mx = -3.0e38f;
    const float4* s4 = (const float4*)src;
    const int n4 = BB*HH*LL*MM/4;
    for (int i = blockIdx.x*256 + threadIdx.x; i < n4; i += 2048*256) {
        float4 v = s4[i];
        mx = fmaxf(mx, fmaxf(fmaxf(v.x, v.y), fmaxf(v.z, v.w)));
    }
#pragma unroll
    for (int off = 32; off > 0; off >>= 1) mx = fmaxf(mx, __shfl_xor(mx, off));
    __shared__ float wsm[4];
    if ((threadIdx.x & 63) == 0) wsm[threadIdx.x >> 6] = mx;
    __syncthreads();
    if (threadIdx.x == 0)
        part[blockIdx.x] = fmaxf(fmaxf(wsm[0], wsm[1]), fmaxf(wsm[2], wsm[3]));
}

__global__ __launch_bounds__(256)
void kmax_final_kernel(const float* __restrict__ part, float* __restrict__ gmax)
{
    float mx = -3.0e38f;
    for (int i = threadIdx.x; i < 2048; i += 256) mx = fmaxf(mx, part[i]);
#pragma unroll
    for (int off = 32; off > 0; off >>= 1) mx = fmaxf(mx, __shfl_xor(mx, off));
    __shared__ float wsm[4];
    if ((threadIdx.x & 63) == 0) wsm[threadIdx.x >> 6] = mx;
    __syncthreads();
    if (threadIdx.x == 0) gmax[0] = fmaxf(fmaxf(wsm[0], wsm[1]), fmaxf(wsm[2], wsm[3]));
}

// ---------------------------------------------------------------------------
// Per-chunk key/value outer-product state:
// Sc[b,h,c,m,d] = sum_{t in chunk} kp[t,m]*v[t,d];  skc[b,h,c,m] = sum kp[t,m]
// ---------------------------------------------------------------------------
__global__ __launch_bounds__(256)
void chunk_state_kernel(const float* __restrict__ kp, const float* __restrict__ vw,
                        float* __restrict__ Sc, float* __restrict__ skc)
{
    const int c = blockIdx.x, h = blockIdx.y, b = blockIdx.z;
    const size_t bh = (size_t)b*HH + h;
    const float* kpc = kp + (bh*LL + (size_t)c*TT) * MM;
    const float* vc  = vw + (bh*LL + (size_t)c*TT) * DD;
    __shared__ float kl[32][MM];
    __shared__ float vl[32][DD];
    const int tid = threadIdx.x;
    const int m0 = (tid >> 3) * 8, d0 = (tid & 7) * 8;
    float acc[8][8] = {};
    float sk[8] = {};
    for (int ts = 0; ts < TT; ts += 32) {
#pragma unroll
        for (int it = 0; it < 8; ++it) {
            int lin = it*256 + tid;          // 0..2047
            int t = lin >> 6, mq = lin & 63;
            *(float4*)&kl[t][mq*4] = *(const float4*)(kpc + (size_t)(ts+t)*MM + mq*4);
        }
#pragma unroll
        for (int it = 0; it < 2; ++it) {
            int lin = it*256 + tid;          // 0..511
            int t = lin >> 4, dq = lin & 15;
            *(float4*)&vl[t][dq*4] = *(const float4*)(vc + (size_t)(ts+t)*DD + dq*4);
        }
        __syncthreads();
        for (int t = 0; t < 32; ++t) {
            float kf[8], vf[8];
            *(float4*)&kf[0] = *(const float4*)&kl[t][m0];
            *(float4*)&kf[4] = *(const float4*)&kl[t][m0+4];
            *(float4*)&vf[0] = *(const float4*)&vl[t][d0];
            *(float4*)&vf[4] = *(const float4*)&vl[t][d0+4];
#pragma unroll
            for (int i = 0; i < 8; ++i) {
                sk[i] += kf[i];
#pragma unroll
                for (int j = 0; j < 8; ++j)
                    acc[i][j] = fmaf(kf[i], vf[j], acc[i][j]);
            }
        }
        __syncthreads();
    }
    float* So = Sc + (bh*NCHUNK + (size_t)c) * (MM*DD);
#pragma unroll
    for (int i = 0; i < 8; ++i)
#pragma unroll
        for (int j = 0; j < 8; j += 4) {
            float4 o; o.x = acc[i][j]; o.y = acc[i][j+1]; o.z = acc[i][j+2]; o.w = acc[i][j+3];
            *(float4*)(So + (size_t)(m0+i)*DD + d0 + j) = o;
        }
    if ((tid & 7) == 0) {
        float* ko = skc + (bh*NCHUNK + (size_t)c) * MM;
#pragma unroll
        for (int i = 0; i < 8; ++i) ko[m0+i] = sk[i];
    }
}

// Exclusive prefix over chunks (in-place). grid (64, 32): x=element slice, y=bh
__global__ __launch_bounds__(256)
void chunk_prefix_kernel(float* __restrict__ Sc, float* __restrict__ skc)
{
    const int bh = blockIdx.y;
    const int e = blockIdx.x*256 + threadIdx.x;   // 0..16383
    size_t base = (size_t)bh * NCHUNK * (MM*DD) + e;
    float s = 0.f;
#pragma unroll
    for (int c = 0; c < NCHUNK; ++c) {
        size_t idx = base + (size_t)c * (MM*DD);
        float t = Sc[idx];
        Sc[idx] = s;
        s += t;
    }
    if (blockIdx.x == 0) {
        size_t kb = (size_t)bh * NCHUNK * MM + threadIdx.x;  // 256 == MM
        float s2 = 0.f;
#pragma unroll
        for (int c = 0; c < NCHUNK; ++c) {
            size_t idx = kb + (size_t)c * MM;
            float t = skc[idx];
            skc[idx] = s2;
            s2 += t;
        }
    }
}

// ---------------------------------------------------------------------------
// Per-chunk output:
//   A[t,s] = qp_t . kp_s  (s<=t), O = A@V + Qp@S_prev,
//   den_t = rowsum(A) + qp_t . sk_prev,  attn = O/den
// One block per (b,h,chunk), 256 threads, T=64.
// ---------------------------------------------------------------------------
__global__ __launch_bounds__(256)
void chunk_out_kernel(const float* __restrict__ qp, const float* __restrict__ kp,
                      const float* __restrict__ vw, const float* __restrict__ Sp,
                      const float* __restrict__ skp, float* __restrict__ attn)
{
    const int c = blockIdx.x, h = blockIdx.y, b = blockIdx.z;
    const size_t bh = (size_t)b*HH + h;
    const float* qpc = qp + (bh*LL + (size_t)c*TT) * MM;
    const float* kpc = kp + (bh*LL + (size_t)c*TT) * MM;
    const float* vc  = vw + (bh*LL + (size_t)c*TT) * DD;
    const float* Spc = Sp + (bh*NCHUNK + (size_t)c) * (MM*DD);
    const float* skcp = skp + (bh*NCHUNK + (size_t)c) * MM;

    __shared__ float qT[32][68];     // [mm][t]
    __shared__ float kT[32][68];     // [mm][s]; reused as S_sub[mm][d] in phase 2b
    __shared__ float Al[TT][68];     // A[s][t] (masked)
    __shared__ float vl[TT][DD];     // [s][d]
    __shared__ float skl[32];
    __shared__ float denl[TT];

    const int tid = threadIdx.x;
    const int tg = tid >> 4;   // 0..15 -> t-group (phase1: t rows; phase2: t rows)
    const int lg = tid & 15;   // 0..15 -> s-group (phase1) / d-group (phase2)

    // ---- phase 1: A = Qp @ Kp^T over M=256 ----
    float accA[4][4] = {};
    for (int mb = 0; mb < MM; mb += 32) {
#pragma unroll
        for (int it = 0; it < 2; ++it) {
            int lin = (it*256 + tid) * 4;   // 0..2044
            int t = lin >> 5, mq = lin & 31;
            float4 a = *(const float4*)(qpc + (size_t)t*MM + mb + mq);
            qT[mq+0][t] = a.x; qT[mq+1][t] = a.y; qT[mq+2][t] = a.z; qT[mq+3][t] = a.w;
            float4 bb = *(const float4*)(kpc + (size_t)t*MM + mb + mq);
            kT[mq+0][t] = bb.x; kT[mq+1][t] = bb.y; kT[mq+2][t] = bb.z; kT[mq+3][t] = bb.w;
        }
        __syncthreads();
#pragma unroll
        for (int mm = 0; mm < 32; ++mm) {
            float a4[4], b4[4];
            *(float4*)a4 = *(const float4*)&qT[mm][tg*4];
            *(float4*)b4 = *(const float4*)&kT[mm][lg*4];
#pragma unroll
            for (int i = 0; i < 4; ++i)
#pragma unroll
                for (int j = 0; j < 4; ++j)
                    accA[i][j] = fmaf(a4[i], b4[j], accA[i][j]);
        }
        __syncthreads();
    }
    // write masked A (transposed: A[s][t]) and stage V
#pragma unroll
    for (int i = 0; i < 4; ++i) {
        const int t = tg*4 + i;
#pragma unroll
        for (int j = 0; j < 4; ++j) {
            const int s = lg*4 + j;
            Al[s][t] = (s <= t) ? accA[i][j] : 0.f;
        }
    }
#pragma unroll
    for (int it = 0; it < 4; ++it) {
        int lin = it*256 + tid;            // 0..1023
        int s = lin >> 4, dq = lin & 15;
        *(float4*)&vl[s][dq*4] = *(const float4*)(vc + (size_t)s*DD + dq*4);
    }
    __syncthreads();

    // den (intra part), owned by threads tid < 64 (one per t)
    float den = 0.f;
    if (tid < TT) {
#pragma unroll 8
        for (int s = 0; s < TT; ++s) den += Al[s][tid];
    }

    // ---- phase 2a: O = A @ V (intra-chunk causal part) ----
    float accO[4][4] = {};
    for (int s = 0; s < TT; ++s) {
        float a4[4], v4[4];
        *(float4*)a4 = *(const float4*)&Al[s][tg*4];
        *(float4*)v4 = *(const float4*)&vl[s][lg*4];
#pragma unroll
        for (int i = 0; i < 4; ++i)
#pragma unroll
            for (int j = 0; j < 4; ++j)
                accO[i][j] = fmaf(a4[i], v4[j], accO[i][j]);
    }

    // ---- phase 2b: O += Qp @ S_prev; den += Qp . sk_prev ----
    for (int mb = 0; mb < MM; mb += 32) {
        __syncthreads();   // protect qT/kT reuse against previous reads
#pragma unroll
        for (int it = 0; it < 2; ++it) {
            int lin = (it*256 + tid) * 4;
            int t = lin >> 5, mq = lin & 31;
            float4 a = *(const float4*)(qpc + (size_t)t*MM + mb + mq);
            qT[mq+0][t] = a.x; qT[mq+1][t] = a.y; qT[mq+2][t] = a.z; qT[mq+3][t] = a.w;
        }
#pragma unroll
        for (int it = 0; it < 2; ++it) {
            int lin = it*256 + tid;        // 0..511
            int mmr = lin >> 4, dq = lin & 15;
            *(float4*)&kT[mmr][dq*4] = *(const float4*)(Spc + (size_t)(mb+mmr)*DD + dq*4);
        }
        if (tid < 32) skl[tid] = skcp[mb + tid];
        __syncthreads();
#pragma unroll
        for (int mm = 0; mm < 32; ++mm) {
            float a4[4], s4[4];
            *(float4*)a4 = *(const float4*)&qT[mm][tg*4];
            *(float4*)s4 = *(const float4*)&kT[mm][lg*4];
#pragma unroll
            for (int i = 0; i < 4; ++i)
#pragma unroll
                for (int j = 0; j < 4; ++j)
                    accO[i][j] = fmaf(a4[i], s4[j], accO[i][j]);
        }
        if (tid < TT) {
#pragma unroll
            for (int mm = 0; mm < 32; ++mm)
                den = fmaf(qT[mm][tid], skl[mm], den);
        }
    }
    __syncthreads();
    if (tid < TT) denl[tid] = den;
    __syncthreads();

    // epilogue: attn[b, c*T + t, h*64 + d] = O/den
    float* arow = attn + ((size_t)b*LL + (size_t)c*TT) * DIMM + h*DD;
#pragma unroll
    for (int i = 0; i < 4; ++i) {
        const int t = tg*4 + i;
        const float inv = 1.0f / denl[t];
        float4 o;
        o.x = accO[i][0]*inv; o.y = accO[i][1]*inv;
        o.z = accO[i][2]*inv; o.w = accO[i][3]*inv;
        *(float4*)(arow + (size_t)t*DIMM + lg*4) = o;
    }
}

// ---------------------------------------------------------------------------
extern "C" void kernel_launch(void* const* d_in, const int* in_sizes, int n_in,
                              void* d_out, int out_size, void* d_ws, size_t ws_size,
                              hipStream_t stream)
{
    (void)in_sizes; (void)n_in; (void)out_size; (void)ws_size;
    const float* query = (const float*)d_in[0];
    const float* key   = (const float*)d_in[1];
    const float* value = (const float*)d_in[2];
    const float* Wq = (const float*)d_in[3];
    const float* bq = (const float*)d_in[4];
    const float* Wk = (const float*)d_in[5];
    const float* bk = (const float*)d_in[6];
    const float* Wv = (const float*)d_in[7];
    const float* bv = (const float*)d_in[8];
    const float* Wo = (const float*)d_in[9];
    const float* bo = (const float*)d_in[10];
    const float* proj = (const float*)d_in[11];

    float* ws = (float*)d_ws;
    float* qs   = ws;             // [8192,512] scaled q proj; reused as attn later
    float* ks   = ws +  4194304;  // [8192,512] scaled k proj
    float* vw   = ws +  8388608;  // [B,H,L,64]
    float* qp   = ws + 12582912;  // [B,H,L,256]  (dd_q -> qp)
    float* kp   = ws + 29360128;  // [B,H,L,256]  (dd_k -> kp)
    float* Sc   = ws + 46137344;  // [B,H,NC,256,64] chunk states -> excl. prefix
    float* skc  = ws + 62914560;  // [B,H,NC,256]
    float* part = ws + 63176704;  // [2048]
    float* gmax = ws + 63178752;  // [1]
    float* attn = qs;             // overlay (qs dead before chunk_out)

    const dim3 blk(256);

    // projections: q/k scaled by 64^-0.25 (bias folded, then scaled); v scattered
    gemm_xwt<512,0><<<dim3(4,64), blk, 0, stream>>>(query, Wq, bq, qs, K_SCALE, 512);
    gemm_xwt<512,0><<<dim3(4,64), blk, 0, stream>>>(key,   Wk, bk, ks, K_SCALE, 512);
    gemm_xwt<512,1><<<dim3(4,64), blk, 0, stream>>>(value, Wv, bv, vw, 1.0f,    512);

    // dd = data_scaled @ proj^T, scattered to [B,H,L,M]
    gemm_xwt<64,2><<<dim3(2,512), blk, 0, stream>>>(qs, proj, nullptr, qp, 1.0f, MM);
    gemm_xwt<64,2><<<dim3(2,512), blk, 0, stream>>>(ks, proj, nullptr, kp, 1.0f, MM);

    // global max over key dd
    kmax_part_kernel<<<2048, blk, 0, stream>>>(kp, part);
    kmax_final_kernel<<<1, blk, 0, stream>>>(part, gmax);

    // feature post-process (exp etc.)
    feat_post_kernel<<<16384, blk, 0, stream>>>(qp, qs, nullptr); // per-row max
    feat_post_kernel<<<16384, blk, 0, stream>>>(kp, ks, gmax);    // global max

    // chunked causal linear attention
    chunk_state_kernel<<<dim3(NCHUNK,HH,BB), blk, 0, stream>>>(kp, vw, Sc, skc);
    chunk_prefix_kernel<<<dim3(64,32), blk, 0, stream>>>(Sc, skc);
    chunk_out_kernel<<<dim3(NCHUNK,HH,BB), blk, 0, stream>>>(qp, kp, vw, Sc, skc, attn);

    // output projection
    gemm_xwt<512,0><<<dim3(4,64), blk, 0, stream>>>(attn, Wo, bo, (float*)d_out, 1.0f, 512);
}

// Round 2
// 411.937 us; speedup vs baseline: 1.6666x; 1.6666x over previous
//
#include <hip/hip_runtime.h>
#include <hip/hip_bf16.h>
#include <math.h>

// Problem constants
#define BB 4
#define LL 2048
#define HH 8
#define DD 64          // head dim
#define MM 256         // nb_features
#define DIMM 512
#define TT 64          // chunk length
#define NCHUNK (LL/TT) // 32

constexpr float K_SCALE = 0.35355339059327379f; // 64^-0.25
constexpr float K_RATIO = 0.0625f;              // 256^-0.5
constexpr float K_EPS   = 1e-6f;

using short8 = __attribute__((ext_vector_type(8))) short;
using f32x4  = __attribute__((ext_vector_type(4))) float;

__device__ inline unsigned short f2b_u16(float x) {
    __hip_bfloat16 h = __float2bfloat16(x);
    return *reinterpret_cast<unsigned short*>(&h);
}

// ---------------------------------------------------------------------------
// f32 -> bf16 vectorized cast (n4 = count of float4 groups)
// ---------------------------------------------------------------------------
__global__ __launch_bounds__(256)
void cvt_bf16_kernel(const float* __restrict__ src, __hip_bfloat16* __restrict__ dst, int n4)
{
    for (int i = blockIdx.x*256 + threadIdx.x; i < n4; i += gridDim.x*256) {
        float4 v = reinterpret_cast<const float4*>(src)[i];
        ushort4 o;
        o.x = f2b_u16(v.x); o.y = f2b_u16(v.y);
        o.z = f2b_u16(v.z); o.w = f2b_u16(v.w);
        reinterpret_cast<ushort4*>(dst)[i] = o;
    }
}

// ---------------------------------------------------------------------------
// bf16 MFMA GEMM: Y = X[MR,K] @ W[N,K]^T (+bias) * postscale, f32 out.
// Tile 128x128, BK=64, 256 threads = 4 waves (2x2), each wave 64x64.
// MODE 0: row-major [MR,512]
// MODE 1: v-scatter   out[((b*H+h)*L+l)*64+d],  r=b*L+l, c=h*64+d
// MODE 2: feat-scatter out[((b*H+h)*L+l)*256+c], r=(b*L+l)*H+h
// LDS rows padded to 72 bf16 (144B = 9*16B: aligned b128, 2-way aliasing only)
// ---------------------------------------------------------------------------
template<int KDIM, int MODE>
__global__ __launch_bounds__(256)
void gemm_bf16(const __hip_bfloat16* __restrict__ X, const __hip_bfloat16* __restrict__ W,
               const float* __restrict__ bias, float* __restrict__ out, float postscale)
{
    constexpr int LDT = 72;
    __shared__ __hip_bfloat16 As[128*LDT];
    __shared__ __hip_bfloat16 Bs[128*LDT];
    const int tid = threadIdx.x;
    const int lane = tid & 63;
    const int w = tid >> 6;
    const int wm = (w >> 1) * 64, wn = (w & 1) * 64;
    const int row0 = blockIdx.y * 128, col0 = blockIdx.x * 128;
    const int l15 = lane & 15, l4 = lane >> 4;

    f32x4 acc[4][4];
#pragma unroll
    for (int mt = 0; mt < 4; ++mt)
#pragma unroll
        for (int nt = 0; nt < 4; ++nt) {
            f32x4 z = {0.f, 0.f, 0.f, 0.f};
            acc[mt][nt] = z;
        }

    for (int k0 = 0; k0 < KDIM; k0 += 64) {
#pragma unroll
        for (int i = 0; i < 4; ++i) {
            int lin = i*256 + tid;      // 0..1023
            int r = lin >> 3, kc = lin & 7;
            *(uint4*)&As[r*LDT + kc*8] = *(const uint4*)(X + (size_t)(row0 + r)*KDIM + k0 + kc*8);
            *(uint4*)&Bs[r*LDT + kc*8] = *(const uint4*)(W + (size_t)(col0 + r)*KDIM + k0 + kc*8);
        }
        __syncthreads();
#pragma unroll
        for (int ks = 0; ks < 2; ++ks) {
            const int koff = ks*32 + l4*8;
            short8 aF[4], bF[4];
#pragma unroll
            for (int mt = 0; mt < 4; ++mt)
                aF[mt] = *(const short8*)&As[(wm + mt*16 + l15)*LDT + koff];
#pragma unroll
            for (int nt = 0; nt < 4; ++nt)
                bF[nt] = *(const short8*)&Bs[(wn + nt*16 + l15)*LDT + koff];
#pragma unroll
            for (int mt = 0; mt < 4; ++mt)
#pragma unroll
                for (int nt = 0; nt < 4; ++nt)
                    acc[mt][nt] = __builtin_amdgcn_mfma_f32_16x16x32_bf16(aF[mt], bF[nt], acc[mt][nt], 0, 0, 0);
        }
        __syncthreads();
    }

#pragma unroll
    for (int mt = 0; mt < 4; ++mt) {
#pragma unroll
        for (int nt = 0; nt < 4; ++nt) {
            const int c = col0 + wn + nt*16 + l15;
            const float bval = (MODE == 2) ? 0.f : bias[c];
#pragma unroll
            for (int j = 0; j < 4; ++j) {
                const int r = row0 + wm + mt*16 + l4*4 + j;
                const float val = (acc[mt][nt][j] + bval) * postscale;
                if (MODE == 0) {
                    out[(size_t)r*DIMM + c] = val;
                } else if (MODE == 1) {
                    const int b = r >> 11, l = r & 2047;
                    const int hh = c >> 6, d = c & 63;
                    out[(((size_t)b*HH + hh)*LL + l)*DD + d] = val;
                } else {
                    const int bl = r >> 3, hh = r & 7;
                    const int b = bl >> 11, l = bl & 2047;
                    out[(((size_t)b*HH + hh)*LL + l)*MM + c] = val;
                }
            }
        }
    }
}

// ---------------------------------------------------------------------------
// Feature post-process: fp = RATIO*(exp(dd - diag - stab) + EPS), in place.
// One 64-lane wave per (b,l,h) row. gmax==nullptr -> per-row max (query).
// ---------------------------------------------------------------------------
__global__ __launch_bounds__(256)
void feat_post_kernel(float* __restrict__ fp, const float* __restrict__ data,
                      const float* __restrict__ gmax)
{
    const int wave = threadIdx.x >> 6, lane = threadIdx.x & 63;
    const int r = blockIdx.x*4 + wave;           // (b*L+l)*H + h
    const int h = r & 7; const int bl = r >> 3;
    float x = data[(size_t)bl*DIMM + h*DD + lane];
    float s = x * x;
#pragma unroll
    for (int off = 32; off > 0; off >>= 1) s += __shfl_xor(s, off);
    const float diag = 0.5f * s;
    const int bidx = bl / LL, l = bl % LL;
    const size_t rowbase = (((size_t)bidx*HH + h)*LL + l) * MM;
    float4 dd = *(const float4*)(fp + rowbase + lane*4);
    float stab;
    if (gmax) {
        stab = gmax[0];
    } else {
        float mx = fmaxf(fmaxf(dd.x, dd.y), fmaxf(dd.z, dd.w));
#pragma unroll
        for (int off = 32; off > 0; off >>= 1) mx = fmaxf(mx, __shfl_xor(mx, off));
        stab = mx;
    }
    const float cc = diag + stab;
    float4 o;
    o.x = K_RATIO * (__expf(dd.x - cc) + K_EPS);
    o.y = K_RATIO * (__expf(dd.y - cc) + K_EPS);
    o.z = K_RATIO * (__expf(dd.z - cc) + K_EPS);
    o.w = K_RATIO * (__expf(dd.w - cc) + K_EPS);
    *(float4*)(fp + rowbase + lane*4) = o;
}

__global__ __launch_bounds__(256)
void kmax_part_kernel(const float* __restrict__ src, float* __restrict__ part)
{
    float mx = -3.0e38f;
    const float4* s4 = (const float4*)src;
    const int n4 = BB*HH*LL*MM/4;
    for (int i = blockIdx.x*256 + threadIdx.x; i < n4; i += 2048*256) {
        float4 v = s4[i];
        mx = fmaxf(mx, fmaxf(fmaxf(v.x, v.y), fmaxf(v.z, v.w)));
    }
#pragma unroll
    for (int off = 32; off > 0; off >>= 1) mx = fmaxf(mx, __shfl_xor(mx, off));
    __shared__ float wsm[4];
    if ((threadIdx.x & 63) == 0) wsm[threadIdx.x >> 6] = mx;
    __syncthreads();
    if (threadIdx.x == 0)
        part[blockIdx.x] = fmaxf(fmaxf(wsm[0], wsm[1]), fmaxf(wsm[2], wsm[3]));
}

__global__ __launch_bounds__(256)
void kmax_final_kernel(const float* __restrict__ part, float* __restrict__ gmax)
{
    float mx = -3.0e38f;
    for (int i = threadIdx.x; i < 2048; i += 256) mx = fmaxf(mx, part[i]);
#pragma unroll
    for (int off = 32; off > 0; off >>= 1) mx = fmaxf(mx, __shfl_xor(mx, off));
    __shared__ float wsm[4];
    if ((threadIdx.x & 63) == 0) wsm[threadIdx.x >> 6] = mx;
    __syncthreads();
    if (threadIdx.x == 0) gmax[0] = fmaxf(fmaxf(wsm[0], wsm[1]), fmaxf(wsm[2], wsm[3]));
}

// ---------------------------------------------------------------------------
// Per-chunk key/value outer-product state.
// ---------------------------------------------------------------------------
__global__ __launch_bounds__(256)
void chunk_state_kernel(const float* __restrict__ kp, const float* __restrict__ vw,
                        float* __restrict__ Sc, float* __restrict__ skc)
{
    const int c = blockIdx.x, h = blockIdx.y, b = blockIdx.z;
    const size_t bh = (size_t)b*HH + h;
    const float* kpc = kp + (bh*LL + (size_t)c*TT) * MM;
    const float* vc  = vw + (bh*LL + (size_t)c*TT) * DD;
    __shared__ float kl[32][MM];
    __shared__ float vl[32][DD];
    const int tid = threadIdx.x;
    const int m0 = (tid >> 3) * 8, d0 = (tid & 7) * 8;
    float acc[8][8] = {};
    float sk[8] = {};
    for (int ts = 0; ts < TT; ts += 32) {
#pragma unroll
        for (int it = 0; it < 8; ++it) {
            int lin = it*256 + tid;
            int t = lin >> 6, mq = lin & 63;
            *(float4*)&kl[t][mq*4] = *(const float4*)(kpc + (size_t)(ts+t)*MM + mq*4);
        }
#pragma unroll
        for (int it = 0; it < 2; ++it) {
            int lin = it*256 + tid;
            int t = lin >> 4, dq = lin & 15;
            *(float4*)&vl[t][dq*4] = *(const float4*)(vc + (size_t)(ts+t)*DD + dq*4);
        }
        __syncthreads();
        for (int t = 0; t < 32; ++t) {
            float kf[8], vf[8];
            *(float4*)&kf[0] = *(const float4*)&kl[t][m0];
            *(float4*)&kf[4] = *(const float4*)&kl[t][m0+4];
            *(float4*)&vf[0] = *(const float4*)&vl[t][d0];
            *(float4*)&vf[4] = *(const float4*)&vl[t][d0+4];
#pragma unroll
            for (int i = 0; i < 8; ++i) {
                sk[i] += kf[i];
#pragma unroll
                for (int j = 0; j < 8; ++j)
                    acc[i][j] = fmaf(kf[i], vf[j], acc[i][j]);
            }
        }
        __syncthreads();
    }
    float* So = Sc + (bh*NCHUNK + (size_t)c) * (MM*DD);
#pragma unroll
    for (int i = 0; i < 8; ++i)
#pragma unroll
        for (int j = 0; j < 8; j += 4) {
            float4 o; o.x = acc[i][j]; o.y = acc[i][j+1]; o.z = acc[i][j+2]; o.w = acc[i][j+3];
            *(float4*)(So + (size_t)(m0+i)*DD + d0 + j) = o;
        }
    if ((tid & 7) == 0) {
        float* ko = skc + (bh*NCHUNK + (size_t)c) * MM;
#pragma unroll
        for (int i = 0; i < 8; ++i) ko[m0+i] = sk[i];
    }
}

// Exclusive prefix over chunks (in-place).
__global__ __launch_bounds__(256)
void chunk_prefix_kernel(float* __restrict__ Sc, float* __restrict__ skc)
{
    const int bh = blockIdx.y;
    const int e = blockIdx.x*256 + threadIdx.x;
    size_t base = (size_t)bh * NCHUNK * (MM*DD) + e;
    float s = 0.f;
#pragma unroll
    for (int c = 0; c < NCHUNK; ++c) {
        size_t idx = base + (size_t)c * (MM*DD);
        float t = Sc[idx];
        Sc[idx] = s;
        s += t;
    }
    if (blockIdx.x == 0) {
        size_t kb = (size_t)bh * NCHUNK * MM + threadIdx.x;
        float s2 = 0.f;
#pragma unroll
        for (int c = 0; c < NCHUNK; ++c) {
            size_t idx = kb + (size_t)c * MM;
            float t = skc[idx];
            skc[idx] = s2;
            s2 += t;
        }
    }
}

// ---------------------------------------------------------------------------
// Per-chunk output; writes attn in bf16 layout [B,L,512].
// ---------------------------------------------------------------------------
__global__ __launch_bounds__(256)
void chunk_out_kernel(const float* __restrict__ qp, const float* __restrict__ kp,
                      const float* __restrict__ vw, const float* __restrict__ Sp,
                      const float* __restrict__ skp, __hip_bfloat16* __restrict__ attn)
{
    const int c = blockIdx.x, h = blockIdx.y, b = blockIdx.z;
    const size_t bh = (size_t)b*HH + h;
    const float* qpc = qp + (bh*LL + (size_t)c*TT) * MM;
    const float* kpc = kp + (bh*LL + (size_t)c*TT) * MM;
    const float* vc  = vw + (bh*LL + (size_t)c*TT) * DD;
    const float* Spc = Sp + (bh*NCHUNK + (size_t)c) * (MM*DD);
    const float* skcp = skp + (bh*NCHUNK + (size_t)c) * MM;

    __shared__ float qT[32][68];
    __shared__ float kT[32][68];
    __shared__ float Al[TT][68];
    __shared__ float vl[TT][DD];
    __shared__ float skl[32];
    __shared__ float denl[TT];

    const int tid = threadIdx.x;
    const int tg = tid >> 4;
    const int lg = tid & 15;

    // phase 1: A = Qp @ Kp^T
    float accA[4][4] = {};
    for (int mb = 0; mb < MM; mb += 32) {
#pragma unroll
        for (int it = 0; it < 2; ++it) {
            int lin = (it*256 + tid) * 4;
            int t = lin >> 5, mq = lin & 31;
            float4 a = *(const float4*)(qpc + (size_t)t*MM + mb + mq);
            qT[mq+0][t] = a.x; qT[mq+1][t] = a.y; qT[mq+2][t] = a.z; qT[mq+3][t] = a.w;
            float4 bb = *(const float4*)(kpc + (size_t)t*MM + mb + mq);
            kT[mq+0][t] = bb.x; kT[mq+1][t] = bb.y; kT[mq+2][t] = bb.z; kT[mq+3][t] = bb.w;
        }
        __syncthreads();
#pragma unroll
        for (int mm = 0; mm < 32; ++mm) {
            float a4[4], b4[4];
            *(float4*)a4 = *(const float4*)&qT[mm][tg*4];
            *(float4*)b4 = *(const float4*)&kT[mm][lg*4];
#pragma unroll
            for (int i = 0; i < 4; ++i)
#pragma unroll
                for (int j = 0; j < 4; ++j)
                    accA[i][j] = fmaf(a4[i], b4[j], accA[i][j]);
        }
        __syncthreads();
    }
#pragma unroll
    for (int i = 0; i < 4; ++i) {
        const int t = tg*4 + i;
#pragma unroll
        for (int j = 0; j < 4; ++j) {
            const int s = lg*4 + j;
            Al[s][t] = (s <= t) ? accA[i][j] : 0.f;
        }
    }
#pragma unroll
    for (int it = 0; it < 4; ++it) {
        int lin = it*256 + tid;
        int s = lin >> 4, dq = lin & 15;
        *(float4*)&vl[s][dq*4] = *(const float4*)(vc + (size_t)s*DD + dq*4);
    }
    __syncthreads();

    float den = 0.f;
    if (tid < TT) {
#pragma unroll 8
        for (int s = 0; s < TT; ++s) den += Al[s][tid];
    }

    // phase 2a: O = A @ V
    float accO[4][4] = {};
    for (int s = 0; s < TT; ++s) {
        float a4[4], v4[4];
        *(float4*)a4 = *(const float4*)&Al[s][tg*4];
        *(float4*)v4 = *(const float4*)&vl[s][lg*4];
#pragma unroll
        for (int i = 0; i < 4; ++i)
#pragma unroll
            for (int j = 0; j < 4; ++j)
                accO[i][j] = fmaf(a4[i], v4[j], accO[i][j]);
    }

    // phase 2b: O += Qp @ S_prev; den += Qp . sk_prev
    for (int mb = 0; mb < MM; mb += 32) {
        __syncthreads();
#pragma unroll
        for (int it = 0; it < 2; ++it) {
            int lin = (it*256 + tid) * 4;
            int t = lin >> 5, mq = lin & 31;
            float4 a = *(const float4*)(qpc + (size_t)t*MM + mb + mq);
            qT[mq+0][t] = a.x; qT[mq+1][t] = a.y; qT[mq+2][t] = a.z; qT[mq+3][t] = a.w;
        }
#pragma unroll
        for (int it = 0; it < 2; ++it) {
            int lin = it*256 + tid;
            int mmr = lin >> 4, dq = lin & 15;
            *(float4*)&kT[mmr][dq*4] = *(const float4*)(Spc + (size_t)(mb+mmr)*DD + dq*4);
        }
        if (tid < 32) skl[tid] = skcp[mb + tid];
        __syncthreads();
#pragma unroll
        for (int mm = 0; mm < 32; ++mm) {
            float a4[4], s4[4];
            *(float4*)a4 = *(const float4*)&qT[mm][tg*4];
            *(float4*)s4 = *(const float4*)&kT[mm][lg*4];
#pragma unroll
            for (int i = 0; i < 4; ++i)
#pragma unroll
                for (int j = 0; j < 4; ++j)
                    accO[i][j] = fmaf(a4[i], s4[j], accO[i][j]);
        }
        if (tid < TT) {
#pragma unroll
            for (int mm = 0; mm < 32; ++mm)
                den = fmaf(qT[mm][tid], skl[mm], den);
        }
    }
    __syncthreads();
    if (tid < TT) denl[tid] = den;
    __syncthreads();

    __hip_bfloat16* arow = attn + ((size_t)b*LL + (size_t)c*TT) * DIMM + h*DD;
#pragma unroll
    for (int i = 0; i < 4; ++i) {
        const int t = tg*4 + i;
        const float inv = 1.0f / denl[t];
        ushort4 o;
        o.x = f2b_u16(accO[i][0]*inv);
        o.y = f2b_u16(accO[i][1]*inv);
        o.z = f2b_u16(accO[i][2]*inv);
        o.w = f2b_u16(accO[i][3]*inv);
        *(ushort4*)(arow + (size_t)t*DIMM + lg*4) = o;
    }
}

// ---------------------------------------------------------------------------
extern "C" void kernel_launch(void* const* d_in, const int* in_sizes, int n_in,
                              void* d_out, int out_size, void* d_ws, size_t ws_size,
                              hipStream_t stream)
{
    (void)in_sizes; (void)n_in; (void)out_size; (void)ws_size;
    const float* query = (const float*)d_in[0];
    const float* key   = (const float*)d_in[1];
    const float* value = (const float*)d_in[2];
    const float* Wq = (const float*)d_in[3];
    const float* bq = (const float*)d_in[4];
    const float* Wk = (const float*)d_in[5];
    const float* bk = (const float*)d_in[6];
    const float* Wv = (const float*)d_in[7];
    const float* bv = (const float*)d_in[8];
    const float* Wo = (const float*)d_in[9];
    const float* bo = (const float*)d_in[10];
    const float* proj = (const float*)d_in[11];

    float* ws = (float*)d_ws;
    // f32 region R1 (reused later: Sc overlays [0,16777216), attn_b overlays ksb)
    float* qs = ws;                                               // 4,194,304 f32
    float* ks = ws + 4194304;                                     // 4,194,304 f32
    __hip_bfloat16* qb   = (__hip_bfloat16*)(ws + 8388608);       // 4,194,304 bf16
    __hip_bfloat16* kb   = (__hip_bfloat16*)(ws + 10485760);
    __hip_bfloat16* vb   = (__hip_bfloat16*)(ws + 12582912);
    __hip_bfloat16* qsb  = (__hip_bfloat16*)(ws + 14680064);
    __hip_bfloat16* ksb  = (__hip_bfloat16*)(ws + 16777216);
    float* Sc            = ws;                                    // overlay (16,777,216 f32)
    __hip_bfloat16* attn_b = (__hip_bfloat16*)(ws + 16777216);    // overlay ksb
    float* qp  = ws + 18874368;                                   // 16,777,216 f32
    float* kp  = ws + 35651584;                                   // 16,777,216 f32
    float* vw  = ws + 52428800;                                   // 4,194,304 f32
    float* skc = ws + 56623104;                                   // 262,144 f32
    float* part = ws + 56885248;                                  // 2048
    float* gmax = ws + 56887296;                                  // 1
    __hip_bfloat16* Wqb   = (__hip_bfloat16*)(ws + 56887300);
    __hip_bfloat16* Wkb   = (__hip_bfloat16*)(ws + 57018372);
    __hip_bfloat16* Wvb   = (__hip_bfloat16*)(ws + 57149444);
    __hip_bfloat16* Wob   = (__hip_bfloat16*)(ws + 57280516);
    __hip_bfloat16* projb = (__hip_bfloat16*)(ws + 57411588);

    const dim3 blk(256);

    // casts
    cvt_bf16_kernel<<<2048, blk, 0, stream>>>(query, qb, 1048576);
    cvt_bf16_kernel<<<2048, blk, 0, stream>>>(key,   kb, 1048576);
    cvt_bf16_kernel<<<2048, blk, 0, stream>>>(value, vb, 1048576);
    cvt_bf16_kernel<<<256,  blk, 0, stream>>>(Wq, Wqb, 65536);
    cvt_bf16_kernel<<<256,  blk, 0, stream>>>(Wk, Wkb, 65536);
    cvt_bf16_kernel<<<256,  blk, 0, stream>>>(Wv, Wvb, 65536);
    cvt_bf16_kernel<<<256,  blk, 0, stream>>>(Wo, Wob, 65536);
    cvt_bf16_kernel<<<16,   blk, 0, stream>>>(proj, projb, 4096);

    // projections (MFMA): q/k scaled by 64^-0.25; v scattered to [B,H,L,64]
    gemm_bf16<512,0><<<dim3(4,64), blk, 0, stream>>>(qb, Wqb, bq, qs, K_SCALE);
    gemm_bf16<512,0><<<dim3(4,64), blk, 0, stream>>>(kb, Wkb, bk, ks, K_SCALE);
    gemm_bf16<512,1><<<dim3(4,64), blk, 0, stream>>>(vb, Wvb, bv, vw, 1.0f);

    // bf16 copies of scaled projections for the feature GEMMs
    cvt_bf16_kernel<<<2048, blk, 0, stream>>>(qs, qsb, 1048576);
    cvt_bf16_kernel<<<2048, blk, 0, stream>>>(ks, ksb, 1048576);

    // dd = data_scaled @ proj^T -> [B,H,L,M]   (X viewed as [65536,64])
    gemm_bf16<64,2><<<dim3(2,512), blk, 0, stream>>>(qsb, projb, nullptr, qp, 1.0f);
    gemm_bf16<64,2><<<dim3(2,512), blk, 0, stream>>>(ksb, projb, nullptr, kp, 1.0f);

    // global max over key dd
    kmax_part_kernel<<<2048, blk, 0, stream>>>(kp, part);
    kmax_final_kernel<<<1, blk, 0, stream>>>(part, gmax);

    // feature post-process
    feat_post_kernel<<<16384, blk, 0, stream>>>(qp, qs, nullptr);
    feat_post_kernel<<<16384, blk, 0, stream>>>(kp, ks, gmax);

    // chunked causal linear attention (f32 pipeline)
    chunk_state_kernel<<<dim3(NCHUNK,HH,BB), blk, 0, stream>>>(kp, vw, Sc, skc);
    chunk_prefix_kernel<<<dim3(64,32), blk, 0, stream>>>(Sc, skc);
    chunk_out_kernel<<<dim3(NCHUNK,HH,BB), blk, 0, stream>>>(qp, kp, vw, Sc, skc, attn_b);

    // output projection (MFMA)
    gemm_bf16<512,0><<<dim3(4,64), blk, 0, stream>>>(attn_b, Wob, bo, (float*)d_out, 1.0f);
}

// Round 4
// 252.208 us; speedup vs baseline: 2.7221x; 1.6333x over previous
//
#include <hip/hip_runtime.h>
#include <hip/hip_bf16.h>
#include <math.h>

// Problem constants
#define BB 4
#define LL 2048
#define HH 8
#define DD 64          // head dim
#define MM 256         // nb_features
#define DIMM 512
#define TT 64          // chunk length
#define NCHUNK (LL/TT) // 32

constexpr float K_SCALE = 0.35355339059327379f; // 64^-0.25
constexpr float K_RATIO = 0.0625f;              // 256^-0.5
constexpr float K_EPS   = 1e-6f;

using short8 = __attribute__((ext_vector_type(8))) short;
using f32x4  = __attribute__((ext_vector_type(4))) float;

__device__ inline unsigned short f2b_u16(float x) {
    __hip_bfloat16 h = __float2bfloat16(x);
    return *reinterpret_cast<unsigned short*>(&h);
}

template<typename T> __device__ inline T f2o(float v);
template<> __device__ inline float f2o<float>(float v) { return v; }
template<> __device__ inline __hip_bfloat16 f2o<__hip_bfloat16>(float v) { return __float2bfloat16(v); }

// ---------------------------------------------------------------------------
// f32 -> bf16 vectorized cast
// ---------------------------------------------------------------------------
__global__ __launch_bounds__(256)
void cvt_bf16_kernel(const float* __restrict__ src, __hip_bfloat16* __restrict__ dst, int n4)
{
    for (int i = blockIdx.x*256 + threadIdx.x; i < n4; i += gridDim.x*256) {
        float4 v = reinterpret_cast<const float4*>(src)[i];
        ushort4 o;
        o.x = f2b_u16(v.x); o.y = f2b_u16(v.y);
        o.z = f2b_u16(v.z); o.w = f2b_u16(v.w);
        reinterpret_cast<ushort4*>(dst)[i] = o;
    }
}

// ---------------------------------------------------------------------------
// bf16 MFMA GEMM: Y = X[MR,K] @ W[N,K]^T (+bias) * postscale, OT out.
// Tile 128x128, BK=64, 4 waves (2x2), each wave 64x64. (verified round 2)
// MODE 0: row-major [MR,512]
// MODE 1: v-scatter   out[((b*H+h)*L+l)*64+d]
// MODE 2: feat-scatter out[((b*H+h)*L+l)*256+c]
// ---------------------------------------------------------------------------
template<int KDIM, int MODE, typename OT>
__global__ __launch_bounds__(256)
void gemm_bf16(const __hip_bfloat16* __restrict__ X, const __hip_bfloat16* __restrict__ W,
               const float* __restrict__ bias, OT* __restrict__ out, float postscale)
{
    constexpr int LDT = 72;
    __shared__ __hip_bfloat16 As[128*LDT];
    __shared__ __hip_bfloat16 Bs[128*LDT];
    const int tid = threadIdx.x;
    const int lane = tid & 63;
    const int w = tid >> 6;
    const int wm = (w >> 1) * 64, wn = (w & 1) * 64;
    const int row0 = blockIdx.y * 128, col0 = blockIdx.x * 128;
    const int l15 = lane & 15, l4 = lane >> 4;

    f32x4 acc[4][4];
#pragma unroll
    for (int mt = 0; mt < 4; ++mt)
#pragma unroll
        for (int nt = 0; nt < 4; ++nt) {
            f32x4 z = {0.f, 0.f, 0.f, 0.f};
            acc[mt][nt] = z;
        }

    for (int k0 = 0; k0 < KDIM; k0 += 64) {
#pragma unroll
        for (int i = 0; i < 4; ++i) {
            int lin = i*256 + tid;
            int r = lin >> 3, kc = lin & 7;
            *(uint4*)&As[r*LDT + kc*8] = *(const uint4*)(X + (size_t)(row0 + r)*KDIM + k0 + kc*8);
            *(uint4*)&Bs[r*LDT + kc*8] = *(const uint4*)(W + (size_t)(col0 + r)*KDIM + k0 + kc*8);
        }
        __syncthreads();
#pragma unroll
        for (int ks = 0; ks < 2; ++ks) {
            const int koff = ks*32 + l4*8;
            short8 aF[4], bF[4];
#pragma unroll
            for (int mt = 0; mt < 4; ++mt)
                aF[mt] = *(const short8*)&As[(wm + mt*16 + l15)*LDT + koff];
#pragma unroll
            for (int nt = 0; nt < 4; ++nt)
                bF[nt] = *(const short8*)&Bs[(wn + nt*16 + l15)*LDT + koff];
#pragma unroll
            for (int mt = 0; mt < 4; ++mt)
#pragma unroll
                for (int nt = 0; nt < 4; ++nt)
                    acc[mt][nt] = __builtin_amdgcn_mfma_f32_16x16x32_bf16(aF[mt], bF[nt], acc[mt][nt], 0, 0, 0);
        }
        __syncthreads();
    }

#pragma unroll
    for (int mt = 0; mt < 4; ++mt) {
#pragma unroll
        for (int nt = 0; nt < 4; ++nt) {
            const int c = col0 + wn + nt*16 + l15;
            const float bval = (MODE == 2) ? 0.f : bias[c];
#pragma unroll
            for (int j = 0; j < 4; ++j) {
                const int r = row0 + wm + mt*16 + l4*4 + j;
                const float val = (acc[mt][nt][j] + bval) * postscale;
                if (MODE == 0) {
                    out[(size_t)r*DIMM + c] = f2o<OT>(val);
                } else if (MODE == 1) {
                    const int b = r >> 11, l = r & 2047;
                    const int hh = c >> 6, d = c & 63;
                    out[(((size_t)b*HH + hh)*LL + l)*DD + d] = f2o<OT>(val);
                } else {
                    const int bl = r >> 3, hh = r & 7;
                    const int b = bl >> 11, l = bl & 2047;
                    out[(((size_t)b*HH + hh)*LL + l)*MM + c] = f2o<OT>(val);
                }
            }
        }
    }
}

// ---------------------------------------------------------------------------
// vw [B,H,L,D] f32  ->  vT [B,H,D,L] bf16  (tiled LDS transpose)
// ---------------------------------------------------------------------------
__global__ __launch_bounds__(256)
void transpose_v_kernel(const float* __restrict__ vw, __hip_bfloat16* __restrict__ vT)
{
    __shared__ float vl[64][65];
    const int bh = blockIdx.y;
    const int l0 = blockIdx.x*64;
    const float* src = vw + ((size_t)bh*LL + l0)*DD;
#pragma unroll
    for (int it = 0; it < 4; ++it) {
        int lin = it*256 + threadIdx.x;
        int t = lin >> 4, d4 = (lin & 15)*4;
        float4 v = *(const float4*)(src + (size_t)t*DD + d4);
        vl[t][d4+0]=v.x; vl[t][d4+1]=v.y; vl[t][d4+2]=v.z; vl[t][d4+3]=v.w;
    }
    __syncthreads();
    const int d = threadIdx.x >> 2, q = threadIdx.x & 3;
    __hip_bfloat16* dst = vT + ((size_t)bh*DD + d)*LL + l0 + q*16;
#pragma unroll
    for (int g = 0; g < 4; ++g) {
        ushort4 o;
        o.x = f2b_u16(vl[q*16+g*4+0][d]);
        o.y = f2b_u16(vl[q*16+g*4+1][d]);
        o.z = f2b_u16(vl[q*16+g*4+2][d]);
        o.w = f2b_u16(vl[q*16+g*4+3][d]);
        *(ushort4*)(dst + g*4) = o;
    }
}

// ---------------------------------------------------------------------------
// Feature post-process: out_b = RATIO*(exp(dd - diag - stab) + EPS), bf16.
// dd read f32; diag recomputed from bf16 scaled projections (data_b).
// gmax==nullptr -> per-row max (query path).
// ---------------------------------------------------------------------------
__global__ __launch_bounds__(256)
void feat_post_kernel(const float* __restrict__ dd_in, const __hip_bfloat16* __restrict__ data_b,
                      const float* __restrict__ gmax, __hip_bfloat16* __restrict__ out_b)
{
    const int wave = threadIdx.x >> 6, lane = threadIdx.x & 63;
    const int r = blockIdx.x*4 + wave;
    const int h = r & 7; const int bl = r >> 3;
    float x = __bfloat162float(data_b[(size_t)bl*DIMM + h*DD + lane]);
    float s = x * x;
#pragma unroll
    for (int off = 32; off > 0; off >>= 1) s += __shfl_xor(s, off);
    const float diag = 0.5f * s;
    const int bidx = bl / LL, l = bl % LL;
    const size_t rowbase = (((size_t)bidx*HH + h)*LL + l) * MM;
    float4 dd = *(const float4*)(dd_in + rowbase + lane*4);
    float stab;
    if (gmax) {
        stab = gmax[0];
    } else {
        float mx = fmaxf(fmaxf(dd.x, dd.y), fmaxf(dd.z, dd.w));
#pragma unroll
        for (int off = 32; off > 0; off >>= 1) mx = fmaxf(mx, __shfl_xor(mx, off));
        stab = mx;
    }
    const float cc = diag + stab;
    ushort4 ob;
    ob.x = f2b_u16(K_RATIO * (__expf(dd.x - cc) + K_EPS));
    ob.y = f2b_u16(K_RATIO * (__expf(dd.y - cc) + K_EPS));
    ob.z = f2b_u16(K_RATIO * (__expf(dd.z - cc) + K_EPS));
    ob.w = f2b_u16(K_RATIO * (__expf(dd.w - cc) + K_EPS));
    *(ushort4*)(out_b + rowbase + lane*4) = ob;
}

__global__ __launch_bounds__(256)
void kmax_part_kernel(const float* __restrict__ src, float* __restrict__ part)
{
    float mx = -3.0e38f;
    const float4* s4 = (const float4*)src;
    const int n4 = BB*HH*LL*MM/4;
    for (int i = blockIdx.x*256 + threadIdx.x; i < n4; i += 2048*256) {
        float4 v = s4[i];
        mx = fmaxf(mx, fmaxf(fmaxf(v.x, v.y), fmaxf(v.z, v.w)));
    }
#pragma unroll
    for (int off = 32; off > 0; off >>= 1) mx = fmaxf(mx, __shfl_xor(mx, off));
    __shared__ float wsm[4];
    if ((threadIdx.x & 63) == 0) wsm[threadIdx.x >> 6] = mx;
    __syncthreads();
    if (threadIdx.x == 0)
        part[blockIdx.x] = fmaxf(fmaxf(wsm[0], wsm[1]), fmaxf(wsm[2], wsm[3]));
}

__global__ __launch_bounds__(256)
void kmax_final_kernel(const float* __restrict__ part, float* __restrict__ gmax)
{
    float mx = -3.0e38f;
    for (int i = threadIdx.x; i < 2048; i += 256) mx = fmaxf(mx, part[i]);
#pragma unroll
    for (int off = 32; off > 0; off >>= 1) mx = fmaxf(mx, __shfl_xor(mx, off));
    __shared__ float wsm[4];
    if ((threadIdx.x & 63) == 0) wsm[threadIdx.x >> 6] = mx;
    __syncthreads();
    if (threadIdx.x == 0) gmax[0] = fmaxf(fmaxf(wsm[0], wsm[1]), fmaxf(wsm[2], wsm[3]));
}

// ---------------------------------------------------------------------------
// Per-chunk state, TRANSPOSED output: Sc[b,h,c,d,m] = sum_t v[t,d]*kp[t,m]
// kp read as bf16 (converted in-register), v read f32.
// ---------------------------------------------------------------------------
__global__ __launch_bounds__(256)
void chunk_state_kernel(const __hip_bfloat16* __restrict__ kp_b, const float* __restrict__ vw,
                        float* __restrict__ Sc, float* __restrict__ skc)
{
    const int c = blockIdx.x, h = blockIdx.y, b = blockIdx.z;
    const size_t bh = (size_t)b*HH + h;
    const __hip_bfloat16* kpc = kp_b + (bh*LL + (size_t)c*TT) * MM;
    const float* vc  = vw + (bh*LL + (size_t)c*TT) * DD;
    __shared__ float kl[32][MM];
    __shared__ float vl[32][DD];
    const int tid = threadIdx.x;
    const int m0 = (tid >> 3) * 8, d0 = (tid & 7) * 8;
    float acc[8][8] = {};   // [i over m][j over d]
    float sk[8] = {};
    for (int ts = 0; ts < TT; ts += 32) {
#pragma unroll
        for (int it = 0; it < 8; ++it) {
            int lin = it*256 + tid;
            int t = lin >> 6, mq = lin & 63;
            ushort4 kv = *(const ushort4*)(kpc + (size_t)(ts+t)*MM + mq*4);
            float4 kf4;
            kf4.x = __bfloat162float(*(__hip_bfloat16*)&kv.x);
            kf4.y = __bfloat162float(*(__hip_bfloat16*)&kv.y);
            kf4.z = __bfloat162float(*(__hip_bfloat16*)&kv.z);
            kf4.w = __bfloat162float(*(__hip_bfloat16*)&kv.w);
            *(float4*)&kl[t][mq*4] = kf4;
        }
#pragma unroll
        for (int it = 0; it < 2; ++it) {
            int lin = it*256 + tid;
            int t = lin >> 4, dq = lin & 15;
            *(float4*)&vl[t][dq*4] = *(const float4*)(vc + (size_t)(ts+t)*DD + dq*4);
        }
        __syncthreads();
        for (int t = 0; t < 32; ++t) {
            float kf[8], vf[8];
            *(float4*)&kf[0] = *(const float4*)&kl[t][m0];
            *(float4*)&kf[4] = *(const float4*)&kl[t][m0+4];
            *(float4*)&vf[0] = *(const float4*)&vl[t][d0];
            *(float4*)&vf[4] = *(const float4*)&vl[t][d0+4];
#pragma unroll
            for (int i = 0; i < 8; ++i) {
                sk[i] += kf[i];
#pragma unroll
                for (int j = 0; j < 8; ++j)
                    acc[i][j] = fmaf(kf[i], vf[j], acc[i][j]);
            }
        }
        __syncthreads();
    }
    float* So = Sc + (bh*NCHUNK + (size_t)c) * (MM*DD);   // [d][m]
#pragma unroll
    for (int j = 0; j < 8; ++j)
#pragma unroll
        for (int i = 0; i < 8; i += 4) {
            float4 o; o.x = acc[i][j]; o.y = acc[i+1][j]; o.z = acc[i+2][j]; o.w = acc[i+3][j];
            *(float4*)(So + (size_t)(d0+j)*MM + m0 + i) = o;
        }
    if ((tid & 7) == 0) {
        float* ko = skc + (bh*NCHUNK + (size_t)c) * MM;
#pragma unroll
        for (int i = 0; i < 8; ++i) ko[m0+i] = sk[i];
    }
}

// ---------------------------------------------------------------------------
// Exclusive prefix over chunks: Sc f32 [bh][c][d][m] -> bf16 running prefix.
// skc prefixed f32 in place. grid (16, 32).
// ---------------------------------------------------------------------------
__global__ __launch_bounds__(256)
void chunk_prefix_kernel(const float* __restrict__ Sc, __hip_bfloat16* __restrict__ ScT_b,
                         float* __restrict__ skc)
{
    const int bh = blockIdx.y;
    const int e4 = blockIdx.x*256 + threadIdx.x;
    size_t base = (size_t)bh * NCHUNK * (MM*DD) + (size_t)e4*4;
    float4 run = {0.f, 0.f, 0.f, 0.f};
#pragma unroll
    for (int c = 0; c < NCHUNK; ++c) {
        size_t idx = base + (size_t)c * (MM*DD);
        float4 t = *(const float4*)(Sc + idx);
        ushort4 o;
        o.x = f2b_u16(run.x); o.y = f2b_u16(run.y);
        o.z = f2b_u16(run.z); o.w = f2b_u16(run.w);
        *(ushort4*)(ScT_b + idx) = o;
        run.x += t.x; run.y += t.y; run.z += t.z; run.w += t.w;
    }
    if (blockIdx.x == 0) {
        size_t kb = (size_t)bh * NCHUNK * MM + threadIdx.x;
        float s2 = 0.f;
#pragma unroll
        for (int c = 0; c < NCHUNK; ++c) {
            size_t idx = kb + (size_t)c * MM;
            float t = skc[idx];
            skc[idx] = s2;
            s2 += t;
        }
    }
}

// ---------------------------------------------------------------------------
// MFMA chunk_out: per (b,h,c):
//   A = Qp Kp^T (K=256), mask s<=t -> Al bf16
//   O = Al @ [V;1] + Qp @ [S_prev; sk_prev]   (den rides as column 64)
//   attn[b, c*64+t, h*64+d] = O/den  (bf16)
// ---------------------------------------------------------------------------
__global__ __launch_bounds__(256)
void chunk_out_kernel(const __hip_bfloat16* __restrict__ qp_b,
                      const __hip_bfloat16* __restrict__ kp_b,
                      const __hip_bfloat16* __restrict__ vT_b,
                      const __hip_bfloat16* __restrict__ ScT_b,
                      const float* __restrict__ skp,
                      __hip_bfloat16* __restrict__ attn)
{
    constexpr int LDQ = 72;
    constexpr int LDA = 72;
    __shared__ __hip_bfloat16 Qs[64*LDQ];
    __shared__ __hip_bfloat16 Ks[64*LDQ];
    __shared__ __hip_bfloat16 Ss[80*LDQ];   // rows 0..63 = S_prev^T, 64 = sk, 65..79 = 0
    __shared__ __hip_bfloat16 Al[64*LDA];
    __shared__ __hip_bfloat16 Vl[80*LDA];   // rows 0..63 = V^T, 64 = ones, 65..79 = 0

    const int c = blockIdx.x, h = blockIdx.y, b = blockIdx.z;
    const size_t bh = (size_t)b*HH + h;
    const __hip_bfloat16* qpc = qp_b + (bh*LL + (size_t)c*TT) * MM;
    const __hip_bfloat16* kpc = kp_b + (bh*LL + (size_t)c*TT) * MM;
    const __hip_bfloat16* vTc = vT_b + bh*(size_t)(DD*LL) + (size_t)c*TT;
    const __hip_bfloat16* Scc = ScT_b + (bh*NCHUNK + (size_t)c) * (MM*DD);
    const float* skrow = skp + (bh*NCHUNK + (size_t)c) * MM;

    const int tid = threadIdx.x;
    const int lane = tid & 63;
    const int w = tid >> 6;
    const int l15 = lane & 15, l4 = lane >> 4;

    // preamble: V^T staging + constant rows
    {
#pragma unroll
        for (int it = 0; it < 2; ++it) {
            int lin = it*256 + tid;
            int d = lin >> 3, c8 = (lin & 7)*8;
            *(uint4*)&Vl[d*LDA + c8] = *(const uint4*)(vTc + (size_t)d*LL + c8);
        }
        const __hip_bfloat16 one = __float2bfloat16(1.0f);
        const __hip_bfloat16 zero = __float2bfloat16(0.0f);
        for (int idx = tid; idx < 16*64; idx += 256) {
            int rr = idx >> 6, cc2 = idx & 63;
            Vl[(64+rr)*LDA + cc2] = (rr == 0) ? one : zero;
        }
        for (int idx = tid; idx < 15*64; idx += 256) {
            int rr = idx / 64, cc2 = idx % 64;
            Ss[(65+rr)*LDQ + cc2] = zero;
        }
    }

    f32x4 accA[4];
    f32x4 accO[5];
#pragma unroll
    for (int i = 0; i < 4; ++i) { f32x4 z = {0.f,0.f,0.f,0.f}; accA[i] = z; }
#pragma unroll
    for (int i = 0; i < 5; ++i) { f32x4 z = {0.f,0.f,0.f,0.f}; accO[i] = z; }

    for (int mq = 0; mq < MM; mq += 64) {
        __syncthreads();
#pragma unroll
        for (int it = 0; it < 2; ++it) {
            int lin = it*256 + tid;
            int r = lin >> 3, m8 = (lin & 7)*8;
            *(uint4*)&Qs[r*LDQ + m8] = *(const uint4*)(qpc + (size_t)r*MM + mq + m8);
            *(uint4*)&Ks[r*LDQ + m8] = *(const uint4*)(kpc + (size_t)r*MM + mq + m8);
            *(uint4*)&Ss[r*LDQ + m8] = *(const uint4*)(Scc + (size_t)r*MM + mq + m8);
        }
        if (tid < 64) Ss[64*LDQ + tid] = __float2bfloat16(skrow[mq + tid]);
        __syncthreads();
#pragma unroll
        for (int ks = 0; ks < 2; ++ks) {
            const int ko = ks*32 + l4*8;
            short8 aF = *(const short8*)&Qs[(w*16 + l15)*LDQ + ko];
#pragma unroll
            for (int nt = 0; nt < 4; ++nt) {
                short8 bF = *(const short8*)&Ks[(nt*16 + l15)*LDQ + ko];
                accA[nt] = __builtin_amdgcn_mfma_f32_16x16x32_bf16(aF, bF, accA[nt], 0, 0, 0);
            }
#pragma unroll
            for (int nt = 0; nt < 5; ++nt) {
                short8 sF = *(const short8*)&Ss[(nt*16 + l15)*LDQ + ko];
                accO[nt] = __builtin_amdgcn_mfma_f32_16x16x32_bf16(aF, sF, accO[nt], 0, 0, 0);
            }
        }
    }
    __syncthreads();
    // causal mask -> Al[t][s] bf16
#pragma unroll
    for (int nt = 0; nt < 4; ++nt) {
        const int s = nt*16 + l15;
#pragma unroll
        for (int j = 0; j < 4; ++j) {
            const int t = w*16 + l4*4 + j;
            const float v = (s <= t) ? accA[nt][j] : 0.f;
            Al[t*LDA + s] = __float2bfloat16(v);
        }
    }
    __syncthreads();
    // O += Al @ [V; ones]
#pragma unroll
    for (int ks = 0; ks < 2; ++ks) {
        const int ko = ks*32 + l4*8;
        short8 aF = *(const short8*)&Al[(w*16 + l15)*LDA + ko];
#pragma unroll
        for (int nt = 0; nt < 5; ++nt) {
            short8 vF = *(const short8*)&Vl[(nt*16 + l15)*LDA + ko];
            accO[nt] = __builtin_amdgcn_mfma_f32_16x16x32_bf16(aF, vF, accO[nt], 0, 0, 0);
        }
    }
    // epilogue: divide by den (col 64, held by lane l4*16), write bf16
    __hip_bfloat16* arow = attn + ((size_t)b*LL + (size_t)c*TT) * DIMM + h*DD;
#pragma unroll
    for (int j = 0; j < 4; ++j) {
        const float den = __shfl(accO[4][j], (lane & 48));
        const float inv = 1.0f / den;
        const int t = w*16 + l4*4 + j;
#pragma unroll
        for (int nt = 0; nt < 4; ++nt) {
            const int d = nt*16 + l15;
            arow[(size_t)t*DIMM + d] = __float2bfloat16(accO[nt][j] * inv);
        }
    }
}

// ---------------------------------------------------------------------------
extern "C" void kernel_launch(void* const* d_in, const int* in_sizes, int n_in,
                              void* d_out, int out_size, void* d_ws, size_t ws_size,
                              hipStream_t stream)
{
    (void)in_sizes; (void)n_in; (void)out_size; (void)ws_size;
    const float* query = (const float*)d_in[0];
    const float* key   = (const float*)d_in[1];
    const float* value = (const float*)d_in[2];
    const float* Wq = (const float*)d_in[3];
    const float* bq = (const float*)d_in[4];
    const float* Wk = (const float*)d_in[5];
    const float* bk = (const float*)d_in[6];
    const float* Wv = (const float*)d_in[7];
    const float* bv = (const float*)d_in[8];
    const float* Wo = (const float*)d_in[9];
    const float* bo = (const float*)d_in[10];
    const float* proj = (const float*)d_in[11];

    float* ws = (float*)d_ws;
    // Workspace peak ~245.4 MB (f32 slots), under the round-1-verified 253 MB.
    // Timeline overlays (hazard-checked):
    //   ddq [0, 16.7M)            : dd_q (step5-7); Sc f32 overlays (step8-9); vb cast overlays (step1-2)
    //   ddk [16.7M, 33.5M)        : dd_k (step5-7); ScT_b + skc overlay (step8+)
    //   qp_b [33.5M, 41.9M)       : qb input cast (step1-2), then qp bf16 (step7+)
    //   kp_b [41.9M, 50.3M)       : kb input cast (step1-2), then kp bf16 (step7+)
    float* ddq = ws;
    float* ddk = ws + 16777216;
    __hip_bfloat16* qp_b  = (__hip_bfloat16*)(ws + 33554432);
    __hip_bfloat16* kp_b  = (__hip_bfloat16*)(ws + 41943040);
    float* vw             = ws + 50331648;                       // 4,194,304 f32
    __hip_bfloat16* vT_b  = (__hip_bfloat16*)(ws + 54525952);    // 4,194,304 bf16
    __hip_bfloat16* qsb   = (__hip_bfloat16*)(ws + 56623104);    // 4,194,304 bf16; attn_b overlays
    __hip_bfloat16* ksb   = (__hip_bfloat16*)(ws + 58720256);    // 4,194,304 bf16
    __hip_bfloat16* Wqb   = (__hip_bfloat16*)(ws + 60817408);
    __hip_bfloat16* Wkb   = (__hip_bfloat16*)(ws + 60948480);
    __hip_bfloat16* Wvb   = (__hip_bfloat16*)(ws + 61079552);
    __hip_bfloat16* Wob   = (__hip_bfloat16*)(ws + 61210624);
    __hip_bfloat16* projb = (__hip_bfloat16*)(ws + 61341696);
    float* part           = ws + 61349888;                       // 2048
    float* gmax           = ws + 61351936;                       // 1
    // overlays
    __hip_bfloat16* qb     = qp_b;
    __hip_bfloat16* kb     = kp_b;
    __hip_bfloat16* vb     = (__hip_bfloat16*)ddq;
    float* Sc              = ddq;
    __hip_bfloat16* ScT_b  = (__hip_bfloat16*)ddk;
    float* skc             = ws + 25165824;                      // inside ddk region
    __hip_bfloat16* attn_b = qsb;

    const dim3 blk(256);

    // input / weight casts
    cvt_bf16_kernel<<<2048, blk, 0, stream>>>(query, qb, 1048576);
    cvt_bf16_kernel<<<2048, blk, 0, stream>>>(key,   kb, 1048576);
    cvt_bf16_kernel<<<2048, blk, 0, stream>>>(value, vb, 1048576);
    cvt_bf16_kernel<<<256,  blk, 0, stream>>>(Wq, Wqb, 65536);
    cvt_bf16_kernel<<<256,  blk, 0, stream>>>(Wk, Wkb, 65536);
    cvt_bf16_kernel<<<256,  blk, 0, stream>>>(Wv, Wvb, 65536);
    cvt_bf16_kernel<<<256,  blk, 0, stream>>>(Wo, Wob, 65536);
    cvt_bf16_kernel<<<16,   blk, 0, stream>>>(proj, projb, 4096);

    // projections: q/k -> bf16 scaled; v -> f32 scattered [B,H,L,64]
    gemm_bf16<512,0,__hip_bfloat16><<<dim3(4,64), blk, 0, stream>>>(qb, Wqb, bq, qsb, K_SCALE);
    gemm_bf16<512,0,__hip_bfloat16><<<dim3(4,64), blk, 0, stream>>>(kb, Wkb, bk, ksb, K_SCALE);
    gemm_bf16<512,1,float><<<dim3(4,64), blk, 0, stream>>>(vb, Wvb, bv, vw, 1.0f);

    // v transpose -> bf16 [B,H,D,L]
    transpose_v_kernel<<<dim3(32,32), blk, 0, stream>>>(vw, vT_b);

    // dd = data_scaled @ proj^T -> [B,H,L,M] f32
    gemm_bf16<64,2,float><<<dim3(2,512), blk, 0, stream>>>(qsb, projb, nullptr, ddq, 1.0f);
    gemm_bf16<64,2,float><<<dim3(2,512), blk, 0, stream>>>(ksb, projb, nullptr, ddk, 1.0f);

    // global max over key dd
    kmax_part_kernel<<<2048, blk, 0, stream>>>(ddk, part);
    kmax_final_kernel<<<1, blk, 0, stream>>>(part, gmax);

    // feature post-process -> bf16
    feat_post_kernel<<<16384, blk, 0, stream>>>(ddq, qsb, nullptr, qp_b);
    feat_post_kernel<<<16384, blk, 0, stream>>>(ddk, ksb, gmax,    kp_b);

    // chunked causal linear attention
    chunk_state_kernel<<<dim3(NCHUNK,HH,BB), blk, 0, stream>>>(kp_b, vw, Sc, skc);
    chunk_prefix_kernel<<<dim3(16,32), blk, 0, stream>>>(Sc, ScT_b, skc);
    chunk_out_kernel<<<dim3(NCHUNK,HH,BB), blk, 0, stream>>>(qp_b, kp_b, vT_b, ScT_b, skc, attn_b);

    // output projection (f32 out)
    gemm_bf16<512,0,float><<<dim3(4,64), blk, 0, stream>>>(attn_b, Wob, bo, (float*)d_out, 1.0f);
}

// Round 5
// 251.435 us; speedup vs baseline: 2.7304x; 1.0031x over previous
//
#include <hip/hip_runtime.h>
#include <hip/hip_bf16.h>
#include <math.h>

// Problem constants
#define BB 4
#define LL 2048
#define HH 8
#define DD 64          // head dim
#define MM 256         // nb_features
#define DIMM 512
#define TT 64          // chunk length
#define NCHUNK (LL/TT) // 32

constexpr float K_SCALE = 0.35355339059327379f; // 64^-0.25
constexpr float K_RATIO = 0.0625f;              // 256^-0.5
constexpr float K_EPS   = 1e-6f;

using short8 = __attribute__((ext_vector_type(8))) short;
using f32x4  = __attribute__((ext_vector_type(4))) float;

__device__ inline unsigned short f2b_u16(float x) {
    __hip_bfloat16 h = __float2bfloat16(x);
    return *reinterpret_cast<unsigned short*>(&h);
}
__device__ inline ushort4 f2b4(float4 v) {
    ushort4 o; o.x = f2b_u16(v.x); o.y = f2b_u16(v.y); o.z = f2b_u16(v.z); o.w = f2b_u16(v.w);
    return o;
}

template<typename T> __device__ inline T f2o(float v);
template<> __device__ inline float f2o<float>(float v) { return v; }
template<> __device__ inline __hip_bfloat16 f2o<__hip_bfloat16>(float v) { return __float2bfloat16(v); }

// ---------------------------------------------------------------------------
// bf16 MFMA GEMM: Y = X[MR,K] @ W[N,K]^T (+bias) * postscale, OT out.
// XT/WT in {float, bf16}: f32 operands are converted during LDS staging.
// Tile 128x128, BK=64, 4 waves (2x2), each wave 64x64. (layout verified r2)
// MODE 0: row-major [MR,512]
// MODE 1: v-scatter   out[((b*H+h)*L+l)*64+d]
// MODE 2: feat-scatter out[((b*H+h)*L+l)*256+c]
// BMAX: also emit per-block max of raw acc (dd) into bpart[block].
// ---------------------------------------------------------------------------
template<int KDIM, int MODE, typename OT, typename XT, typename WT, bool BMAX>
__global__ __launch_bounds__(256)
void gemm_bf16(const XT* __restrict__ X, const WT* __restrict__ W,
               const float* __restrict__ bias, OT* __restrict__ out, float postscale,
               float* __restrict__ bpart)
{
    constexpr int LDT = 72;
    __shared__ __hip_bfloat16 As[128*LDT];
    __shared__ __hip_bfloat16 Bs[128*LDT];
    __shared__ float wmx[4];
    const int tid = threadIdx.x;
    const int lane = tid & 63;
    const int w = tid >> 6;
    const int wm = (w >> 1) * 64, wn = (w & 1) * 64;
    const int row0 = blockIdx.y * 128, col0 = blockIdx.x * 128;
    const int l15 = lane & 15, l4 = lane >> 4;

    f32x4 acc[4][4];
#pragma unroll
    for (int mt = 0; mt < 4; ++mt)
#pragma unroll
        for (int nt = 0; nt < 4; ++nt) {
            f32x4 z = {0.f, 0.f, 0.f, 0.f};
            acc[mt][nt] = z;
        }

    for (int k0 = 0; k0 < KDIM; k0 += 64) {
        if constexpr (sizeof(XT) == 4) {
#pragma unroll
            for (int i = 0; i < 8; ++i) {
                int lin = i*256 + tid;                  // 0..2047
                int r = lin >> 4, kc = (lin & 15)*4;
                float4 a = *(const float4*)(X + (size_t)(row0 + r)*KDIM + k0 + kc);
                *(ushort4*)&As[r*LDT + kc] = f2b4(a);
            }
        } else {
#pragma unroll
            for (int i = 0; i < 4; ++i) {
                int lin = i*256 + tid;                  // 0..1023
                int r = lin >> 3, kc = (lin & 7)*8;
                *(uint4*)&As[r*LDT + kc] = *(const uint4*)(X + (size_t)(row0 + r)*KDIM + k0 + kc);
            }
        }
        if constexpr (sizeof(WT) == 4) {
#pragma unroll
            for (int i = 0; i < 8; ++i) {
                int lin = i*256 + tid;
                int r = lin >> 4, kc = (lin & 15)*4;
                float4 b = *(const float4*)(W + (size_t)(col0 + r)*KDIM + k0 + kc);
                *(ushort4*)&Bs[r*LDT + kc] = f2b4(b);
            }
        } else {
#pragma unroll
            for (int i = 0; i < 4; ++i) {
                int lin = i*256 + tid;
                int r = lin >> 3, kc = (lin & 7)*8;
                *(uint4*)&Bs[r*LDT + kc] = *(const uint4*)(W + (size_t)(col0 + r)*KDIM + k0 + kc);
            }
        }
        __syncthreads();
#pragma unroll
        for (int ks = 0; ks < 2; ++ks) {
            const int koff = ks*32 + l4*8;
            short8 aF[4], bF[4];
#pragma unroll
            for (int mt = 0; mt < 4; ++mt)
                aF[mt] = *(const short8*)&As[(wm + mt*16 + l15)*LDT + koff];
#pragma unroll
            for (int nt = 0; nt < 4; ++nt)
                bF[nt] = *(const short8*)&Bs[(wn + nt*16 + l15)*LDT + koff];
#pragma unroll
            for (int mt = 0; mt < 4; ++mt)
#pragma unroll
                for (int nt = 0; nt < 4; ++nt)
                    acc[mt][nt] = __builtin_amdgcn_mfma_f32_16x16x32_bf16(aF[mt], bF[nt], acc[mt][nt], 0, 0, 0);
        }
        __syncthreads();
    }

    if constexpr (BMAX) {
        float mx = -3.0e38f;
#pragma unroll
        for (int mt = 0; mt < 4; ++mt)
#pragma unroll
            for (int nt = 0; nt < 4; ++nt)
#pragma unroll
                for (int j = 0; j < 4; ++j)
                    mx = fmaxf(mx, acc[mt][nt][j]);
#pragma unroll
        for (int off = 32; off > 0; off >>= 1) mx = fmaxf(mx, __shfl_xor(mx, off));
        if (lane == 0) wmx[w] = mx;
        __syncthreads();
        if (tid == 0)
            bpart[blockIdx.y*gridDim.x + blockIdx.x] =
                fmaxf(fmaxf(wmx[0], wmx[1]), fmaxf(wmx[2], wmx[3]));
    }

#pragma unroll
    for (int mt = 0; mt < 4; ++mt) {
#pragma unroll
        for (int nt = 0; nt < 4; ++nt) {
            const int c = col0 + wn + nt*16 + l15;
            const float bval = (MODE == 2) ? 0.f : bias[c];
#pragma unroll
            for (int j = 0; j < 4; ++j) {
                const int r = row0 + wm + mt*16 + l4*4 + j;
                const float val = (acc[mt][nt][j] + bval) * postscale;
                if (MODE == 0) {
                    out[(size_t)r*DIMM + c] = f2o<OT>(val);
                } else if (MODE == 1) {
                    const int b = r >> 11, l = r & 2047;
                    const int hh = c >> 6, d = c & 63;
                    out[(((size_t)b*HH + hh)*LL + l)*DD + d] = f2o<OT>(val);
                } else {
                    const int bl = r >> 3, hh = r & 7;
                    const int b = bl >> 11, l = bl & 2047;
                    out[(((size_t)b*HH + hh)*LL + l)*MM + c] = f2o<OT>(val);
                }
            }
        }
    }
}

// ---------------------------------------------------------------------------
// Fused Q feature map: qp = RATIO*(exp(X@P^T - diag - rowmax) + EPS), bf16.
// X = qsb [65536,64] bf16 (scaled q proj); P = proj [256,64] f32.
// BM=128, BN=256(=all M, so rowmax is block-local), 512 threads = 8 waves 2x4.
// ---------------------------------------------------------------------------
__global__ __launch_bounds__(512)
void feat_gemm_q_kernel(const __hip_bfloat16* __restrict__ X, const float* __restrict__ P,
                        __hip_bfloat16* __restrict__ qp_b)
{
    constexpr int LDT = 72;
    __shared__ __hip_bfloat16 As[128*LDT];
    __shared__ __hip_bfloat16 Bs[256*LDT];
    __shared__ float rowmax[128][4];
    __shared__ float diagl[128];
    const int tid = threadIdx.x;
    const int lane = tid & 63, w = tid >> 6;
    const int wr = w >> 2, wc = w & 3;
    const int l15 = lane & 15, l4 = lane >> 4;
    const int row0 = blockIdx.x * 128;

    // stage A (bf16 copy): 1024 uint4
#pragma unroll
    for (int i = 0; i < 2; ++i) {
        int lin = i*512 + tid;
        int r = lin >> 3, kc = (lin & 7)*8;
        *(uint4*)&As[r*LDT + kc] = *(const uint4*)(X + (size_t)(row0 + r)*64 + kc);
    }
    // stage B (f32 -> bf16): 4096 float4
#pragma unroll
    for (int i = 0; i < 8; ++i) {
        int lin = i*512 + tid;
        int r = lin >> 4, kc = (lin & 15)*4;
        float4 v = *(const float4*)(P + (size_t)r*64 + kc);
        *(ushort4*)&Bs[r*LDT + kc] = f2b4(v);
    }
    __syncthreads();

    f32x4 acc[4][4];
#pragma unroll
    for (int mt = 0; mt < 4; ++mt)
#pragma unroll
        for (int nt = 0; nt < 4; ++nt) {
            f32x4 z = {0.f,0.f,0.f,0.f};
            acc[mt][nt] = z;
        }
#pragma unroll
    for (int ks = 0; ks < 2; ++ks) {
        const int ko = ks*32 + l4*8;
        short8 aF[4], bF[4];
#pragma unroll
        for (int mt = 0; mt < 4; ++mt)
            aF[mt] = *(const short8*)&As[(wr*64 + mt*16 + l15)*LDT + ko];
#pragma unroll
        for (int nt = 0; nt < 4; ++nt)
            bF[nt] = *(const short8*)&Bs[(wc*64 + nt*16 + l15)*LDT + ko];
#pragma unroll
        for (int mt = 0; mt < 4; ++mt)
#pragma unroll
            for (int nt = 0; nt < 4; ++nt)
                acc[mt][nt] = __builtin_amdgcn_mfma_f32_16x16x32_bf16(aF[mt], bF[nt], acc[mt][nt], 0, 0, 0);
    }

    // diag from staged A rows: 4 threads per row x 16 elems
    {
        const int r = tid >> 2, q = tid & 3;
        float s = 0.f;
#pragma unroll
        for (int i = 0; i < 16; ++i) {
            float x = __bfloat162float(As[r*LDT + q*16 + i]);
            s += x*x;
        }
        s += __shfl_xor(s, 1);
        s += __shfl_xor(s, 2);
        if (q == 0) diagl[r] = 0.5f * s;
    }
    // per-row max over this wave's 64 cols, then across the 4 col-waves via LDS
#pragma unroll
    for (int mt = 0; mt < 4; ++mt)
#pragma unroll
        for (int j = 0; j < 4; ++j) {
            float m = fmaxf(fmaxf(acc[mt][0][j], acc[mt][1][j]),
                            fmaxf(acc[mt][2][j], acc[mt][3][j]));
#pragma unroll
            for (int off = 8; off > 0; off >>= 1) m = fmaxf(m, __shfl_xor(m, off));
            if (l15 == 0) rowmax[wr*64 + mt*16 + l4*4 + j][wc] = m;
        }
    __syncthreads();

#pragma unroll
    for (int mt = 0; mt < 4; ++mt)
#pragma unroll
        for (int j = 0; j < 4; ++j) {
            const int r = wr*64 + mt*16 + l4*4 + j;
            const float stab = fmaxf(fmaxf(rowmax[r][0], rowmax[r][1]),
                                     fmaxf(rowmax[r][2], rowmax[r][3]));
            const float cc = diagl[r] + stab;
            const int gr = row0 + r;
            const int bl = gr >> 3, h = gr & 7;
            const int b = bl >> 11, l = bl & 2047;
            const size_t base = (((size_t)b*HH + h)*LL + l)*MM;
#pragma unroll
            for (int nt = 0; nt < 4; ++nt)
                qp_b[base + wc*64 + nt*16 + l15] =
                    __float2bfloat16(K_RATIO * (__expf(acc[mt][nt][j] - cc) + K_EPS));
        }
}

__global__ __launch_bounds__(256)
void kmax_final_kernel(const float* __restrict__ part, float* __restrict__ gmax)
{
    float mx = -3.0e38f;
    for (int i = threadIdx.x; i < 1024; i += 256) mx = fmaxf(mx, part[i]);
#pragma unroll
    for (int off = 32; off > 0; off >>= 1) mx = fmaxf(mx, __shfl_xor(mx, off));
    __shared__ float wsm[4];
    if ((threadIdx.x & 63) == 0) wsm[threadIdx.x >> 6] = mx;
    __syncthreads();
    if (threadIdx.x == 0) gmax[0] = fmaxf(fmaxf(wsm[0], wsm[1]), fmaxf(wsm[2], wsm[3]));
}

// ---------------------------------------------------------------------------
// K feature post-process, tiled 64t x 256m per (b,h):
//   kp = RATIO*(exp(ddk - diag - gmax) + EPS)
// writes kp_b [bh][t][m] and kpT_b [bh][m][t] (LDS transpose).
// ---------------------------------------------------------------------------
__global__ __launch_bounds__(256)
void feat_post_k_kernel(const float* __restrict__ ddk, const __hip_bfloat16* __restrict__ ksb,
                        const float* __restrict__ gmax,
                        __hip_bfloat16* __restrict__ kp_b, __hip_bfloat16* __restrict__ kpT_b)
{
    constexpr int LDK = 260;
    __shared__ __hip_bfloat16 kpl[64*LDK];
    const int lt = blockIdx.x, bh = blockIdx.y;
    const int b = bh >> 3, h = bh & 7;
    const int tid = threadIdx.x;
    const int r = tid >> 2, q = tid & 3;   // row t = r, m-quarter q (64 m)

    // diag from ksb (scaled bf16 k-proj)
    const __hip_bfloat16* krow = ksb + ((size_t)(b*LL + lt*64 + r))*DIMM + h*DD + q*16;
    float s = 0.f;
#pragma unroll
    for (int i = 0; i < 16; ++i) {
        float x = __bfloat162float(krow[i]);
        s += x*x;
    }
    s += __shfl_xor(s, 1);
    s += __shfl_xor(s, 2);
    const float cc = 0.5f*s + gmax[0];

    const float* dsrc = ddk + ((size_t)bh*LL + lt*64 + r)*MM + q*64;
    __hip_bfloat16* kout = kp_b + ((size_t)bh*LL + lt*64 + r)*MM + q*64;
#pragma unroll
    for (int g = 0; g < 16; ++g) {
        float4 dd = *(const float4*)(dsrc + g*4);
        float4 e;
        e.x = K_RATIO * (__expf(dd.x - cc) + K_EPS);
        e.y = K_RATIO * (__expf(dd.y - cc) + K_EPS);
        e.z = K_RATIO * (__expf(dd.z - cc) + K_EPS);
        e.w = K_RATIO * (__expf(dd.w - cc) + K_EPS);
        ushort4 o = f2b4(e);
        *(ushort4*)(kout + g*4) = o;
        *(ushort4*)&kpl[r*LDK + q*64 + g*4] = o;
    }
    __syncthreads();
    // transposed write: 16 passes; lanes tid&15 cover t contiguously
    const int mrow = tid >> 4;          // 0..15
    const int t4 = (tid & 15) * 4;
#pragma unroll
    for (int pass = 0; pass < 16; ++pass) {
        const int m = pass*16 + mrow;
        ushort4 o;
        o.x = *(unsigned short*)&kpl[(t4+0)*LDK + m];
        o.y = *(unsigned short*)&kpl[(t4+1)*LDK + m];
        o.z = *(unsigned short*)&kpl[(t4+2)*LDK + m];
        o.w = *(unsigned short*)&kpl[(t4+3)*LDK + m];
        *(ushort4*)(kpT_b + ((size_t)bh*MM + m)*LL + lt*64 + t4) = o;
    }
}

// ---------------------------------------------------------------------------
// vw [B,H,L,D] f32  ->  vT [B,H,D,L] bf16  (tiled LDS transpose)
// ---------------------------------------------------------------------------
__global__ __launch_bounds__(256)
void transpose_v_kernel(const float* __restrict__ vw, __hip_bfloat16* __restrict__ vT)
{
    __shared__ float vl[64][65];
    const int bh = blockIdx.y;
    const int l0 = blockIdx.x*64;
    const float* src = vw + ((size_t)bh*LL + l0)*DD;
#pragma unroll
    for (int it = 0; it < 4; ++it) {
        int lin = it*256 + threadIdx.x;
        int t = lin >> 4, d4 = (lin & 15)*4;
        float4 v = *(const float4*)(src + (size_t)t*DD + d4);
        vl[t][d4+0]=v.x; vl[t][d4+1]=v.y; vl[t][d4+2]=v.z; vl[t][d4+3]=v.w;
    }
    __syncthreads();
    const int d = threadIdx.x >> 2, q = threadIdx.x & 3;
    __hip_bfloat16* dst = vT + ((size_t)bh*DD + d)*LL + l0 + q*16;
#pragma unroll
    for (int g = 0; g < 4; ++g) {
        ushort4 o;
        o.x = f2b_u16(vl[q*16+g*4+0][d]);
        o.y = f2b_u16(vl[q*16+g*4+1][d]);
        o.z = f2b_u16(vl[q*16+g*4+2][d]);
        o.w = f2b_u16(vl[q*16+g*4+3][d]);
        *(ushort4*)(dst + g*4) = o;
    }
}

// ---------------------------------------------------------------------------
// Fused chunk state + exclusive prefix (MFMA). Running state lives in the
// MFMA accumulators. Per block: one (bh, 64-wide m-block), chunks serial.
// For each chunk c: write acc (= prefix over chunks < c) as bf16, then
// acc += vT_tile^T-product: S^T[d][m] += sum_t vT[d][t]*kpT[m][t].
// sk rides as a register-built ones-row A-fragment (extra 16x16 tile).
// ---------------------------------------------------------------------------
__global__ __launch_bounds__(256)
void chunk_state_mfma_kernel(const __hip_bfloat16* __restrict__ kpT_b,
                             const __hip_bfloat16* __restrict__ vT_b,
                             __hip_bfloat16* __restrict__ ScT_b,
                             float* __restrict__ skc)
{
    __shared__ __hip_bfloat16 kT[2][64*72];
    __shared__ __hip_bfloat16 vT[2][64*72];
    const int mb = blockIdx.x, bh = blockIdx.y;
    const int tid = threadIdx.x, lane = tid & 63, w = tid >> 6;
    const int l15 = lane & 15, l4 = lane >> 4;
    const int sr = tid >> 2, sq = tid & 3;      // staging row / col-quarter
    const __hip_bfloat16* ksrc = kpT_b + ((size_t)bh*MM + mb*64 + sr)*LL + sq*16;
    const __hip_bfloat16* vsrc = vT_b  + ((size_t)bh*DD + sr)*LL + sq*16;

    f32x4 accS[4];
    f32x4 accK;
#pragma unroll
    for (int i = 0; i < 4; ++i) { f32x4 z = {0.f,0.f,0.f,0.f}; accS[i] = z; }
    { f32x4 z = {0.f,0.f,0.f,0.f}; accK = z; }

    short8 ones8;
    {
        const short ov = (short)0x3F80;   // bf16 1.0
#pragma unroll
        for (int i = 0; i < 8; ++i) ones8[i] = (l15 == 0) ? ov : (short)0;
    }

    // stage chunk 0 into buf 0
    {
        *(uint4*)&kT[0][sr*72 + sq*16]     = *(const uint4*)(ksrc + 0);
        *(uint4*)&kT[0][sr*72 + sq*16 + 8] = *(const uint4*)(ksrc + 8);
        *(uint4*)&vT[0][sr*72 + sq*16]     = *(const uint4*)(vsrc + 0);
        *(uint4*)&vT[0][sr*72 + sq*16 + 8] = *(const uint4*)(vsrc + 8);
    }

    for (int c = 0; c < NCHUNK; ++c) {
        // write exclusive prefix from registers
        __hip_bfloat16* So = ScT_b + ((size_t)(bh*NCHUNK + c))*(MM*DD);
        const int mcol = mb*64 + w*16 + l15;
#pragma unroll
        for (int dt = 0; dt < 4; ++dt)
#pragma unroll
            for (int j = 0; j < 4; ++j)
                So[(size_t)(dt*16 + l4*4 + j)*MM + mcol] = __float2bfloat16(accS[dt][j]);
        if (l4 == 0)
            skc[((size_t)bh*NCHUNK + c)*MM + mcol] = accK[0];

        __syncthreads();   // stage(c) complete; prior buf reads done
        if (c + 1 < NCHUNK) {
            const int nb = (c + 1) & 1;
            const size_t off = (size_t)(c + 1) * 64;
            *(uint4*)&kT[nb][sr*72 + sq*16]     = *(const uint4*)(ksrc + off);
            *(uint4*)&kT[nb][sr*72 + sq*16 + 8] = *(const uint4*)(ksrc + off + 8);
            *(uint4*)&vT[nb][sr*72 + sq*16]     = *(const uint4*)(vsrc + off);
            *(uint4*)&vT[nb][sr*72 + sq*16 + 8] = *(const uint4*)(vsrc + off + 8);
        }
        const int buf = c & 1;
#pragma unroll
        for (int ks = 0; ks < 2; ++ks) {
            const int ko = ks*32 + l4*8;
            short8 bF = *(const short8*)&kT[buf][(w*16 + l15)*72 + ko];
#pragma unroll
            for (int dt = 0; dt < 4; ++dt) {
                short8 aF = *(const short8*)&vT[buf][(dt*16 + l15)*72 + ko];
                accS[dt] = __builtin_amdgcn_mfma_f32_16x16x32_bf16(aF, bF, accS[dt], 0, 0, 0);
            }
            accK = __builtin_amdgcn_mfma_f32_16x16x32_bf16(ones8, bF, accK, 0, 0, 0);
        }
    }
}

// ---------------------------------------------------------------------------
// MFMA chunk_out (verified round 4): per (b,h,c):
//   A = Qp Kp^T (K=256), mask s<=t -> Al bf16
//   O = Al @ [V;1] + Qp @ [S_prev; sk_prev]   (den rides as column 64)
//   attn[b, c*64+t, h*64+d] = O/den  (bf16)
// ---------------------------------------------------------------------------
__global__ __launch_bounds__(256)
void chunk_out_kernel(const __hip_bfloat16* __restrict__ qp_b,
                      const __hip_bfloat16* __restrict__ kp_b,
                      const __hip_bfloat16* __restrict__ vT_b,
                      const __hip_bfloat16* __restrict__ ScT_b,
                      const float* __restrict__ skp,
                      __hip_bfloat16* __restrict__ attn)
{
    constexpr int LDQ = 72;
    constexpr int LDA = 72;
    __shared__ __hip_bfloat16 Qs[64*LDQ];
    __shared__ __hip_bfloat16 Ks[64*LDQ];
    __shared__ __hip_bfloat16 Ss[80*LDQ];
    __shared__ __hip_bfloat16 Al[64*LDA];
    __shared__ __hip_bfloat16 Vl[80*LDA];

    const int c = blockIdx.x, h = blockIdx.y, b = blockIdx.z;
    const size_t bh = (size_t)b*HH + h;
    const __hip_bfloat16* qpc = qp_b + (bh*LL + (size_t)c*TT) * MM;
    const __hip_bfloat16* kpc = kp_b + (bh*LL + (size_t)c*TT) * MM;
    const __hip_bfloat16* vTc = vT_b + bh*(size_t)(DD*LL) + (size_t)c*TT;
    const __hip_bfloat16* Scc = ScT_b + (bh*NCHUNK + (size_t)c) * (MM*DD);
    const float* skrow = skp + (bh*NCHUNK + (size_t)c) * MM;

    const int tid = threadIdx.x;
    const int lane = tid & 63;
    const int w = tid >> 6;
    const int l15 = lane & 15, l4 = lane >> 4;

    {
#pragma unroll
        for (int it = 0; it < 2; ++it) {
            int lin = it*256 + tid;
            int d = lin >> 3, c8 = (lin & 7)*8;
            *(uint4*)&Vl[d*LDA + c8] = *(const uint4*)(vTc + (size_t)d*LL + c8);
        }
        const __hip_bfloat16 one = __float2bfloat16(1.0f);
        const __hip_bfloat16 zero = __float2bfloat16(0.0f);
        for (int idx = tid; idx < 16*64; idx += 256) {
            int rr = idx >> 6, cc2 = idx & 63;
            Vl[(64+rr)*LDA + cc2] = (rr == 0) ? one : zero;
        }
        for (int idx = tid; idx < 15*64; idx += 256) {
            int rr = idx / 64, cc2 = idx % 64;
            Ss[(65+rr)*LDQ + cc2] = zero;
        }
    }

    f32x4 accA[4];
    f32x4 accO[5];
#pragma unroll
    for (int i = 0; i < 4; ++i) { f32x4 z = {0.f,0.f,0.f,0.f}; accA[i] = z; }
#pragma unroll
    for (int i = 0; i < 5; ++i) { f32x4 z = {0.f,0.f,0.f,0.f}; accO[i] = z; }

    for (int mq = 0; mq < MM; mq += 64) {
        __syncthreads();
#pragma unroll
        for (int it = 0; it < 2; ++it) {
            int lin = it*256 + tid;
            int r = lin >> 3, m8 = (lin & 7)*8;
            *(uint4*)&Qs[r*LDQ + m8] = *(const uint4*)(qpc + (size_t)r*MM + mq + m8);
            *(uint4*)&Ks[r*LDQ + m8] = *(const uint4*)(kpc + (size_t)r*MM + mq + m8);
            *(uint4*)&Ss[r*LDQ + m8] = *(const uint4*)(Scc + (size_t)r*MM + mq + m8);
        }
        if (tid < 64) Ss[64*LDQ + tid] = __float2bfloat16(skrow[mq + tid]);
        __syncthreads();
#pragma unroll
        for (int ks = 0; ks < 2; ++ks) {
            const int ko = ks*32 + l4*8;
            short8 aF = *(const short8*)&Qs[(w*16 + l15)*LDQ + ko];
#pragma unroll
            for (int nt = 0; nt < 4; ++nt) {
                short8 bF = *(const short8*)&Ks[(nt*16 + l15)*LDQ + ko];
                accA[nt] = __builtin_amdgcn_mfma_f32_16x16x32_bf16(aF, bF, accA[nt], 0, 0, 0);
            }
#pragma unroll
            for (int nt = 0; nt < 5; ++nt) {
                short8 sF = *(const short8*)&Ss[(nt*16 + l15)*LDQ + ko];
                accO[nt] = __builtin_amdgcn_mfma_f32_16x16x32_bf16(aF, sF, accO[nt], 0, 0, 0);
            }
        }
    }
    __syncthreads();
#pragma unroll
    for (int nt = 0; nt < 4; ++nt) {
        const int s = nt*16 + l15;
#pragma unroll
        for (int j = 0; j < 4; ++j) {
            const int t = w*16 + l4*4 + j;
            const float v = (s <= t) ? accA[nt][j] : 0.f;
            Al[t*LDA + s] = __float2bfloat16(v);
        }
    }
    __syncthreads();
#pragma unroll
    for (int ks = 0; ks < 2; ++ks) {
        const int ko = ks*32 + l4*8;
        short8 aF = *(const short8*)&Al[(w*16 + l15)*LDA + ko];
#pragma unroll
        for (int nt = 0; nt < 5; ++nt) {
            short8 vF = *(const short8*)&Vl[(nt*16 + l15)*LDA + ko];
            accO[nt] = __builtin_amdgcn_mfma_f32_16x16x32_bf16(aF, vF, accO[nt], 0, 0, 0);
        }
    }
    __hip_bfloat16* arow = attn + ((size_t)b*LL + (size_t)c*TT) * DIMM + h*DD;
#pragma unroll
    for (int j = 0; j < 4; ++j) {
        const float den = __shfl(accO[4][j], (lane & 48));
        const float inv = 1.0f / den;
        const int t = w*16 + l4*4 + j;
#pragma unroll
        for (int nt = 0; nt < 4; ++nt) {
            const int d = nt*16 + l15;
            arow[(size_t)t*DIMM + d] = __float2bfloat16(accO[nt][j] * inv);
        }
    }
}

// ---------------------------------------------------------------------------
extern "C" void kernel_launch(void* const* d_in, const int* in_sizes, int n_in,
                              void* d_out, int out_size, void* d_ws, size_t ws_size,
                              hipStream_t stream)
{
    (void)in_sizes; (void)n_in; (void)out_size; (void)ws_size;
    const float* query = (const float*)d_in[0];
    const float* key   = (const float*)d_in[1];
    const float* value = (const float*)d_in[2];
    const float* Wq = (const float*)d_in[3];
    const float* bq = (const float*)d_in[4];
    const float* Wk = (const float*)d_in[5];
    const float* bk = (const float*)d_in[6];
    const float* Wv = (const float*)d_in[7];
    const float* bv = (const float*)d_in[8];
    const float* Wo = (const float*)d_in[9];
    const float* bo = (const float*)d_in[10];
    const float* proj = (const float*)d_in[11];

    float* ws = (float*)d_ws;
    // Workspace peak ~244.3 MB (f32-word offsets). No overlays needed.
    float* ddk            = ws;                                  // [0, 16,777,216)
    __hip_bfloat16* kpT_b = (__hip_bfloat16*)(ws + 16777216);    // 16.7M bf16
    __hip_bfloat16* qp_b  = (__hip_bfloat16*)(ws + 25165824);    // 16.7M bf16
    __hip_bfloat16* kp_b  = (__hip_bfloat16*)(ws + 33554432);    // 16.7M bf16
    __hip_bfloat16* ScT_b = (__hip_bfloat16*)(ws + 41943040);    // 16.7M bf16
    float* vw             = ws + 50331648;                       // 4,194,304 f32
    __hip_bfloat16* vT_b  = (__hip_bfloat16*)(ws + 54525952);    // 4.2M bf16
    __hip_bfloat16* qsb   = (__hip_bfloat16*)(ws + 56623104);    // 4.2M bf16; attn_b overlays
    __hip_bfloat16* ksb   = (__hip_bfloat16*)(ws + 58720256);    // 4.2M bf16
    float* skc            = ws + 60817408;                       // 262,144 f32
    float* part           = ws + 61079552;                       // 1024
    float* gmax           = ws + 61080576;                       // 1
    __hip_bfloat16* attn_b = qsb;   // qsb dead after feat_gemm_q

    const dim3 blk(256);

    // projections (f32 operands staged->bf16 in-kernel): q/k scaled -> bf16; v -> f32 scattered
    gemm_bf16<512,0,__hip_bfloat16,float,float,false><<<dim3(4,64), blk, 0, stream>>>(query, Wq, bq, qsb, K_SCALE, nullptr);
    gemm_bf16<512,0,__hip_bfloat16,float,float,false><<<dim3(4,64), blk, 0, stream>>>(key,   Wk, bk, ksb, K_SCALE, nullptr);
    gemm_bf16<512,1,float,float,float,false><<<dim3(4,64), blk, 0, stream>>>(value, Wv, bv, vw, 1.0f, nullptr);

    // v transpose -> bf16 [B,H,D,L]
    transpose_v_kernel<<<dim3(32,32), blk, 0, stream>>>(vw, vT_b);

    // Q path: fused feature GEMM + softmax-map -> qp_b
    feat_gemm_q_kernel<<<512, dim3(512), 0, stream>>>(qsb, proj, qp_b);

    // K path: feature GEMM (dd f32) + fused block max
    gemm_bf16<64,2,float,__hip_bfloat16,float,true><<<dim3(2,512), blk, 0, stream>>>(ksb, proj, nullptr, ddk, 1.0f, part);
    kmax_final_kernel<<<1, blk, 0, stream>>>(part, gmax);
    feat_post_k_kernel<<<dim3(32,32), blk, 0, stream>>>(ddk, ksb, gmax, kp_b, kpT_b);

    // fused chunk state + exclusive prefix (MFMA)
    chunk_state_mfma_kernel<<<dim3(4,32), blk, 0, stream>>>(kpT_b, vT_b, ScT_b, skc);

    // chunk output
    chunk_out_kernel<<<dim3(NCHUNK,HH,BB), blk, 0, stream>>>(qp_b, kp_b, vT_b, ScT_b, skc, attn_b);

    // output projection
    gemm_bf16<512,0,float,__hip_bfloat16,float,false><<<dim3(4,64), blk, 0, stream>>>(attn_b, Wo, bo, (float*)d_out, 1.0f, nullptr);
}

// Round 6
// 198.305 us; speedup vs baseline: 3.4620x; 1.2679x over previous
//
#include <hip/hip_runtime.h>
#include <hip/hip_bf16.h>
#include <math.h>

// Problem constants
#define BB 4
#define LL 2048
#define HH 8
#define DD 64          // head dim
#define MM 256         // nb_features
#define DIMM 512
#define TT 64          // chunk length
#define NCHUNK (LL/TT) // 32

constexpr float K_SCALE = 0.35355339059327379f; // 64^-0.25
constexpr float K_RATIO = 0.0625f;              // 256^-0.5
constexpr float K_EPS   = 1e-6f;

using short8 = __attribute__((ext_vector_type(8))) short;
using f32x4  = __attribute__((ext_vector_type(4))) float;
typedef _Float16 f16_t;

__device__ inline unsigned short f2b_u16(float x) {
    __hip_bfloat16 h = __float2bfloat16(x);
    return *reinterpret_cast<unsigned short*>(&h);
}
__device__ inline ushort4 f2b4(float4 v) {
    ushort4 o; o.x = f2b_u16(v.x); o.y = f2b_u16(v.y); o.z = f2b_u16(v.z); o.w = f2b_u16(v.w);
    return o;
}
__device__ inline unsigned short f2h_u16(float x) {
    f16_t h = (f16_t)x;
    return *reinterpret_cast<unsigned short*>(&h);
}
__device__ inline float h2f(unsigned short u) {
    f16_t h = *reinterpret_cast<f16_t*>(&u);
    return (float)h;
}

template<typename T> __device__ inline T f2o(float v);
template<> __device__ inline float f2o<float>(float v) { return v; }
template<> __device__ inline __hip_bfloat16 f2o<__hip_bfloat16>(float v) { return __float2bfloat16(v); }

// XOR-swizzled byte offset into the chunk_state kT tile ([m][t] bf16, row
// stride 72 elems = 144B). Swizzle spreads the 8-m-stride (1152B == 0 mod
// 128B) transposed reads across distinct 16B slots; 16B-aligned accesses
// stay aligned (XOR touches bits 4-5 only).
#define KSWZ(m, te) ((((m)*144) + ((te)*2)) ^ ((((m)>>3) & 3) << 4))

// ---------------------------------------------------------------------------
// bf16 MFMA GEMM: Y = X[MR,K] @ W[N,K]^T (+bias) * postscale, OT out.
// XT/WT in {float, bf16}: f32 operands converted during LDS staging.
// Tile 128x128, BK=64, 4 waves (2x2), each wave 64x64. (layout verified r2)
// MODE 0: row-major [MR,512]
// MODE 1: scatter out[((b*H+h)*L+l)*64+d]  (r=b*L+l, c=h*64+d)
// ---------------------------------------------------------------------------
template<int KDIM, int MODE, typename OT, typename XT, typename WT>
__global__ __launch_bounds__(256)
void gemm_bf16(const XT* __restrict__ X, const WT* __restrict__ W,
               const float* __restrict__ bias, OT* __restrict__ out, float postscale)
{
    constexpr int LDT = 72;
    __shared__ __hip_bfloat16 As[128*LDT];
    __shared__ __hip_bfloat16 Bs[128*LDT];
    const int tid = threadIdx.x;
    const int lane = tid & 63;
    const int w = tid >> 6;
    const int wm = (w >> 1) * 64, wn = (w & 1) * 64;
    const int row0 = blockIdx.y * 128, col0 = blockIdx.x * 128;
    const int l15 = lane & 15, l4 = lane >> 4;

    f32x4 acc[4][4];
#pragma unroll
    for (int mt = 0; mt < 4; ++mt)
#pragma unroll
        for (int nt = 0; nt < 4; ++nt) {
            f32x4 z = {0.f, 0.f, 0.f, 0.f};
            acc[mt][nt] = z;
        }

    for (int k0 = 0; k0 < KDIM; k0 += 64) {
        if constexpr (sizeof(XT) == 4) {
#pragma unroll
            for (int i = 0; i < 8; ++i) {
                int lin = i*256 + tid;
                int r = lin >> 4, kc = (lin & 15)*4;
                float4 a = *(const float4*)(X + (size_t)(row0 + r)*KDIM + k0 + kc);
                *(ushort4*)&As[r*LDT + kc] = f2b4(a);
            }
        } else {
#pragma unroll
            for (int i = 0; i < 4; ++i) {
                int lin = i*256 + tid;
                int r = lin >> 3, kc = (lin & 7)*8;
                *(uint4*)&As[r*LDT + kc] = *(const uint4*)(X + (size_t)(row0 + r)*KDIM + k0 + kc);
            }
        }
        if constexpr (sizeof(WT) == 4) {
#pragma unroll
            for (int i = 0; i < 8; ++i) {
                int lin = i*256 + tid;
                int r = lin >> 4, kc = (lin & 15)*4;
                float4 b = *(const float4*)(W + (size_t)(col0 + r)*KDIM + k0 + kc);
                *(ushort4*)&Bs[r*LDT + kc] = f2b4(b);
            }
        } else {
#pragma unroll
            for (int i = 0; i < 4; ++i) {
                int lin = i*256 + tid;
                int r = lin >> 3, kc = (lin & 7)*8;
                *(uint4*)&Bs[r*LDT + kc] = *(const uint4*)(W + (size_t)(col0 + r)*KDIM + k0 + kc);
            }
        }
        __syncthreads();
#pragma unroll
        for (int ks = 0; ks < 2; ++ks) {
            const int koff = ks*32 + l4*8;
            short8 aF[4], bF[4];
#pragma unroll
            for (int mt = 0; mt < 4; ++mt)
                aF[mt] = *(const short8*)&As[(wm + mt*16 + l15)*LDT + koff];
#pragma unroll
            for (int nt = 0; nt < 4; ++nt)
                bF[nt] = *(const short8*)&Bs[(wn + nt*16 + l15)*LDT + koff];
#pragma unroll
            for (int mt = 0; mt < 4; ++mt)
#pragma unroll
                for (int nt = 0; nt < 4; ++nt)
                    acc[mt][nt] = __builtin_amdgcn_mfma_f32_16x16x32_bf16(aF[mt], bF[nt], acc[mt][nt], 0, 0, 0);
        }
        __syncthreads();
    }

#pragma unroll
    for (int mt = 0; mt < 4; ++mt) {
#pragma unroll
        for (int nt = 0; nt < 4; ++nt) {
            const int c = col0 + wn + nt*16 + l15;
            const float bval = bias[c];
#pragma unroll
            for (int j = 0; j < 4; ++j) {
                const int r = row0 + wm + mt*16 + l4*4 + j;
                const float val = (acc[mt][nt][j] + bval) * postscale;
                if (MODE == 0) {
                    out[(size_t)r*DIMM + c] = f2o<OT>(val);
                } else {
                    const int b = r >> 11, l = r & 2047;
                    const int hh = c >> 6, d = c & 63;
                    out[(((size_t)b*HH + hh)*LL + l)*DD + d] = f2o<OT>(val);
                }
            }
        }
    }
}

// ---------------------------------------------------------------------------
// Fused Q feature map: qp = RATIO*(exp(X@P^T - diag - rowmax) + EPS), bf16.
// X = qsb [65536,64] bf16; P = proj [256,64] f32. (verified round 5)
// BM=128, BN=256(=all M -> rowmax block-local), 512 threads = 8 waves 2x4.
// ---------------------------------------------------------------------------
__global__ __launch_bounds__(512)
void feat_gemm_q_kernel(const __hip_bfloat16* __restrict__ X, const float* __restrict__ P,
                        __hip_bfloat16* __restrict__ qp_b)
{
    constexpr int LDT = 72;
    __shared__ __hip_bfloat16 As[128*LDT];
    __shared__ __hip_bfloat16 Bs[256*LDT];
    __shared__ float rowmax[128][4];
    __shared__ float diagl[128];
    const int tid = threadIdx.x;
    const int lane = tid & 63, w = tid >> 6;
    const int wr = w >> 2, wc = w & 3;
    const int l15 = lane & 15, l4 = lane >> 4;
    const int row0 = blockIdx.x * 128;

#pragma unroll
    for (int i = 0; i < 2; ++i) {
        int lin = i*512 + tid;
        int r = lin >> 3, kc = (lin & 7)*8;
        *(uint4*)&As[r*LDT + kc] = *(const uint4*)(X + (size_t)(row0 + r)*64 + kc);
    }
#pragma unroll
    for (int i = 0; i < 8; ++i) {
        int lin = i*512 + tid;
        int r = lin >> 4, kc = (lin & 15)*4;
        float4 v = *(const float4*)(P + (size_t)r*64 + kc);
        *(ushort4*)&Bs[r*LDT + kc] = f2b4(v);
    }
    __syncthreads();

    f32x4 acc[4][4];
#pragma unroll
    for (int mt = 0; mt < 4; ++mt)
#pragma unroll
        for (int nt = 0; nt < 4; ++nt) {
            f32x4 z = {0.f,0.f,0.f,0.f};
            acc[mt][nt] = z;
        }
#pragma unroll
    for (int ks = 0; ks < 2; ++ks) {
        const int ko = ks*32 + l4*8;
        short8 aF[4], bF[4];
#pragma unroll
        for (int mt = 0; mt < 4; ++mt)
            aF[mt] = *(const short8*)&As[(wr*64 + mt*16 + l15)*LDT + ko];
#pragma unroll
        for (int nt = 0; nt < 4; ++nt)
            bF[nt] = *(const short8*)&Bs[(wc*64 + nt*16 + l15)*LDT + ko];
#pragma unroll
        for (int mt = 0; mt < 4; ++mt)
#pragma unroll
            for (int nt = 0; nt < 4; ++nt)
                acc[mt][nt] = __builtin_amdgcn_mfma_f32_16x16x32_bf16(aF[mt], bF[nt], acc[mt][nt], 0, 0, 0);
    }

    {
        const int r = tid >> 2, q = tid & 3;
        float s = 0.f;
#pragma unroll
        for (int i = 0; i < 16; ++i) {
            float x = __bfloat162float(As[r*LDT + q*16 + i]);
            s += x*x;
        }
        s += __shfl_xor(s, 1);
        s += __shfl_xor(s, 2);
        if (q == 0) diagl[r] = 0.5f * s;
    }
#pragma unroll
    for (int mt = 0; mt < 4; ++mt)
#pragma unroll
        for (int j = 0; j < 4; ++j) {
            float m = fmaxf(fmaxf(acc[mt][0][j], acc[mt][1][j]),
                            fmaxf(acc[mt][2][j], acc[mt][3][j]));
#pragma unroll
            for (int off = 8; off > 0; off >>= 1) m = fmaxf(m, __shfl_xor(m, off));
            if (l15 == 0) rowmax[wr*64 + mt*16 + l4*4 + j][wc] = m;
        }
    __syncthreads();

#pragma unroll
    for (int mt = 0; mt < 4; ++mt)
#pragma unroll
        for (int j = 0; j < 4; ++j) {
            const int r = wr*64 + mt*16 + l4*4 + j;
            const float stab = fmaxf(fmaxf(rowmax[r][0], rowmax[r][1]),
                                     fmaxf(rowmax[r][2], rowmax[r][3]));
            const float cc = diagl[r] + stab;
            const int gr = row0 + r;
            const int bl = gr >> 3, h = gr & 7;
            const int b = bl >> 11, l = bl & 2047;
            const size_t base = (((size_t)b*HH + h)*LL + l)*MM;
#pragma unroll
            for (int nt = 0; nt < 4; ++nt)
                qp_b[base + wc*64 + nt*16 + l15] =
                    __float2bfloat16(K_RATIO * (__expf(acc[mt][nt][j] - cc) + K_EPS));
        }
}

// ---------------------------------------------------------------------------
// K feature GEMM, TRANSPOSED f16 output with diag folded:
//   ddT[bh][m][l] = (X_bh @ P^T)[l][m] - diag[l]   (f16)
// X = ksw_b [bh][2048][64] bf16; also emits per-block max of RAW dd -> part.
// BM=128(l), BN=256(all m), 512 threads = 8 waves (2 row x 4 col).
// ---------------------------------------------------------------------------
__global__ __launch_bounds__(512)
void feat_gemm_kT_kernel(const __hip_bfloat16* __restrict__ X, const float* __restrict__ P,
                         unsigned short* __restrict__ ddT, float* __restrict__ part)
{
    constexpr int LDT = 72;
    __shared__ __hip_bfloat16 As[128*LDT];
    __shared__ __hip_bfloat16 Bs[256*LDT];
    __shared__ float diagl[128];
    __shared__ float wmx[8];
    const int tid = threadIdx.x;
    const int lane = tid & 63, w = tid >> 6;
    const int wr = w >> 2, wc = w & 3;
    const int l15 = lane & 15, l4 = lane >> 4;
    const int bh = blockIdx.y;
    const int l0 = blockIdx.x * 128;

#pragma unroll
    for (int i = 0; i < 2; ++i) {
        int lin = i*512 + tid;
        int r = lin >> 3, kc = (lin & 7)*8;
        *(uint4*)&As[r*LDT + kc] = *(const uint4*)(X + ((size_t)bh*LL + l0 + r)*64 + kc);
    }
#pragma unroll
    for (int i = 0; i < 8; ++i) {
        int lin = i*512 + tid;
        int r = lin >> 4, kc = (lin & 15)*4;
        float4 v = *(const float4*)(P + (size_t)r*64 + kc);
        *(ushort4*)&Bs[r*LDT + kc] = f2b4(v);
    }
    __syncthreads();

    f32x4 acc[4][4];
#pragma unroll
    for (int mt = 0; mt < 4; ++mt)
#pragma unroll
        for (int nt = 0; nt < 4; ++nt) {
            f32x4 z = {0.f,0.f,0.f,0.f};
            acc[mt][nt] = z;
        }
#pragma unroll
    for (int ks = 0; ks < 2; ++ks) {
        const int ko = ks*32 + l4*8;
        short8 aF[4], bF[4];
#pragma unroll
        for (int mt = 0; mt < 4; ++mt)
            aF[mt] = *(const short8*)&As[(wr*64 + mt*16 + l15)*LDT + ko];
#pragma unroll
        for (int nt = 0; nt < 4; ++nt)
            bF[nt] = *(const short8*)&Bs[(wc*64 + nt*16 + l15)*LDT + ko];
#pragma unroll
        for (int mt = 0; mt < 4; ++mt)
#pragma unroll
            for (int nt = 0; nt < 4; ++nt)
                acc[mt][nt] = __builtin_amdgcn_mfma_f32_16x16x32_bf16(aF[mt], bF[nt], acc[mt][nt], 0, 0, 0);
    }

    // diag from staged A rows
    {
        const int r = tid >> 2, q = tid & 3;
        float s = 0.f;
#pragma unroll
        for (int i = 0; i < 16; ++i) {
            float x = __bfloat162float(As[r*LDT + q*16 + i]);
            s += x*x;
        }
        s += __shfl_xor(s, 1);
        s += __shfl_xor(s, 2);
        if (q == 0) diagl[r] = 0.5f * s;
    }
    // block max of RAW dd (matches reference stab = max(dd))
    {
        float mx = -3.0e38f;
#pragma unroll
        for (int mt = 0; mt < 4; ++mt)
#pragma unroll
            for (int nt = 0; nt < 4; ++nt)
#pragma unroll
                for (int j = 0; j < 4; ++j)
                    mx = fmaxf(mx, acc[mt][nt][j]);
#pragma unroll
        for (int off = 32; off > 0; off >>= 1) mx = fmaxf(mx, __shfl_xor(mx, off));
        if (lane == 0) wmx[w] = mx;
    }
    __syncthreads();
    if (tid == 0) {
        float mx = wmx[0];
#pragma unroll
        for (int i = 1; i < 8; ++i) mx = fmaxf(mx, wmx[i]);
        part[blockIdx.y*16 + blockIdx.x] = mx;
    }

    // transposed epilogue: 4 consecutive l per lane -> 8B f16 stores
#pragma unroll
    for (int mt = 0; mt < 4; ++mt) {
#pragma unroll
        for (int nt = 0; nt < 4; ++nt) {
            const int m = wc*64 + nt*16 + l15;
            const int rbase = wr*64 + mt*16 + l4*4;
            ushort4 o;
            o.x = f2h_u16(acc[mt][nt][0] - diagl[rbase+0]);
            o.y = f2h_u16(acc[mt][nt][1] - diagl[rbase+1]);
            o.z = f2h_u16(acc[mt][nt][2] - diagl[rbase+2]);
            o.w = f2h_u16(acc[mt][nt][3] - diagl[rbase+3]);
            *(ushort4*)(ddT + ((size_t)bh*MM + m)*LL + l0 + rbase) = o;
        }
    }
}

__global__ __launch_bounds__(256)
void kmax_final_kernel(const float* __restrict__ part, float* __restrict__ gmax)
{
    float mx = -3.0e38f;
    for (int i = threadIdx.x; i < 512; i += 256) mx = fmaxf(mx, part[i]);
#pragma unroll
    for (int off = 32; off > 0; off >>= 1) mx = fmaxf(mx, __shfl_xor(mx, off));
    __shared__ float wsm[4];
    if ((threadIdx.x & 63) == 0) wsm[threadIdx.x >> 6] = mx;
    __syncthreads();
    if (threadIdx.x == 0) gmax[0] = fmaxf(fmaxf(wsm[0], wsm[1]), fmaxf(wsm[2], wsm[3]));
}

// ---------------------------------------------------------------------------
// vw [B,H,L,D] f32  ->  vT [B,H,D,L] bf16  (tiled LDS transpose)
// ---------------------------------------------------------------------------
__global__ __launch_bounds__(256)
void transpose_v_kernel(const float* __restrict__ vw, __hip_bfloat16* __restrict__ vT)
{
    __shared__ float vl[64][65];
    const int bh = blockIdx.y;
    const int l0 = blockIdx.x*64;
    const float* src = vw + ((size_t)bh*LL + l0)*DD;
#pragma unroll
    for (int it = 0; it < 4; ++it) {
        int lin = it*256 + threadIdx.x;
        int t = lin >> 4, d4 = (lin & 15)*4;
        float4 v = *(const float4*)(src + (size_t)t*DD + d4);
        vl[t][d4+0]=v.x; vl[t][d4+1]=v.y; vl[t][d4+2]=v.z; vl[t][d4+3]=v.w;
    }
    __syncthreads();
    const int d = threadIdx.x >> 2, q = threadIdx.x & 3;
    __hip_bfloat16* dst = vT + ((size_t)bh*DD + d)*LL + l0 + q*16;
#pragma unroll
    for (int g = 0; g < 4; ++g) {
        ushort4 o;
        o.x = f2b_u16(vl[q*16+g*4+0][d]);
        o.y = f2b_u16(vl[q*16+g*4+1][d]);
        o.z = f2b_u16(vl[q*16+g*4+2][d]);
        o.w = f2b_u16(vl[q*16+g*4+3][d]);
        *(ushort4*)(dst + g*4) = o;
    }
}

// ---------------------------------------------------------------------------
// Fused K-feature-exp + chunk state + exclusive prefix + kp_b emit.
// Per block (mb, bh): iterate chunks serially. Per chunk:
//   - stage kT tile [m][t] (XOR-swizzled) from ddT f16: kp=RATIO*(exp(v-gmax)+EPS)
//   - stage vT tile [d][t]
//   - write exclusive prefix ScT_b (from MFMA accumulators), skc
//   - MFMA: accS[d-tiles] += vT x kT ; accK += ones x kT
//   - emit kp_b [t][m] (transposed LDS read, coalesced global write)
// ---------------------------------------------------------------------------
__global__ __launch_bounds__(256)
void chunk_state_mfma_kernel(const unsigned short* __restrict__ ddT,
                             const __hip_bfloat16* __restrict__ vT_b,
                             const float* __restrict__ gmax,
                             __hip_bfloat16* __restrict__ ScT_b,
                             float* __restrict__ skc,
                             __hip_bfloat16* __restrict__ kp_b)
{
    __shared__ __hip_bfloat16 kT[2][64*72];
    __shared__ __hip_bfloat16 vT[2][64*72];
    const int mb = blockIdx.x, bh = blockIdx.y;
    const int tid = threadIdx.x, lane = tid & 63, w = tid >> 6;
    const int l15 = lane & 15, l4 = lane >> 4;
    const int sr = tid >> 2, sq = tid & 3;
    const float gm = gmax[0];
    const unsigned short* ksrc = ddT + ((size_t)bh*MM + mb*64 + sr)*LL + sq*16;
    const __hip_bfloat16*  vsrc = vT_b + ((size_t)bh*DD + sr)*LL + sq*16;

    f32x4 accS[4];
    f32x4 accK;
#pragma unroll
    for (int i = 0; i < 4; ++i) { f32x4 z = {0.f,0.f,0.f,0.f}; accS[i] = z; }
    { f32x4 z = {0.f,0.f,0.f,0.f}; accK = z; }

    short8 ones8;
    {
        const short ov = (short)0x3F80;   // bf16 1.0
#pragma unroll
        for (int i = 0; i < 8; ++i) ones8[i] = (l15 == 0) ? ov : (short)0;
    }

    // staging helper behavior (inlined twice): read 16 f16, exp, write swizzled
#define STAGE_CHUNK(CC, BUFI)                                                        \
    {                                                                                \
        const size_t off = (size_t)(CC) * 64;                                        \
        uint4 r0 = *(const uint4*)(ksrc + off);                                      \
        uint4 r1 = *(const uint4*)(ksrc + off + 8);                                  \
        const unsigned short* u0 = (const unsigned short*)&r0;                       \
        const unsigned short* u1 = (const unsigned short*)&r1;                       \
        unsigned short p0[8], p1[8];                                                 \
        _Pragma("unroll")                                                            \
        for (int i = 0; i < 8; ++i) {                                                \
            p0[i] = f2b_u16(K_RATIO * (__expf(h2f(u0[i]) - gm) + K_EPS));            \
            p1[i] = f2b_u16(K_RATIO * (__expf(h2f(u1[i]) - gm) + K_EPS));            \
        }                                                                            \
        char* kb = (char*)&kT[BUFI][0];                                              \
        *(uint4*)(kb + KSWZ(sr, sq*16))     = *(uint4*)&p0[0];                       \
        *(uint4*)(kb + KSWZ(sr, sq*16 + 8)) = *(uint4*)&p1[0];                       \
        *(uint4*)((char*)&vT[BUFI][0] + sr*144 + sq*32)      = *(const uint4*)(vsrc + off);     \
        *(uint4*)((char*)&vT[BUFI][0] + sr*144 + sq*32 + 16) = *(const uint4*)(vsrc + off + 8); \
    }

    STAGE_CHUNK(0, 0)

    for (int c = 0; c < NCHUNK; ++c) {
        // exclusive prefix write from accumulators
        __hip_bfloat16* So = ScT_b + ((size_t)(bh*NCHUNK + c))*(MM*DD);
        const int mcol = mb*64 + w*16 + l15;
#pragma unroll
        for (int dt = 0; dt < 4; ++dt)
#pragma unroll
            for (int j = 0; j < 4; ++j)
                So[(size_t)(dt*16 + l4*4 + j)*MM + mcol] = __float2bfloat16(accS[dt][j]);
        if (l4 == 0)
            skc[((size_t)bh*NCHUNK + c)*MM + mcol] = accK[0];

        __syncthreads();   // stage(c) visible; prior-buf readers done
        if (c + 1 < NCHUNK) {
            const int nb = (c + 1) & 1;
            STAGE_CHUNK(c + 1, nb)
        }
        const int buf = c & 1;
        char* kbuf = (char*)&kT[buf][0];
        char* vbuf = (char*)&vT[buf][0];
#pragma unroll
        for (int ks = 0; ks < 2; ++ks) {
            const int ko = ks*32 + l4*8;
            short8 bF = *(const short8*)(kbuf + KSWZ(w*16 + l15, ko));
#pragma unroll
            for (int dt = 0; dt < 4; ++dt) {
                short8 aF = *(const short8*)(vbuf + (dt*16 + l15)*144 + ko*2);
                accS[dt] = __builtin_amdgcn_mfma_f32_16x16x32_bf16(aF, bF, accS[dt], 0, 0, 0);
            }
            accK = __builtin_amdgcn_mfma_f32_16x16x32_bf16(ones8, bF, accK, 0, 0, 0);
        }
        // emit kp_b [t][m]: per wave 16 t-rows; 4 lanes x 16 m = 128B/row-chunk
        {
            const int t2 = w*16 + (lane >> 2);
            const int m0 = (lane & 3)*16;
            unsigned short vals[16];
#pragma unroll
            for (int i = 0; i < 16; ++i)
                vals[i] = *(const unsigned short*)(kbuf + KSWZ(m0 + i, t2));
            __hip_bfloat16* krow = kp_b + ((size_t)bh*LL + (size_t)c*64 + t2)*MM + mb*64 + m0;
            *(uint4*)krow       = *(uint4*)&vals[0];
            *(uint4*)(krow + 8) = *(uint4*)&vals[8];
        }
    }
#undef STAGE_CHUNK
}

// ---------------------------------------------------------------------------
// MFMA chunk_out (verified round 4): per (b,h,c):
//   A = Qp Kp^T (K=256), mask s<=t -> Al bf16
//   O = Al @ [V;1] + Qp @ [S_prev; sk_prev]   (den rides as column 64)
//   attn[b, c*64+t, h*64+d] = O/den  (bf16)
// ---------------------------------------------------------------------------
__global__ __launch_bounds__(256)
void chunk_out_kernel(const __hip_bfloat16* __restrict__ qp_b,
                      const __hip_bfloat16* __restrict__ kp_b,
                      const __hip_bfloat16* __restrict__ vT_b,
                      const __hip_bfloat16* __restrict__ ScT_b,
                      const float* __restrict__ skp,
                      __hip_bfloat16* __restrict__ attn)
{
    constexpr int LDQ = 72;
    constexpr int LDA = 72;
    __shared__ __hip_bfloat16 Qs[64*LDQ];
    __shared__ __hip_bfloat16 Ks[64*LDQ];
    __shared__ __hip_bfloat16 Ss[80*LDQ];
    __shared__ __hip_bfloat16 Al[64*LDA];
    __shared__ __hip_bfloat16 Vl[80*LDA];

    const int c = blockIdx.x, h = blockIdx.y, b = blockIdx.z;
    const size_t bh = (size_t)b*HH + h;
    const __hip_bfloat16* qpc = qp_b + (bh*LL + (size_t)c*TT) * MM;
    const __hip_bfloat16* kpc = kp_b + (bh*LL + (size_t)c*TT) * MM;
    const __hip_bfloat16* vTc = vT_b + bh*(size_t)(DD*LL) + (size_t)c*TT;
    const __hip_bfloat16* Scc = ScT_b + (bh*NCHUNK + (size_t)c) * (MM*DD);
    const float* skrow = skp + (bh*NCHUNK + (size_t)c) * MM;

    const int tid = threadIdx.x;
    const int lane = tid & 63;
    const int w = tid >> 6;
    const int l15 = lane & 15, l4 = lane >> 4;

    {
#pragma unroll
        for (int it = 0; it < 2; ++it) {
            int lin = it*256 + tid;
            int d = lin >> 3, c8 = (lin & 7)*8;
            *(uint4*)&Vl[d*LDA + c8] = *(const uint4*)(vTc + (size_t)d*LL + c8);
        }
        const __hip_bfloat16 one = __float2bfloat16(1.0f);
        const __hip_bfloat16 zero = __float2bfloat16(0.0f);
        for (int idx = tid; idx < 16*64; idx += 256) {
            int rr = idx >> 6, cc2 = idx & 63;
            Vl[(64+rr)*LDA + cc2] = (rr == 0) ? one : zero;
        }
        for (int idx = tid; idx < 15*64; idx += 256) {
            int rr = idx / 64, cc2 = idx % 64;
            Ss[(65+rr)*LDQ + cc2] = zero;
        }
    }

    f32x4 accA[4];
    f32x4 accO[5];
#pragma unroll
    for (int i = 0; i < 4; ++i) { f32x4 z = {0.f,0.f,0.f,0.f}; accA[i] = z; }
#pragma unroll
    for (int i = 0; i < 5; ++i) { f32x4 z = {0.f,0.f,0.f,0.f}; accO[i] = z; }

    for (int mq = 0; mq < MM; mq += 64) {
        __syncthreads();
#pragma unroll
        for (int it = 0; it < 2; ++it) {
            int lin = it*256 + tid;
            int r = lin >> 3, m8 = (lin & 7)*8;
            *(uint4*)&Qs[r*LDQ + m8] = *(const uint4*)(qpc + (size_t)r*MM + mq + m8);
            *(uint4*)&Ks[r*LDQ + m8] = *(const uint4*)(kpc + (size_t)r*MM + mq + m8);
            *(uint4*)&Ss[r*LDQ + m8] = *(const uint4*)(Scc + (size_t)r*MM + mq + m8);
        }
        if (tid < 64) Ss[64*LDQ + tid] = __float2bfloat16(skrow[mq + tid]);
        __syncthreads();
#pragma unroll
        for (int ks = 0; ks < 2; ++ks) {
            const int ko = ks*32 + l4*8;
            short8 aF = *(const short8*)&Qs[(w*16 + l15)*LDQ + ko];
#pragma unroll
            for (int nt = 0; nt < 4; ++nt) {
                short8 bF = *(const short8*)&Ks[(nt*16 + l15)*LDQ + ko];
                accA[nt] = __builtin_amdgcn_mfma_f32_16x16x32_bf16(aF, bF, accA[nt], 0, 0, 0);
            }
#pragma unroll
            for (int nt = 0; nt < 5; ++nt) {
                short8 sF = *(const short8*)&Ss[(nt*16 + l15)*LDQ + ko];
                accO[nt] = __builtin_amdgcn_mfma_f32_16x16x32_bf16(aF, sF, accO[nt], 0, 0, 0);
            }
        }
    }
    __syncthreads();
#pragma unroll
    for (int nt = 0; nt < 4; ++nt) {
        const int s = nt*16 + l15;
#pragma unroll
        for (int j = 0; j < 4; ++j) {
            const int t = w*16 + l4*4 + j;
            const float v = (s <= t) ? accA[nt][j] : 0.f;
            Al[t*LDA + s] = __float2bfloat16(v);
        }
    }
    __syncthreads();
#pragma unroll
    for (int ks = 0; ks < 2; ++ks) {
        const int ko = ks*32 + l4*8;
        short8 aF = *(const short8*)&Al[(w*16 + l15)*LDA + ko];
#pragma unroll
        for (int nt = 0; nt < 5; ++nt) {
            short8 vF = *(const short8*)&Vl[(nt*16 + l15)*LDA + ko];
            accO[nt] = __builtin_amdgcn_mfma_f32_16x16x32_bf16(aF, vF, accO[nt], 0, 0, 0);
        }
    }
    __hip_bfloat16* arow = attn + ((size_t)b*LL + (size_t)c*TT) * DIMM + h*DD;
#pragma unroll
    for (int j = 0; j < 4; ++j) {
        const float den = __shfl(accO[4][j], (lane & 48));
        const float inv = 1.0f / den;
        const int t = w*16 + l4*4 + j;
#pragma unroll
        for (int nt = 0; nt < 4; ++nt) {
            const int d = nt*16 + l15;
            arow[(size_t)t*DIMM + d] = __float2bfloat16(accO[nt][j] * inv);
        }
    }
}

// ---------------------------------------------------------------------------
extern "C" void kernel_launch(void* const* d_in, const int* in_sizes, int n_in,
                              void* d_out, int out_size, void* d_ws, size_t ws_size,
                              hipStream_t stream)
{
    (void)in_sizes; (void)n_in; (void)out_size; (void)ws_size;
    const float* query = (const float*)d_in[0];
    const float* key   = (const float*)d_in[1];
    const float* value = (const float*)d_in[2];
    const float* Wq = (const float*)d_in[3];
    const float* bq = (const float*)d_in[4];
    const float* Wk = (const float*)d_in[5];
    const float* bk = (const float*)d_in[6];
    const float* Wv = (const float*)d_in[7];
    const float* bv = (const float*)d_in[8];
    const float* Wo = (const float*)d_in[9];
    const float* bo = (const float*)d_in[10];
    const float* proj = (const float*)d_in[11];

    float* ws = (float*)d_ws;
    // Workspace peak ~178 MB (f32-word offsets). No overlays except attn_b<-qsb.
    unsigned short* ddT   = (unsigned short*)ws;                 // 16.7M f16  [bh][m][l]
    __hip_bfloat16* qp_b  = (__hip_bfloat16*)(ws +  8388608);    // 16.7M bf16
    __hip_bfloat16* kp_b  = (__hip_bfloat16*)(ws + 16777216);    // 16.7M bf16
    __hip_bfloat16* ScT_b = (__hip_bfloat16*)(ws + 25165824);    // 16.7M bf16
    float* vw             = ws + 33554432;                       // 4,194,304 f32
    __hip_bfloat16* vT_b  = (__hip_bfloat16*)(ws + 37748736);    // 4.2M bf16
    __hip_bfloat16* qsb   = (__hip_bfloat16*)(ws + 39845888);    // 4.2M bf16
    __hip_bfloat16* ksw_b = (__hip_bfloat16*)(ws + 41943040);    // 4.2M bf16 [bh][l][64]
    float* skc            = ws + 44040192;                       // 262,144 f32
    float* part           = ws + 44302336;                       // 512
    float* gmax           = ws + 44302848;                       // 1
    __hip_bfloat16* attn_b = qsb;   // qsb dead after feat_gemm_q

    const dim3 blk(256);

    // projections: q -> bf16 row-major; k -> bf16 scattered [bh][l][64]; v -> f32 scattered
    gemm_bf16<512,0,__hip_bfloat16,float,float><<<dim3(4,64), blk, 0, stream>>>(query, Wq, bq, qsb, K_SCALE);
    gemm_bf16<512,1,__hip_bfloat16,float,float><<<dim3(4,64), blk, 0, stream>>>(key,   Wk, bk, ksw_b, K_SCALE);
    gemm_bf16<512,1,float,float,float><<<dim3(4,64), blk, 0, stream>>>(value, Wv, bv, vw, 1.0f);

    // v transpose -> bf16 [B,H,D,L]
    transpose_v_kernel<<<dim3(32,32), blk, 0, stream>>>(vw, vT_b);

    // Q path: fused feature GEMM + softmax-map
    feat_gemm_q_kernel<<<512, dim3(512), 0, stream>>>(qsb, proj, qp_b);

    // K path: feature GEMM -> ddT f16 (diag folded, transposed) + block max
    feat_gemm_kT_kernel<<<dim3(16,32), dim3(512), 0, stream>>>(ksw_b, proj, ddT, part);
    kmax_final_kernel<<<1, blk, 0, stream>>>(part, gmax);

    // fused exp + chunk state + prefix + kp_b emit
    chunk_state_mfma_kernel<<<dim3(4,32), blk, 0, stream>>>(ddT, vT_b, gmax, ScT_b, skc, kp_b);

    // chunk output
    chunk_out_kernel<<<dim3(NCHUNK,HH,BB), blk, 0, stream>>>(qp_b, kp_b, vT_b, ScT_b, skc, attn_b);

    // output projection
    gemm_bf16<512,0,float,__hip_bfloat16,float><<<dim3(4,64), blk, 0, stream>>>(attn_b, Wo, bo, (float*)d_out, 1.0f);
}

// Round 7
// 172.974 us; speedup vs baseline: 3.9690x; 1.1464x over previous
//
#include <hip/hip_runtime.h>
#include <hip/hip_bf16.h>
#include <math.h>

// Problem constants
#define BB 4
#define LL 2048
#define HH 8
#define DD 64          // head dim
#define MM 256         // nb_features
#define DIMM 512
#define TT 64          // chunk length
#define NCHUNK (LL/TT) // 32

constexpr float K_SCALE = 0.35355339059327379f; // 64^-0.25
constexpr float K_RATIO = 0.0625f;              // 256^-0.5
constexpr float K_EPS   = 1e-6f;

using short8 = __attribute__((ext_vector_type(8))) short;
using f32x4  = __attribute__((ext_vector_type(4))) float;
typedef _Float16 f16_t;

__device__ inline unsigned short f2b_u16(float x) {
    __hip_bfloat16 h = __float2bfloat16(x);
    return *reinterpret_cast<unsigned short*>(&h);
}
__device__ inline ushort4 f2b4(float4 v) {
    ushort4 o; o.x = f2b_u16(v.x); o.y = f2b_u16(v.y); o.z = f2b_u16(v.z); o.w = f2b_u16(v.w);
    return o;
}
__device__ inline unsigned short f2h_u16(float x) {
    f16_t h = (f16_t)x;
    return *reinterpret_cast<unsigned short*>(&h);
}
__device__ inline float h2f(unsigned short u) {
    f16_t h = *reinterpret_cast<f16_t*>(&u);
    return (float)h;
}
__device__ inline float b2f_u16(unsigned short u) {
    __hip_bfloat16 h = *reinterpret_cast<__hip_bfloat16*>(&u);
    return __bfloat162float(h);
}

template<typename T> __device__ inline T f2o(float v);
template<> __device__ inline float f2o<float>(float v) { return v; }
template<> __device__ inline __hip_bfloat16 f2o<__hip_bfloat16>(float v) { return __float2bfloat16(v); }

// XOR-swizzled byte offset into the chunk_state kT tile ([m][t] bf16, row
// stride 72 elems = 144B). Spreads transposed reads across 16B slots;
// 16B-aligned accesses stay aligned (XOR touches byte bits 4-5 only).
#define KSWZ(m, te) ((((m)*144) + ((te)*2)) ^ ((((m)>>3) & 3) << 4))

// ---------------------------------------------------------------------------
// Merged q/k/v projection (one launch, gridDim.z=3):
//   z=0: qsb = bf16 row-major (query@Wq^T + bq) * K_SCALE
//   z=1: ksw = bf16 scatter [bh][l][64]  (key @Wk^T + bk) * K_SCALE
//   z=2: vw  = f32 scatter  [bh][l][64]  (value@Wv^T + bv)
// Tile 128x128, BK=64, 4 waves (2x2). (MFMA body verified round 2)
// ---------------------------------------------------------------------------
__global__ __launch_bounds__(256)
void qkv_proj_kernel(const float* __restrict__ Xq, const float* __restrict__ Xk,
                     const float* __restrict__ Xv,
                     const float* __restrict__ Wq, const float* __restrict__ bq,
                     const float* __restrict__ Wk, const float* __restrict__ bk,
                     const float* __restrict__ Wv, const float* __restrict__ bv,
                     __hip_bfloat16* __restrict__ qsb, __hip_bfloat16* __restrict__ ksw,
                     float* __restrict__ vw)
{
    constexpr int LDT = 72;
    __shared__ __hip_bfloat16 As[128*LDT];
    __shared__ __hip_bfloat16 Bs[128*LDT];
    const int z = blockIdx.z;
    const float* X    = (z == 0) ? Xq : (z == 1) ? Xk : Xv;
    const float* W    = (z == 0) ? Wq : (z == 1) ? Wk : Wv;
    const float* bias = (z == 0) ? bq : (z == 1) ? bk : bv;
    const float postscale = (z == 2) ? 1.0f : K_SCALE;

    const int tid = threadIdx.x;
    const int lane = tid & 63;
    const int w = tid >> 6;
    const int wm = (w >> 1) * 64, wn = (w & 1) * 64;
    const int row0 = blockIdx.y * 128, col0 = blockIdx.x * 128;
    const int l15 = lane & 15, l4 = lane >> 4;

    f32x4 acc[4][4];
#pragma unroll
    for (int mt = 0; mt < 4; ++mt)
#pragma unroll
        for (int nt = 0; nt < 4; ++nt) {
            f32x4 zf = {0.f, 0.f, 0.f, 0.f};
            acc[mt][nt] = zf;
        }

    for (int k0 = 0; k0 < DIMM; k0 += 64) {
#pragma unroll
        for (int i = 0; i < 8; ++i) {
            int lin = i*256 + tid;
            int r = lin >> 4, kc = (lin & 15)*4;
            float4 a = *(const float4*)(X + (size_t)(row0 + r)*DIMM + k0 + kc);
            *(ushort4*)&As[r*LDT + kc] = f2b4(a);
            float4 b = *(const float4*)(W + (size_t)(col0 + r)*DIMM + k0 + kc);
            *(ushort4*)&Bs[r*LDT + kc] = f2b4(b);
        }
        __syncthreads();
#pragma unroll
        for (int ks = 0; ks < 2; ++ks) {
            const int koff = ks*32 + l4*8;
            short8 aF[4], bF[4];
#pragma unroll
            for (int mt = 0; mt < 4; ++mt)
                aF[mt] = *(const short8*)&As[(wm + mt*16 + l15)*LDT + koff];
#pragma unroll
            for (int nt = 0; nt < 4; ++nt)
                bF[nt] = *(const short8*)&Bs[(wn + nt*16 + l15)*LDT + koff];
#pragma unroll
            for (int mt = 0; mt < 4; ++mt)
#pragma unroll
                for (int nt = 0; nt < 4; ++nt)
                    acc[mt][nt] = __builtin_amdgcn_mfma_f32_16x16x32_bf16(aF[mt], bF[nt], acc[mt][nt], 0, 0, 0);
        }
        __syncthreads();
    }

#pragma unroll
    for (int mt = 0; mt < 4; ++mt) {
#pragma unroll
        for (int nt = 0; nt < 4; ++nt) {
            const int c = col0 + wn + nt*16 + l15;
            const float bval = bias[c];
#pragma unroll
            for (int j = 0; j < 4; ++j) {
                const int r = row0 + wm + mt*16 + l4*4 + j;
                const float val = (acc[mt][nt][j] + bval) * postscale;
                if (z == 0) {
                    qsb[(size_t)r*DIMM + c] = __float2bfloat16(val);
                } else {
                    const int b = r >> 11, l = r & 2047;
                    const int hh = c >> 6, d = c & 63;
                    const size_t idx = (((size_t)b*HH + hh)*LL + l)*DD + d;
                    if (z == 1) ksw[idx] = __float2bfloat16(val);
                    else        vw[idx] = val;
                }
            }
        }
    }
}

// ---------------------------------------------------------------------------
// Final Wo GEMM: out = attn_b[8192,512](bf16) @ Wo(f32,cast)^T + bo, f32.
// ---------------------------------------------------------------------------
__global__ __launch_bounds__(256)
void gemm_wo_kernel(const __hip_bfloat16* __restrict__ X, const float* __restrict__ W,
                    const float* __restrict__ bias, float* __restrict__ out)
{
    constexpr int LDT = 72;
    __shared__ __hip_bfloat16 As[128*LDT];
    __shared__ __hip_bfloat16 Bs[128*LDT];
    const int tid = threadIdx.x;
    const int lane = tid & 63;
    const int w = tid >> 6;
    const int wm = (w >> 1) * 64, wn = (w & 1) * 64;
    const int row0 = blockIdx.y * 128, col0 = blockIdx.x * 128;
    const int l15 = lane & 15, l4 = lane >> 4;

    f32x4 acc[4][4];
#pragma unroll
    for (int mt = 0; mt < 4; ++mt)
#pragma unroll
        for (int nt = 0; nt < 4; ++nt) {
            f32x4 z = {0.f, 0.f, 0.f, 0.f};
            acc[mt][nt] = z;
        }

    for (int k0 = 0; k0 < DIMM; k0 += 64) {
#pragma unroll
        for (int i = 0; i < 4; ++i) {
            int lin = i*256 + tid;
            int r = lin >> 3, kc = (lin & 7)*8;
            *(uint4*)&As[r*LDT + kc] = *(const uint4*)(X + (size_t)(row0 + r)*DIMM + k0 + kc);
        }
#pragma unroll
        for (int i = 0; i < 8; ++i) {
            int lin = i*256 + tid;
            int r = lin >> 4, kc = (lin & 15)*4;
            float4 b = *(const float4*)(W + (size_t)(col0 + r)*DIMM + k0 + kc);
            *(ushort4*)&Bs[r*LDT + kc] = f2b4(b);
        }
        __syncthreads();
#pragma unroll
        for (int ks = 0; ks < 2; ++ks) {
            const int koff = ks*32 + l4*8;
            short8 aF[4], bF[4];
#pragma unroll
            for (int mt = 0; mt < 4; ++mt)
                aF[mt] = *(const short8*)&As[(wm + mt*16 + l15)*LDT + koff];
#pragma unroll
            for (int nt = 0; nt < 4; ++nt)
                bF[nt] = *(const short8*)&Bs[(wn + nt*16 + l15)*LDT + koff];
#pragma unroll
            for (int mt = 0; mt < 4; ++mt)
#pragma unroll
                for (int nt = 0; nt < 4; ++nt)
                    acc[mt][nt] = __builtin_amdgcn_mfma_f32_16x16x32_bf16(aF[mt], bF[nt], acc[mt][nt], 0, 0, 0);
        }
        __syncthreads();
    }

#pragma unroll
    for (int mt = 0; mt < 4; ++mt) {
#pragma unroll
        for (int nt = 0; nt < 4; ++nt) {
            const int c = col0 + wn + nt*16 + l15;
            const float bval = bias[c];
#pragma unroll
            for (int j = 0; j < 4; ++j) {
                const int r = row0 + wm + mt*16 + l4*4 + j;
                out[(size_t)r*DIMM + c] = acc[mt][nt][j] + bval;
            }
        }
    }
}

// ---------------------------------------------------------------------------
// Fused Q feature map: qp = RATIO*(exp(X@P^T - diag - rowmax) + EPS), bf16.
// (verified round 5)
// ---------------------------------------------------------------------------
__global__ __launch_bounds__(512)
void feat_gemm_q_kernel(const __hip_bfloat16* __restrict__ X, const float* __restrict__ P,
                        __hip_bfloat16* __restrict__ qp_b)
{
    constexpr int LDT = 72;
    __shared__ __hip_bfloat16 As[128*LDT];
    __shared__ __hip_bfloat16 Bs[256*LDT];
    __shared__ float rowmax[128][4];
    __shared__ float diagl[128];
    const int tid = threadIdx.x;
    const int lane = tid & 63, w = tid >> 6;
    const int wr = w >> 2, wc = w & 3;
    const int l15 = lane & 15, l4 = lane >> 4;
    const int row0 = blockIdx.x * 128;

#pragma unroll
    for (int i = 0; i < 2; ++i) {
        int lin = i*512 + tid;
        int r = lin >> 3, kc = (lin & 7)*8;
        *(uint4*)&As[r*LDT + kc] = *(const uint4*)(X + (size_t)(row0 + r)*64 + kc);
    }
#pragma unroll
    for (int i = 0; i < 8; ++i) {
        int lin = i*512 + tid;
        int r = lin >> 4, kc = (lin & 15)*4;
        float4 v = *(const float4*)(P + (size_t)r*64 + kc);
        *(ushort4*)&Bs[r*LDT + kc] = f2b4(v);
    }
    __syncthreads();

    f32x4 acc[4][4];
#pragma unroll
    for (int mt = 0; mt < 4; ++mt)
#pragma unroll
        for (int nt = 0; nt < 4; ++nt) {
            f32x4 z = {0.f,0.f,0.f,0.f};
            acc[mt][nt] = z;
        }
#pragma unroll
    for (int ks = 0; ks < 2; ++ks) {
        const int ko = ks*32 + l4*8;
        short8 aF[4], bF[4];
#pragma unroll
        for (int mt = 0; mt < 4; ++mt)
            aF[mt] = *(const short8*)&As[(wr*64 + mt*16 + l15)*LDT + ko];
#pragma unroll
        for (int nt = 0; nt < 4; ++nt)
            bF[nt] = *(const short8*)&Bs[(wc*64 + nt*16 + l15)*LDT + ko];
#pragma unroll
        for (int mt = 0; mt < 4; ++mt)
#pragma unroll
            for (int nt = 0; nt < 4; ++nt)
                acc[mt][nt] = __builtin_amdgcn_mfma_f32_16x16x32_bf16(aF[mt], bF[nt], acc[mt][nt], 0, 0, 0);
    }

    {
        const int r = tid >> 2, q = tid & 3;
        float s = 0.f;
#pragma unroll
        for (int i = 0; i < 16; ++i) {
            float x = __bfloat162float(As[r*LDT + q*16 + i]);
            s += x*x;
        }
        s += __shfl_xor(s, 1);
        s += __shfl_xor(s, 2);
        if (q == 0) diagl[r] = 0.5f * s;
    }
#pragma unroll
    for (int mt = 0; mt < 4; ++mt)
#pragma unroll
        for (int j = 0; j < 4; ++j) {
            float m = fmaxf(fmaxf(acc[mt][0][j], acc[mt][1][j]),
                            fmaxf(acc[mt][2][j], acc[mt][3][j]));
#pragma unroll
            for (int off = 8; off > 0; off >>= 1) m = fmaxf(m, __shfl_xor(m, off));
            if (l15 == 0) rowmax[wr*64 + mt*16 + l4*4 + j][wc] = m;
        }
    __syncthreads();

#pragma unroll
    for (int mt = 0; mt < 4; ++mt)
#pragma unroll
        for (int j = 0; j < 4; ++j) {
            const int r = wr*64 + mt*16 + l4*4 + j;
            const float stab = fmaxf(fmaxf(rowmax[r][0], rowmax[r][1]),
                                     fmaxf(rowmax[r][2], rowmax[r][3]));
            const float cc = diagl[r] + stab;
            const int gr = row0 + r;
            const int bl = gr >> 3, h = gr & 7;
            const int b = bl >> 11, l = bl & 2047;
            const size_t base = (((size_t)b*HH + h)*LL + l)*MM;
#pragma unroll
            for (int nt = 0; nt < 4; ++nt)
                qp_b[base + wc*64 + nt*16 + l15] =
                    __float2bfloat16(K_RATIO * (__expf(acc[mt][nt][j] - cc) + K_EPS));
        }
}

// ---------------------------------------------------------------------------
// K feature GEMM, TRANSPOSED f16 output with diag folded (verified round 6):
//   ddT[bh][m][l] = (X_bh @ P^T)[l][m] - diag[l]   (f16) ; block max -> part
// ---------------------------------------------------------------------------
__global__ __launch_bounds__(512)
void feat_gemm_kT_kernel(const __hip_bfloat16* __restrict__ X, const float* __restrict__ P,
                         unsigned short* __restrict__ ddT, float* __restrict__ part)
{
    constexpr int LDT = 72;
    __shared__ __hip_bfloat16 As[128*LDT];
    __shared__ __hip_bfloat16 Bs[256*LDT];
    __shared__ float diagl[128];
    __shared__ float wmx[8];
    const int tid = threadIdx.x;
    const int lane = tid & 63, w = tid >> 6;
    const int wr = w >> 2, wc = w & 3;
    const int l15 = lane & 15, l4 = lane >> 4;
    const int bh = blockIdx.y;
    const int l0 = blockIdx.x * 128;

#pragma unroll
    for (int i = 0; i < 2; ++i) {
        int lin = i*512 + tid;
        int r = lin >> 3, kc = (lin & 7)*8;
        *(uint4*)&As[r*LDT + kc] = *(const uint4*)(X + ((size_t)bh*LL + l0 + r)*64 + kc);
    }
#pragma unroll
    for (int i = 0; i < 8; ++i) {
        int lin = i*512 + tid;
        int r = lin >> 4, kc = (lin & 15)*4;
        float4 v = *(const float4*)(P + (size_t)r*64 + kc);
        *(ushort4*)&Bs[r*LDT + kc] = f2b4(v);
    }
    __syncthreads();

    f32x4 acc[4][4];
#pragma unroll
    for (int mt = 0; mt < 4; ++mt)
#pragma unroll
        for (int nt = 0; nt < 4; ++nt) {
            f32x4 z = {0.f,0.f,0.f,0.f};
            acc[mt][nt] = z;
        }
#pragma unroll
    for (int ks = 0; ks < 2; ++ks) {
        const int ko = ks*32 + l4*8;
        short8 aF[4], bF[4];
#pragma unroll
        for (int mt = 0; mt < 4; ++mt)
            aF[mt] = *(const short8*)&As[(wr*64 + mt*16 + l15)*LDT + ko];
#pragma unroll
        for (int nt = 0; nt < 4; ++nt)
            bF[nt] = *(const short8*)&Bs[(wc*64 + nt*16 + l15)*LDT + ko];
#pragma unroll
        for (int mt = 0; mt < 4; ++mt)
#pragma unroll
            for (int nt = 0; nt < 4; ++nt)
                acc[mt][nt] = __builtin_amdgcn_mfma_f32_16x16x32_bf16(aF[mt], bF[nt], acc[mt][nt], 0, 0, 0);
    }

    {
        const int r = tid >> 2, q = tid & 3;
        float s = 0.f;
#pragma unroll
        for (int i = 0; i < 16; ++i) {
            float x = __bfloat162float(As[r*LDT + q*16 + i]);
            s += x*x;
        }
        s += __shfl_xor(s, 1);
        s += __shfl_xor(s, 2);
        if (q == 0) diagl[r] = 0.5f * s;
    }
    {
        float mx = -3.0e38f;
#pragma unroll
        for (int mt = 0; mt < 4; ++mt)
#pragma unroll
            for (int nt = 0; nt < 4; ++nt)
#pragma unroll
                for (int j = 0; j < 4; ++j)
                    mx = fmaxf(mx, acc[mt][nt][j]);
#pragma unroll
        for (int off = 32; off > 0; off >>= 1) mx = fmaxf(mx, __shfl_xor(mx, off));
        if (lane == 0) wmx[w] = mx;
    }
    __syncthreads();
    if (tid == 0) {
        float mx = wmx[0];
#pragma unroll
        for (int i = 1; i < 8; ++i) mx = fmaxf(mx, wmx[i]);
        part[blockIdx.y*16 + blockIdx.x] = mx;
    }

#pragma unroll
    for (int mt = 0; mt < 4; ++mt) {
#pragma unroll
        for (int nt = 0; nt < 4; ++nt) {
            const int m = wc*64 + nt*16 + l15;
            const int rbase = wr*64 + mt*16 + l4*4;
            ushort4 o;
            o.x = f2h_u16(acc[mt][nt][0] - diagl[rbase+0]);
            o.y = f2h_u16(acc[mt][nt][1] - diagl[rbase+1]);
            o.z = f2h_u16(acc[mt][nt][2] - diagl[rbase+2]);
            o.w = f2h_u16(acc[mt][nt][3] - diagl[rbase+3]);
            *(ushort4*)(ddT + ((size_t)bh*MM + m)*LL + l0 + rbase) = o;
        }
    }
}

__global__ __launch_bounds__(256)
void kmax_final_kernel(const float* __restrict__ part, float* __restrict__ gmax)
{
    float mx = -3.0e38f;
    for (int i = threadIdx.x; i < 512; i += 256) mx = fmaxf(mx, part[i]);
#pragma unroll
    for (int off = 32; off > 0; off >>= 1) mx = fmaxf(mx, __shfl_xor(mx, off));
    __shared__ float wsm[4];
    if ((threadIdx.x & 63) == 0) wsm[threadIdx.x >> 6] = mx;
    __syncthreads();
    if (threadIdx.x == 0) gmax[0] = fmaxf(fmaxf(wsm[0], wsm[1]), fmaxf(wsm[2], wsm[3]));
}

// ---------------------------------------------------------------------------
// vw [B,H,L,D] f32  ->  vT [B,H,D,L] bf16  (tiled LDS transpose)
// ---------------------------------------------------------------------------
__global__ __launch_bounds__(256)
void transpose_v_kernel(const float* __restrict__ vw, __hip_bfloat16* __restrict__ vT)
{
    __shared__ float vl[64][65];
    const int bh = blockIdx.y;
    const int l0 = blockIdx.x*64;
    const float* src = vw + ((size_t)bh*LL + l0)*DD;
#pragma unroll
    for (int it = 0; it < 4; ++it) {
        int lin = it*256 + threadIdx.x;
        int t = lin >> 4, d4 = (lin & 15)*4;
        float4 v = *(const float4*)(src + (size_t)t*DD + d4);
        vl[t][d4+0]=v.x; vl[t][d4+1]=v.y; vl[t][d4+2]=v.z; vl[t][d4+3]=v.w;
    }
    __syncthreads();
    const int d = threadIdx.x >> 2, q = threadIdx.x & 3;
    __hip_bfloat16* dst = vT + ((size_t)bh*DD + d)*LL + l0 + q*16;
#pragma unroll
    for (int g = 0; g < 4; ++g) {
        ushort4 o;
        o.x = f2b_u16(vl[q*16+g*4+0][d]);
        o.y = f2b_u16(vl[q*16+g*4+1][d]);
        o.z = f2b_u16(vl[q*16+g*4+2][d]);
        o.w = f2b_u16(vl[q*16+g*4+3][d]);
        *(ushort4*)(dst + g*4) = o;
    }
}

// ---------------------------------------------------------------------------
// Per-chunk state (fully parallel, MFMA). Grid (NCHUNK, 32bh), 256 thr.
// Stages kT [256m][64t] (exp applied, XOR-swizzled) + vT [64d][64t], computes
// Sci[bh][c][d][m] = sum_t v[t,d]*kp[t,m]  (bf16), skc[bh][c][m] (f32),
// and emits kp_b [bh][c*64+t][m] via transposed swizzled LDS reads.
// ---------------------------------------------------------------------------
__global__ __launch_bounds__(256)
void chunk_state_mfma_kernel(const unsigned short* __restrict__ ddT,
                             const __hip_bfloat16* __restrict__ vT_b,
                             const float* __restrict__ gmax,
                             __hip_bfloat16* __restrict__ Sci_b,
                             float* __restrict__ skc,
                             __hip_bfloat16* __restrict__ kp_b)
{
    __shared__ __hip_bfloat16 kT[256*72];
    __shared__ __hip_bfloat16 vT[64*72];
    const int c = blockIdx.x, bh = blockIdx.y;
    const int tid = threadIdx.x, lane = tid & 63, w = tid >> 6;
    const int l15 = lane & 15, l4 = lane >> 4;
    const float gm = gmax[0];
    char* kbuf = (char*)&kT[0];
    char* vbuf = (char*)&vT[0];

    // stage kT: thread tid owns m-row tid, 64 t elems (exp applied)
    {
        const unsigned short* ksrc = ddT + ((size_t)bh*MM + tid)*LL + (size_t)c*64;
#pragma unroll
        for (int o = 0; o < 8; ++o) {
            uint4 r0 = *(const uint4*)(ksrc + o*8);
            const unsigned short* u0 = (const unsigned short*)&r0;
            unsigned short p0[8];
#pragma unroll
            for (int i = 0; i < 8; ++i)
                p0[i] = f2b_u16(K_RATIO * (__expf(h2f(u0[i]) - gm) + K_EPS));
            *(uint4*)(kbuf + KSWZ(tid, o*8)) = *(uint4*)&p0[0];
        }
        const int sr = tid >> 2, sq = tid & 3;
        const __hip_bfloat16* vsrc = vT_b + ((size_t)bh*DD + sr)*LL + (size_t)c*64 + sq*16;
        *(uint4*)(vbuf + sr*144 + sq*32)      = *(const uint4*)(vsrc);
        *(uint4*)(vbuf + sr*144 + sq*32 + 16) = *(const uint4*)(vsrc + 8);
    }
    __syncthreads();

    f32x4 accS[4][4];   // [dt][mt]
    f32x4 accK[4];
#pragma unroll
    for (int i = 0; i < 4; ++i) {
#pragma unroll
        for (int j = 0; j < 4; ++j) { f32x4 z = {0.f,0.f,0.f,0.f}; accS[i][j] = z; }
        f32x4 z = {0.f,0.f,0.f,0.f}; accK[i] = z;
    }
    short8 ones8;
    {
        const short ov = (short)0x3F80;   // bf16 1.0
#pragma unroll
        for (int i = 0; i < 8; ++i) ones8[i] = (l15 == 0) ? ov : (short)0;
    }

#pragma unroll
    for (int ks = 0; ks < 2; ++ks) {
        const int ko = ks*32 + l4*8;
        short8 bF[4], aF[4];
#pragma unroll
        for (int mt = 0; mt < 4; ++mt)
            bF[mt] = *(const short8*)(kbuf + KSWZ(w*64 + mt*16 + l15, ko));
#pragma unroll
        for (int dt = 0; dt < 4; ++dt)
            aF[dt] = *(const short8*)(vbuf + (dt*16 + l15)*144 + ko*2);
#pragma unroll
        for (int dt = 0; dt < 4; ++dt)
#pragma unroll
            for (int mt = 0; mt < 4; ++mt)
                accS[dt][mt] = __builtin_amdgcn_mfma_f32_16x16x32_bf16(aF[dt], bF[mt], accS[dt][mt], 0, 0, 0);
#pragma unroll
        for (int mt = 0; mt < 4; ++mt)
            accK[mt] = __builtin_amdgcn_mfma_f32_16x16x32_bf16(ones8, bF[mt], accK[mt], 0, 0, 0);
    }

    // per-chunk state write [d][m]
    __hip_bfloat16* So = Sci_b + ((size_t)(bh*NCHUNK + c))*(MM*DD);
#pragma unroll
    for (int dt = 0; dt < 4; ++dt)
#pragma unroll
        for (int mt = 0; mt < 4; ++mt) {
            const int m = w*64 + mt*16 + l15;
#pragma unroll
            for (int j = 0; j < 4; ++j)
                So[(size_t)(dt*16 + l4*4 + j)*MM + m] = __float2bfloat16(accS[dt][mt][j]);
        }
    if (l4 == 0) {
#pragma unroll
        for (int mt = 0; mt < 4; ++mt)
            skc[((size_t)bh*NCHUNK + c)*MM + w*64 + mt*16 + l15] = accK[mt][0];
    }

    // kp_b emit [t][m]: wave w owns t-rows w*16..w*16+15
    {
        const int t2 = w*16 + (lane >> 2);
        const int m0 = (lane & 3)*16;
        __hip_bfloat16* krow = kp_b + ((size_t)bh*LL + (size_t)c*64 + t2)*MM;
#pragma unroll
        for (int seg = 0; seg < 4; ++seg) {
            unsigned short vals[16];
#pragma unroll
            for (int i = 0; i < 16; ++i)
                vals[i] = *(const unsigned short*)(kbuf + KSWZ(seg*64 + m0 + i, t2));
            *(uint4*)(krow + seg*64 + m0)     = *(uint4*)&vals[0];
            *(uint4*)(krow + seg*64 + m0 + 8) = *(uint4*)&vals[8];
        }
    }
}

// ---------------------------------------------------------------------------
// Exclusive prefix over chunks, IN PLACE: Sci bf16 [bh][c][d][m] (f32 carry)
// and skc f32 [bh][c][m]. Grid (16, 32), 256 threads.
// ---------------------------------------------------------------------------
__global__ __launch_bounds__(256)
void chunk_prefix_kernel(__hip_bfloat16* __restrict__ S_b, float* __restrict__ skc)
{
    const int bh = blockIdx.y;
    const int e4 = blockIdx.x*256 + threadIdx.x;    // quad index 0..4095
    __hip_bfloat16* base = S_b + (size_t)bh*NCHUNK*(MM*DD) + (size_t)e4*4;
    float4 run = {0.f, 0.f, 0.f, 0.f};
#pragma unroll 4
    for (int c = 0; c < NCHUNK; ++c) {
        __hip_bfloat16* p = base + (size_t)c*(MM*DD);
        ushort4 t = *(ushort4*)p;
        ushort4 o;
        o.x = f2b_u16(run.x); o.y = f2b_u16(run.y);
        o.z = f2b_u16(run.z); o.w = f2b_u16(run.w);
        *(ushort4*)p = o;
        run.x += b2f_u16(t.x); run.y += b2f_u16(t.y);
        run.z += b2f_u16(t.z); run.w += b2f_u16(t.w);
    }
    if (blockIdx.x == 0) {
        float* kb = skc + (size_t)bh*NCHUNK*MM + threadIdx.x;
        float s2 = 0.f;
#pragma unroll 4
        for (int c = 0; c < NCHUNK; ++c) {
            float t = kb[(size_t)c*MM];
            kb[(size_t)c*MM] = s2;
            s2 += t;
        }
    }
}

// ---------------------------------------------------------------------------
// MFMA chunk_out (verified round 4, unchanged).
// ---------------------------------------------------------------------------
__global__ __launch_bounds__(256)
void chunk_out_kernel(const __hip_bfloat16* __restrict__ qp_b,
                      const __hip_bfloat16* __restrict__ kp_b,
                      const __hip_bfloat16* __restrict__ vT_b,
                      const __hip_bfloat16* __restrict__ ScT_b,
                      const float* __restrict__ skp,
                      __hip_bfloat16* __restrict__ attn)
{
    constexpr int LDQ = 72;
    constexpr int LDA = 72;
    __shared__ __hip_bfloat16 Qs[64*LDQ];
    __shared__ __hip_bfloat16 Ks[64*LDQ];
    __shared__ __hip_bfloat16 Ss[80*LDQ];
    __shared__ __hip_bfloat16 Al[64*LDA];
    __shared__ __hip_bfloat16 Vl[80*LDA];

    const int c = blockIdx.x, h = blockIdx.y, b = blockIdx.z;
    const size_t bh = (size_t)b*HH + h;
    const __hip_bfloat16* qpc = qp_b + (bh*LL + (size_t)c*TT) * MM;
    const __hip_bfloat16* kpc = kp_b + (bh*LL + (size_t)c*TT) * MM;
    const __hip_bfloat16* vTc = vT_b + bh*(size_t)(DD*LL) + (size_t)c*TT;
    const __hip_bfloat16* Scc = ScT_b + (bh*NCHUNK + (size_t)c) * (MM*DD);
    const float* skrow = skp + (bh*NCHUNK + (size_t)c) * MM;

    const int tid = threadIdx.x;
    const int lane = tid & 63;
    const int w = tid >> 6;
    const int l15 = lane & 15, l4 = lane >> 4;

    {
#pragma unroll
        for (int it = 0; it < 2; ++it) {
            int lin = it*256 + tid;
            int d = lin >> 3, c8 = (lin & 7)*8;
            *(uint4*)&Vl[d*LDA + c8] = *(const uint4*)(vTc + (size_t)d*LL + c8);
        }
        const __hip_bfloat16 one = __float2bfloat16(1.0f);
        const __hip_bfloat16 zero = __float2bfloat16(0.0f);
        for (int idx = tid; idx < 16*64; idx += 256) {
            int rr = idx >> 6, cc2 = idx & 63;
            Vl[(64+rr)*LDA + cc2] = (rr == 0) ? one : zero;
        }
        for (int idx = tid; idx < 15*64; idx += 256) {
            int rr = idx / 64, cc2 = idx % 64;
            Ss[(65+rr)*LDQ + cc2] = zero;
        }
    }

    f32x4 accA[4];
    f32x4 accO[5];
#pragma unroll
    for (int i = 0; i < 4; ++i) { f32x4 z = {0.f,0.f,0.f,0.f}; accA[i] = z; }
#pragma unroll
    for (int i = 0; i < 5; ++i) { f32x4 z = {0.f,0.f,0.f,0.f}; accO[i] = z; }

    for (int mq = 0; mq < MM; mq += 64) {
        __syncthreads();
#pragma unroll
        for (int it = 0; it < 2; ++it) {
            int lin = it*256 + tid;
            int r = lin >> 3, m8 = (lin & 7)*8;
            *(uint4*)&Qs[r*LDQ + m8] = *(const uint4*)(qpc + (size_t)r*MM + mq + m8);
            *(uint4*)&Ks[r*LDQ + m8] = *(const uint4*)(kpc + (size_t)r*MM + mq + m8);
            *(uint4*)&Ss[r*LDQ + m8] = *(const uint4*)(Scc + (size_t)r*MM + mq + m8);
        }
        if (tid < 64) Ss[64*LDQ + tid] = __float2bfloat16(skrow[mq + tid]);
        __syncthreads();
#pragma unroll
        for (int ks = 0; ks < 2; ++ks) {
            const int ko = ks*32 + l4*8;
            short8 aF = *(const short8*)&Qs[(w*16 + l15)*LDQ + ko];
#pragma unroll
            for (int nt = 0; nt < 4; ++nt) {
                short8 bF = *(const short8*)&Ks[(nt*16 + l15)*LDQ + ko];
                accA[nt] = __builtin_amdgcn_mfma_f32_16x16x32_bf16(aF, bF, accA[nt], 0, 0, 0);
            }
#pragma unroll
            for (int nt = 0; nt < 5; ++nt) {
                short8 sF = *(const short8*)&Ss[(nt*16 + l15)*LDQ + ko];
                accO[nt] = __builtin_amdgcn_mfma_f32_16x16x32_bf16(aF, sF, accO[nt], 0, 0, 0);
            }
        }
    }
    __syncthreads();
#pragma unroll
    for (int nt = 0; nt < 4; ++nt) {
        const int s = nt*16 + l15;
#pragma unroll
        for (int j = 0; j < 4; ++j) {
            const int t = w*16 + l4*4 + j;
            const float v = (s <= t) ? accA[nt][j] : 0.f;
            Al[t*LDA + s] = __float2bfloat16(v);
        }
    }
    __syncthreads();
#pragma unroll
    for (int ks = 0; ks < 2; ++ks) {
        const int ko = ks*32 + l4*8;
        short8 aF = *(const short8*)&Al[(w*16 + l15)*LDA + ko];
#pragma unroll
        for (int nt = 0; nt < 5; ++nt) {
            short8 vF = *(const short8*)&Vl[(nt*16 + l15)*LDA + ko];
            accO[nt] = __builtin_amdgcn_mfma_f32_16x16x32_bf16(aF, vF, accO[nt], 0, 0, 0);
        }
    }
    __hip_bfloat16* arow = attn + ((size_t)b*LL + (size_t)c*TT) * DIMM + h*DD;
#pragma unroll
    for (int j = 0; j < 4; ++j) {
        const float den = __shfl(accO[4][j], (lane & 48));
        const float inv = 1.0f / den;
        const int t = w*16 + l4*4 + j;
#pragma unroll
        for (int nt = 0; nt < 4; ++nt) {
            const int d = nt*16 + l15;
            arow[(size_t)t*DIMM + d] = __float2bfloat16(accO[nt][j] * inv);
        }
    }
}

// ---------------------------------------------------------------------------
extern "C" void kernel_launch(void* const* d_in, const int* in_sizes, int n_in,
                              void* d_out, int out_size, void* d_ws, size_t ws_size,
                              hipStream_t stream)
{
    (void)in_sizes; (void)n_in; (void)out_size; (void)ws_size;
    const float* query = (const float*)d_in[0];
    const float* key   = (const float*)d_in[1];
    const float* value = (const float*)d_in[2];
    const float* Wq = (const float*)d_in[3];
    const float* bq = (const float*)d_in[4];
    const float* Wk = (const float*)d_in[5];
    const float* bk = (const float*)d_in[6];
    const float* Wv = (const float*)d_in[7];
    const float* bv = (const float*)d_in[8];
    const float* Wo = (const float*)d_in[9];
    const float* bo = (const float*)d_in[10];
    const float* proj = (const float*)d_in[11];

    float* ws = (float*)d_ws;
    // Workspace peak ~178 MB (f32-word offsets, same as round 6).
    unsigned short* ddT   = (unsigned short*)ws;                 // 16.7M f16  [bh][m][l]
    __hip_bfloat16* qp_b  = (__hip_bfloat16*)(ws +  8388608);    // 16.7M bf16
    __hip_bfloat16* kp_b  = (__hip_bfloat16*)(ws + 16777216);    // 16.7M bf16
    __hip_bfloat16* ScT_b = (__hip_bfloat16*)(ws + 25165824);    // 16.7M bf16 (states -> in-place prefix)
    float* vw             = ws + 33554432;                       // 4,194,304 f32
    __hip_bfloat16* vT_b  = (__hip_bfloat16*)(ws + 37748736);    // 4.2M bf16
    __hip_bfloat16* qsb   = (__hip_bfloat16*)(ws + 39845888);    // 4.2M bf16
    __hip_bfloat16* ksw_b = (__hip_bfloat16*)(ws + 41943040);    // 4.2M bf16 [bh][l][64]
    float* skc            = ws + 44040192;                       // 262,144 f32
    float* part           = ws + 44302336;                       // 512
    float* gmax           = ws + 44302848;                       // 1
    __hip_bfloat16* attn_b = qsb;   // qsb dead after feat_gemm_q

    const dim3 blk(256);

    // merged q/k/v projections (one launch, z=3)
    qkv_proj_kernel<<<dim3(4,64,3), blk, 0, stream>>>(query, key, value,
                                                      Wq, bq, Wk, bk, Wv, bv,
                                                      qsb, ksw_b, vw);

    // v transpose -> bf16 [B,H,D,L]
    transpose_v_kernel<<<dim3(32,32), blk, 0, stream>>>(vw, vT_b);

    // Q path: fused feature GEMM + softmax-map
    feat_gemm_q_kernel<<<512, dim3(512), 0, stream>>>(qsb, proj, qp_b);

    // K path: feature GEMM -> ddT f16 (diag folded, transposed) + block max
    feat_gemm_kT_kernel<<<dim3(16,32), dim3(512), 0, stream>>>(ksw_b, proj, ddT, part);
    kmax_final_kernel<<<1, blk, 0, stream>>>(part, gmax);

    // parallel per-chunk states (+ exp + kp_b emit), then in-place prefix
    chunk_state_mfma_kernel<<<dim3(NCHUNK,32), blk, 0, stream>>>(ddT, vT_b, gmax, ScT_b, skc, kp_b);
    chunk_prefix_kernel<<<dim3(16,32), blk, 0, stream>>>(ScT_b, skc);

    // chunk output
    chunk_out_kernel<<<dim3(NCHUNK,HH,BB), blk, 0, stream>>>(qp_b, kp_b, vT_b, ScT_b, skc, attn_b);

    // output projection
    gemm_wo_kernel<<<dim3(4,64), blk, 0, stream>>>(attn_b, Wo, bo, (float*)d_out);
}

// Round 8
// 168.521 us; speedup vs baseline: 4.0739x; 1.0264x over previous
//
#include <hip/hip_runtime.h>
#include <hip/hip_bf16.h>
#include <math.h>

// Problem constants
#define BB 4
#define LL 2048
#define HH 8
#define DD 64          // head dim
#define MM 256         // nb_features
#define DIMM 512
#define TT 64          // chunk length
#define NCHUNK (LL/TT) // 32

constexpr float K_SCALE = 0.35355339059327379f; // 64^-0.25
constexpr float K_RATIO = 0.0625f;              // 256^-0.5
constexpr float K_EPS   = 1e-6f;

using short8 = __attribute__((ext_vector_type(8))) short;
using f32x4  = __attribute__((ext_vector_type(4))) float;
typedef _Float16 f16_t;

__device__ inline unsigned short f2b_u16(float x) {
    __hip_bfloat16 h = __float2bfloat16(x);
    return *reinterpret_cast<unsigned short*>(&h);
}
__device__ inline ushort4 f2b4(float4 v) {
    ushort4 o; o.x = f2b_u16(v.x); o.y = f2b_u16(v.y); o.z = f2b_u16(v.z); o.w = f2b_u16(v.w);
    return o;
}
__device__ inline unsigned short f2h_u16(float x) {
    f16_t h = (f16_t)x;
    return *reinterpret_cast<unsigned short*>(&h);
}
__device__ inline float h2f(unsigned short u) {
    f16_t h = *reinterpret_cast<f16_t*>(&u);
    return (float)h;
}
__device__ inline float b2f_u16(unsigned short u) {
    __hip_bfloat16 h = *reinterpret_cast<__hip_bfloat16*>(&u);
    return __bfloat162float(h);
}

// XOR-swizzled byte offset into the chunk_state kT tile ([m][t] bf16, row
// stride 72 elems = 144B).
#define KSWZ(m, te) ((((m)*144) + ((te)*2)) ^ ((((m)>>3) & 3) << 4))

// XCD-grouping tile swizzle for 256-tile GEMM grids (gridDim (4,64)):
// all 4 col-tiles of one row-panel land on the same XCD (fid%8 == dispatch XCD).
__device__ inline void xcd_tiles(int* rt, int* ct) {
    const int fid = blockIdx.x + (gridDim.x * blockIdx.y);  // 0..255
    const int xcd = fid & 7;
    const int g   = fid >> 3;           // 0..31
    *rt = xcd*8 + (g >> 2);             // 0..63
    *ct = g & 3;                        // 0..3
}

// ---------------------------------------------------------------------------
// f32 -> bf16 casts: q/k/v inputs (2^20 float4 each) and 4 weights (2^16 each)
// ---------------------------------------------------------------------------
__global__ __launch_bounds__(256)
void cast_qkv_kernel(const float* __restrict__ q, const float* __restrict__ k,
                     const float* __restrict__ v,
                     __hip_bfloat16* __restrict__ qo, __hip_bfloat16* __restrict__ ko,
                     __hip_bfloat16* __restrict__ vo)
{
    const int total = 3 << 20;
    for (int i = blockIdx.x*256 + threadIdx.x; i < total; i += gridDim.x*256) {
        const int t = i >> 20, j = i & ((1 << 20) - 1);
        const float* src = (t == 0) ? q : (t == 1) ? k : v;
        __hip_bfloat16* dst = (t == 0) ? qo : (t == 1) ? ko : vo;
        float4 x = reinterpret_cast<const float4*>(src)[j];
        reinterpret_cast<ushort4*>(dst)[j] = f2b4(x);
    }
}

__global__ __launch_bounds__(256)
void cast_w_kernel(const float* __restrict__ w0, const float* __restrict__ w1,
                   const float* __restrict__ w2, const float* __restrict__ w3,
                   __hip_bfloat16* __restrict__ o0, __hip_bfloat16* __restrict__ o1,
                   __hip_bfloat16* __restrict__ o2, __hip_bfloat16* __restrict__ o3)
{
    const int total = 4 << 16;
    for (int i = blockIdx.x*256 + threadIdx.x; i < total; i += gridDim.x*256) {
        const int t = i >> 16, j = i & ((1 << 16) - 1);
        const float* src = (t == 0) ? w0 : (t == 1) ? w1 : (t == 2) ? w2 : w3;
        __hip_bfloat16* dst = (t == 0) ? o0 : (t == 1) ? o1 : (t == 2) ? o2 : o3;
        float4 x = reinterpret_cast<const float4*>(src)[j];
        reinterpret_cast<ushort4*>(dst)[j] = f2b4(x);
    }
}

// ---------------------------------------------------------------------------
// Merged q/k/v projection, bf16 operands, XCD-grouped tiles.
//   z=0: qsb = bf16 row-major (q@Wq^T + bq) * K_SCALE
//   z=1: ksw = bf16 scatter [bh][l][64]
//   z=2: vw  = bf16 scatter [bh][l][64]
// Tile 128x128, BK=64, 4 waves (2x2). (MFMA body verified round 2)
// ---------------------------------------------------------------------------
__global__ __launch_bounds__(256)
void qkv_proj_kernel(const __hip_bfloat16* __restrict__ Xq, const __hip_bfloat16* __restrict__ Xk,
                     const __hip_bfloat16* __restrict__ Xv,
                     const __hip_bfloat16* __restrict__ Wq, const float* __restrict__ bq,
                     const __hip_bfloat16* __restrict__ Wk, const float* __restrict__ bk,
                     const __hip_bfloat16* __restrict__ Wv, const float* __restrict__ bv,
                     __hip_bfloat16* __restrict__ qsb, __hip_bfloat16* __restrict__ ksw,
                     __hip_bfloat16* __restrict__ vw)
{
    constexpr int LDT = 72;
    __shared__ __hip_bfloat16 As[128*LDT];
    __shared__ __hip_bfloat16 Bs[128*LDT];
    const int z = blockIdx.z;
    const __hip_bfloat16* X = (z == 0) ? Xq : (z == 1) ? Xk : Xv;
    const __hip_bfloat16* W = (z == 0) ? Wq : (z == 1) ? Wk : Wv;
    const float* bias = (z == 0) ? bq : (z == 1) ? bk : bv;
    const float postscale = (z == 2) ? 1.0f : K_SCALE;

    int rt, ct;
    xcd_tiles(&rt, &ct);
    const int row0 = rt*128, col0 = ct*128;

    const int tid = threadIdx.x;
    const int lane = tid & 63;
    const int w = tid >> 6;
    const int wm = (w >> 1) * 64, wn = (w & 1) * 64;
    const int l15 = lane & 15, l4 = lane >> 4;

    f32x4 acc[4][4];
#pragma unroll
    for (int mt = 0; mt < 4; ++mt)
#pragma unroll
        for (int nt = 0; nt < 4; ++nt) {
            f32x4 zf = {0.f, 0.f, 0.f, 0.f};
            acc[mt][nt] = zf;
        }

    for (int k0 = 0; k0 < DIMM; k0 += 64) {
#pragma unroll
        for (int i = 0; i < 4; ++i) {
            int lin = i*256 + tid;              // 0..1023
            int r = lin >> 3, kc = (lin & 7)*8;
            *(uint4*)&As[r*LDT + kc] = *(const uint4*)(X + (size_t)(row0 + r)*DIMM + k0 + kc);
            *(uint4*)&Bs[r*LDT + kc] = *(const uint4*)(W + (size_t)(col0 + r)*DIMM + k0 + kc);
        }
        __syncthreads();
#pragma unroll
        for (int ks = 0; ks < 2; ++ks) {
            const int koff = ks*32 + l4*8;
            short8 aF[4], bF[4];
#pragma unroll
            for (int mt = 0; mt < 4; ++mt)
                aF[mt] = *(const short8*)&As[(wm + mt*16 + l15)*LDT + koff];
#pragma unroll
            for (int nt = 0; nt < 4; ++nt)
                bF[nt] = *(const short8*)&Bs[(wn + nt*16 + l15)*LDT + koff];
#pragma unroll
            for (int mt = 0; mt < 4; ++mt)
#pragma unroll
                for (int nt = 0; nt < 4; ++nt)
                    acc[mt][nt] = __builtin_amdgcn_mfma_f32_16x16x32_bf16(aF[mt], bF[nt], acc[mt][nt], 0, 0, 0);
        }
        __syncthreads();
    }

#pragma unroll
    for (int mt = 0; mt < 4; ++mt) {
#pragma unroll
        for (int nt = 0; nt < 4; ++nt) {
            const int c = col0 + wn + nt*16 + l15;
            const float bval = bias[c];
#pragma unroll
            for (int j = 0; j < 4; ++j) {
                const int r = row0 + wm + mt*16 + l4*4 + j;
                const float val = (acc[mt][nt][j] + bval) * postscale;
                if (z == 0) {
                    qsb[(size_t)r*DIMM + c] = __float2bfloat16(val);
                } else {
                    const int b = r >> 11, l = r & 2047;
                    const int hh = c >> 6, d = c & 63;
                    const size_t idx = (((size_t)b*HH + hh)*LL + l)*DD + d;
                    if (z == 1) ksw[idx] = __float2bfloat16(val);
                    else        vw[idx] = __float2bfloat16(val);
                }
            }
        }
    }
}

// ---------------------------------------------------------------------------
// Final Wo GEMM: out = attn_b[8192,512](bf16) @ Wob(bf16)^T + bo, f32. Swizzled.
// ---------------------------------------------------------------------------
__global__ __launch_bounds__(256)
void gemm_wo_kernel(const __hip_bfloat16* __restrict__ X, const __hip_bfloat16* __restrict__ W,
                    const float* __restrict__ bias, float* __restrict__ out)
{
    constexpr int LDT = 72;
    __shared__ __hip_bfloat16 As[128*LDT];
    __shared__ __hip_bfloat16 Bs[128*LDT];
    int rt, ct;
    xcd_tiles(&rt, &ct);
    const int row0 = rt*128, col0 = ct*128;
    const int tid = threadIdx.x;
    const int lane = tid & 63;
    const int w = tid >> 6;
    const int wm = (w >> 1) * 64, wn = (w & 1) * 64;
    const int l15 = lane & 15, l4 = lane >> 4;

    f32x4 acc[4][4];
#pragma unroll
    for (int mt = 0; mt < 4; ++mt)
#pragma unroll
        for (int nt = 0; nt < 4; ++nt) {
            f32x4 z = {0.f, 0.f, 0.f, 0.f};
            acc[mt][nt] = z;
        }

    for (int k0 = 0; k0 < DIMM; k0 += 64) {
#pragma unroll
        for (int i = 0; i < 4; ++i) {
            int lin = i*256 + tid;
            int r = lin >> 3, kc = (lin & 7)*8;
            *(uint4*)&As[r*LDT + kc] = *(const uint4*)(X + (size_t)(row0 + r)*DIMM + k0 + kc);
            *(uint4*)&Bs[r*LDT + kc] = *(const uint4*)(W + (size_t)(col0 + r)*DIMM + k0 + kc);
        }
        __syncthreads();
#pragma unroll
        for (int ks = 0; ks < 2; ++ks) {
            const int koff = ks*32 + l4*8;
            short8 aF[4], bF[4];
#pragma unroll
            for (int mt = 0; mt < 4; ++mt)
                aF[mt] = *(const short8*)&As[(wm + mt*16 + l15)*LDT + koff];
#pragma unroll
            for (int nt = 0; nt < 4; ++nt)
                bF[nt] = *(const short8*)&Bs[(wn + nt*16 + l15)*LDT + koff];
#pragma unroll
            for (int mt = 0; mt < 4; ++mt)
#pragma unroll
                for (int nt = 0; nt < 4; ++nt)
                    acc[mt][nt] = __builtin_amdgcn_mfma_f32_16x16x32_bf16(aF[mt], bF[nt], acc[mt][nt], 0, 0, 0);
        }
        __syncthreads();
    }

#pragma unroll
    for (int mt = 0; mt < 4; ++mt) {
#pragma unroll
        for (int nt = 0; nt < 4; ++nt) {
            const int c = col0 + wn + nt*16 + l15;
            const float bval = bias[c];
#pragma unroll
            for (int j = 0; j < 4; ++j) {
                const int r = row0 + wm + mt*16 + l4*4 + j;
                out[(size_t)r*DIMM + c] = acc[mt][nt][j] + bval;
            }
        }
    }
}

// ---------------------------------------------------------------------------
// Fused Q feature map: qp = RATIO*(exp(X@P^T - diag - rowmax) + EPS), bf16.
// (verified round 5)
// ---------------------------------------------------------------------------
__global__ __launch_bounds__(512)
void feat_gemm_q_kernel(const __hip_bfloat16* __restrict__ X, const float* __restrict__ P,
                        __hip_bfloat16* __restrict__ qp_b)
{
    constexpr int LDT = 72;
    __shared__ __hip_bfloat16 As[128*LDT];
    __shared__ __hip_bfloat16 Bs[256*LDT];
    __shared__ float rowmax[128][4];
    __shared__ float diagl[128];
    const int tid = threadIdx.x;
    const int lane = tid & 63, w = tid >> 6;
    const int wr = w >> 2, wc = w & 3;
    const int l15 = lane & 15, l4 = lane >> 4;
    const int row0 = blockIdx.x * 128;

#pragma unroll
    for (int i = 0; i < 2; ++i) {
        int lin = i*512 + tid;
        int r = lin >> 3, kc = (lin & 7)*8;
        *(uint4*)&As[r*LDT + kc] = *(const uint4*)(X + (size_t)(row0 + r)*64 + kc);
    }
#pragma unroll
    for (int i = 0; i < 8; ++i) {
        int lin = i*512 + tid;
        int r = lin >> 4, kc = (lin & 15)*4;
        float4 v = *(const float4*)(P + (size_t)r*64 + kc);
        *(ushort4*)&Bs[r*LDT + kc] = f2b4(v);
    }
    __syncthreads();

    f32x4 acc[4][4];
#pragma unroll
    for (int mt = 0; mt < 4; ++mt)
#pragma unroll
        for (int nt = 0; nt < 4; ++nt) {
            f32x4 z = {0.f,0.f,0.f,0.f};
            acc[mt][nt] = z;
        }
#pragma unroll
    for (int ks = 0; ks < 2; ++ks) {
        const int ko = ks*32 + l4*8;
        short8 aF[4], bF[4];
#pragma unroll
        for (int mt = 0; mt < 4; ++mt)
            aF[mt] = *(const short8*)&As[(wr*64 + mt*16 + l15)*LDT + ko];
#pragma unroll
        for (int nt = 0; nt < 4; ++nt)
            bF[nt] = *(const short8*)&Bs[(wc*64 + nt*16 + l15)*LDT + ko];
#pragma unroll
        for (int mt = 0; mt < 4; ++mt)
#pragma unroll
            for (int nt = 0; nt < 4; ++nt)
                acc[mt][nt] = __builtin_amdgcn_mfma_f32_16x16x32_bf16(aF[mt], bF[nt], acc[mt][nt], 0, 0, 0);
    }

    {
        const int r = tid >> 2, q = tid & 3;
        float s = 0.f;
#pragma unroll
        for (int i = 0; i < 16; ++i) {
            float x = __bfloat162float(As[r*LDT + q*16 + i]);
            s += x*x;
        }
        s += __shfl_xor(s, 1);
        s += __shfl_xor(s, 2);
        if (q == 0) diagl[r] = 0.5f * s;
    }
#pragma unroll
    for (int mt = 0; mt < 4; ++mt)
#pragma unroll
        for (int j = 0; j < 4; ++j) {
            float m = fmaxf(fmaxf(acc[mt][0][j], acc[mt][1][j]),
                            fmaxf(acc[mt][2][j], acc[mt][3][j]));
#pragma unroll
            for (int off = 8; off > 0; off >>= 1) m = fmaxf(m, __shfl_xor(m, off));
            if (l15 == 0) rowmax[wr*64 + mt*16 + l4*4 + j][wc] = m;
        }
    __syncthreads();

#pragma unroll
    for (int mt = 0; mt < 4; ++mt)
#pragma unroll
        for (int j = 0; j < 4; ++j) {
            const int r = wr*64 + mt*16 + l4*4 + j;
            const float stab = fmaxf(fmaxf(rowmax[r][0], rowmax[r][1]),
                                     fmaxf(rowmax[r][2], rowmax[r][3]));
            const float cc = diagl[r] + stab;
            const int gr = row0 + r;
            const int bl = gr >> 3, h = gr & 7;
            const int b = bl >> 11, l = bl & 2047;
            const size_t base = (((size_t)b*HH + h)*LL + l)*MM;
#pragma unroll
            for (int nt = 0; nt < 4; ++nt)
                qp_b[base + wc*64 + nt*16 + l15] =
                    __float2bfloat16(K_RATIO * (__expf(acc[mt][nt][j] - cc) + K_EPS));
        }
}

// ---------------------------------------------------------------------------
// K feature GEMM, TRANSPOSED f16 output with diag folded (verified round 6).
// ---------------------------------------------------------------------------
__global__ __launch_bounds__(512)
void feat_gemm_kT_kernel(const __hip_bfloat16* __restrict__ X, const float* __restrict__ P,
                         unsigned short* __restrict__ ddT, float* __restrict__ part)
{
    constexpr int LDT = 72;
    __shared__ __hip_bfloat16 As[128*LDT];
    __shared__ __hip_bfloat16 Bs[256*LDT];
    __shared__ float diagl[128];
    __shared__ float wmx[8];
    const int tid = threadIdx.x;
    const int lane = tid & 63, w = tid >> 6;
    const int wr = w >> 2, wc = w & 3;
    const int l15 = lane & 15, l4 = lane >> 4;
    const int bh = blockIdx.y;
    const int l0 = blockIdx.x * 128;

#pragma unroll
    for (int i = 0; i < 2; ++i) {
        int lin = i*512 + tid;
        int r = lin >> 3, kc = (lin & 7)*8;
        *(uint4*)&As[r*LDT + kc] = *(const uint4*)(X + ((size_t)bh*LL + l0 + r)*64 + kc);
    }
#pragma unroll
    for (int i = 0; i < 8; ++i) {
        int lin = i*512 + tid;
        int r = lin >> 4, kc = (lin & 15)*4;
        float4 v = *(const float4*)(P + (size_t)r*64 + kc);
        *(ushort4*)&Bs[r*LDT + kc] = f2b4(v);
    }
    __syncthreads();

    f32x4 acc[4][4];
#pragma unroll
    for (int mt = 0; mt < 4; ++mt)
#pragma unroll
        for (int nt = 0; nt < 4; ++nt) {
            f32x4 z = {0.f,0.f,0.f,0.f};
            acc[mt][nt] = z;
        }
#pragma unroll
    for (int ks = 0; ks < 2; ++ks) {
        const int ko = ks*32 + l4*8;
        short8 aF[4], bF[4];
#pragma unroll
        for (int mt = 0; mt < 4; ++mt)
            aF[mt] = *(const short8*)&As[(wr*64 + mt*16 + l15)*LDT + ko];
#pragma unroll
        for (int nt = 0; nt < 4; ++nt)
            bF[nt] = *(const short8*)&Bs[(wc*64 + nt*16 + l15)*LDT + ko];
#pragma unroll
        for (int mt = 0; mt < 4; ++mt)
#pragma unroll
            for (int nt = 0; nt < 4; ++nt)
                acc[mt][nt] = __builtin_amdgcn_mfma_f32_16x16x32_bf16(aF[mt], bF[nt], acc[mt][nt], 0, 0, 0);
    }

    {
        const int r = tid >> 2, q = tid & 3;
        float s = 0.f;
#pragma unroll
        for (int i = 0; i < 16; ++i) {
            float x = __bfloat162float(As[r*LDT + q*16 + i]);
            s += x*x;
        }
        s += __shfl_xor(s, 1);
        s += __shfl_xor(s, 2);
        if (q == 0) diagl[r] = 0.5f * s;
    }
    {
        float mx = -3.0e38f;
#pragma unroll
        for (int mt = 0; mt < 4; ++mt)
#pragma unroll
            for (int nt = 0; nt < 4; ++nt)
#pragma unroll
                for (int j = 0; j < 4; ++j)
                    mx = fmaxf(mx, acc[mt][nt][j]);
#pragma unroll
        for (int off = 32; off > 0; off >>= 1) mx = fmaxf(mx, __shfl_xor(mx, off));
        if (lane == 0) wmx[w] = mx;
    }
    __syncthreads();
    if (tid == 0) {
        float mx = wmx[0];
#pragma unroll
        for (int i = 1; i < 8; ++i) mx = fmaxf(mx, wmx[i]);
        part[blockIdx.y*16 + blockIdx.x] = mx;
    }

#pragma unroll
    for (int mt = 0; mt < 4; ++mt) {
#pragma unroll
        for (int nt = 0; nt < 4; ++nt) {
            const int m = wc*64 + nt*16 + l15;
            const int rbase = wr*64 + mt*16 + l4*4;
            ushort4 o;
            o.x = f2h_u16(acc[mt][nt][0] - diagl[rbase+0]);
            o.y = f2h_u16(acc[mt][nt][1] - diagl[rbase+1]);
            o.z = f2h_u16(acc[mt][nt][2] - diagl[rbase+2]);
            o.w = f2h_u16(acc[mt][nt][3] - diagl[rbase+3]);
            *(ushort4*)(ddT + ((size_t)bh*MM + m)*LL + l0 + rbase) = o;
        }
    }
}

__global__ __launch_bounds__(256)
void kmax_final_kernel(const float* __restrict__ part, float* __restrict__ gmax)
{
    float mx = -3.0e38f;
    for (int i = threadIdx.x; i < 512; i += 256) mx = fmaxf(mx, part[i]);
#pragma unroll
    for (int off = 32; off > 0; off >>= 1) mx = fmaxf(mx, __shfl_xor(mx, off));
    __shared__ float wsm[4];
    if ((threadIdx.x & 63) == 0) wsm[threadIdx.x >> 6] = mx;
    __syncthreads();
    if (threadIdx.x == 0) gmax[0] = fmaxf(fmaxf(wsm[0], wsm[1]), fmaxf(wsm[2], wsm[3]));
}

// ---------------------------------------------------------------------------
// vw [B,H,L,D] bf16  ->  vT [B,H,D,L] bf16  (tiled LDS transpose)
// ---------------------------------------------------------------------------
__global__ __launch_bounds__(256)
void transpose_v_kernel(const __hip_bfloat16* __restrict__ vw, __hip_bfloat16* __restrict__ vT)
{
    __shared__ unsigned short vl[64][72];
    const int bh = blockIdx.y;
    const int l0 = blockIdx.x*64;
    const __hip_bfloat16* src = vw + ((size_t)bh*LL + l0)*DD;
#pragma unroll
    for (int it = 0; it < 2; ++it) {
        int lin = it*256 + threadIdx.x;       // 0..511
        int t = lin >> 3, c8 = (lin & 7)*8;
        *(uint4*)&vl[t][c8] = *(const uint4*)(src + (size_t)t*DD + c8);
    }
    __syncthreads();
    const int d = threadIdx.x >> 2, q = threadIdx.x & 3;
    __hip_bfloat16* dst = vT + ((size_t)bh*DD + d)*LL + l0 + q*16;
#pragma unroll
    for (int g = 0; g < 4; ++g) {
        ushort4 o;
        o.x = vl[q*16+g*4+0][d];
        o.y = vl[q*16+g*4+1][d];
        o.z = vl[q*16+g*4+2][d];
        o.w = vl[q*16+g*4+3][d];
        *(ushort4*)(dst + g*4) = o;
    }
}

// ---------------------------------------------------------------------------
// Per-chunk state (fully parallel, MFMA; verified round 7).
// ---------------------------------------------------------------------------
__global__ __launch_bounds__(256)
void chunk_state_mfma_kernel(const unsigned short* __restrict__ ddT,
                             const __hip_bfloat16* __restrict__ vT_b,
                             const float* __restrict__ gmax,
                             __hip_bfloat16* __restrict__ Sci_b,
                             float* __restrict__ skc,
                             __hip_bfloat16* __restrict__ kp_b)
{
    __shared__ __hip_bfloat16 kT[256*72];
    __shared__ __hip_bfloat16 vT[64*72];
    const int c = blockIdx.x, bh = blockIdx.y;
    const int tid = threadIdx.x, lane = tid & 63, w = tid >> 6;
    const int l15 = lane & 15, l4 = lane >> 4;
    const float gm = gmax[0];
    char* kbuf = (char*)&kT[0];
    char* vbuf = (char*)&vT[0];

    {
        const unsigned short* ksrc = ddT + ((size_t)bh*MM + tid)*LL + (size_t)c*64;
#pragma unroll
        for (int o = 0; o < 8; ++o) {
            uint4 r0 = *(const uint4*)(ksrc + o*8);
            const unsigned short* u0 = (const unsigned short*)&r0;
            unsigned short p0[8];
#pragma unroll
            for (int i = 0; i < 8; ++i)
                p0[i] = f2b_u16(K_RATIO * (__expf(h2f(u0[i]) - gm) + K_EPS));
            *(uint4*)(kbuf + KSWZ(tid, o*8)) = *(uint4*)&p0[0];
        }
        const int sr = tid >> 2, sq = tid & 3;
        const __hip_bfloat16* vsrc = vT_b + ((size_t)bh*DD + sr)*LL + (size_t)c*64 + sq*16;
        *(uint4*)(vbuf + sr*144 + sq*32)      = *(const uint4*)(vsrc);
        *(uint4*)(vbuf + sr*144 + sq*32 + 16) = *(const uint4*)(vsrc + 8);
    }
    __syncthreads();

    f32x4 accS[4][4];   // [dt][mt]
    f32x4 accK[4];
#pragma unroll
    for (int i = 0; i < 4; ++i) {
#pragma unroll
        for (int j = 0; j < 4; ++j) { f32x4 z = {0.f,0.f,0.f,0.f}; accS[i][j] = z; }
        f32x4 z = {0.f,0.f,0.f,0.f}; accK[i] = z;
    }
    short8 ones8;
    {
        const short ov = (short)0x3F80;   // bf16 1.0
#pragma unroll
        for (int i = 0; i < 8; ++i) ones8[i] = (l15 == 0) ? ov : (short)0;
    }

#pragma unroll
    for (int ks = 0; ks < 2; ++ks) {
        const int ko = ks*32 + l4*8;
        short8 bF[4], aF[4];
#pragma unroll
        for (int mt = 0; mt < 4; ++mt)
            bF[mt] = *(const short8*)(kbuf + KSWZ(w*64 + mt*16 + l15, ko));
#pragma unroll
        for (int dt = 0; dt < 4; ++dt)
            aF[dt] = *(const short8*)(vbuf + (dt*16 + l15)*144 + ko*2);
#pragma unroll
        for (int dt = 0; dt < 4; ++dt)
#pragma unroll
            for (int mt = 0; mt < 4; ++mt)
                accS[dt][mt] = __builtin_amdgcn_mfma_f32_16x16x32_bf16(aF[dt], bF[mt], accS[dt][mt], 0, 0, 0);
#pragma unroll
        for (int mt = 0; mt < 4; ++mt)
            accK[mt] = __builtin_amdgcn_mfma_f32_16x16x32_bf16(ones8, bF[mt], accK[mt], 0, 0, 0);
    }

    __hip_bfloat16* So = Sci_b + ((size_t)(bh*NCHUNK + c))*(MM*DD);
#pragma unroll
    for (int dt = 0; dt < 4; ++dt)
#pragma unroll
        for (int mt = 0; mt < 4; ++mt) {
            const int m = w*64 + mt*16 + l15;
#pragma unroll
            for (int j = 0; j < 4; ++j)
                So[(size_t)(dt*16 + l4*4 + j)*MM + m] = __float2bfloat16(accS[dt][mt][j]);
        }
    if (l4 == 0) {
#pragma unroll
        for (int mt = 0; mt < 4; ++mt)
            skc[((size_t)bh*NCHUNK + c)*MM + w*64 + mt*16 + l15] = accK[mt][0];
    }

    {
        const int t2 = w*16 + (lane >> 2);
        const int m0 = (lane & 3)*16;
        __hip_bfloat16* krow = kp_b + ((size_t)bh*LL + (size_t)c*64 + t2)*MM;
#pragma unroll
        for (int seg = 0; seg < 4; ++seg) {
            unsigned short vals[16];
#pragma unroll
            for (int i = 0; i < 16; ++i)
                vals[i] = *(const unsigned short*)(kbuf + KSWZ(seg*64 + m0 + i, t2));
            *(uint4*)(krow + seg*64 + m0)     = *(uint4*)&vals[0];
            *(uint4*)(krow + seg*64 + m0 + 8) = *(uint4*)&vals[8];
        }
    }
}

// ---------------------------------------------------------------------------
// Exclusive prefix over chunks, IN PLACE (verified round 7).
// ---------------------------------------------------------------------------
__global__ __launch_bounds__(256)
void chunk_prefix_kernel(__hip_bfloat16* __restrict__ S_b, float* __restrict__ skc)
{
    const int bh = blockIdx.y;
    const int e4 = blockIdx.x*256 + threadIdx.x;
    __hip_bfloat16* base = S_b + (size_t)bh*NCHUNK*(MM*DD) + (size_t)e4*4;
    float4 run = {0.f, 0.f, 0.f, 0.f};
#pragma unroll 4
    for (int c = 0; c < NCHUNK; ++c) {
        __hip_bfloat16* p = base + (size_t)c*(MM*DD);
        ushort4 t = *(ushort4*)p;
        ushort4 o;
        o.x = f2b_u16(run.x); o.y = f2b_u16(run.y);
        o.z = f2b_u16(run.z); o.w = f2b_u16(run.w);
        *(ushort4*)p = o;
        run.x += b2f_u16(t.x); run.y += b2f_u16(t.y);
        run.z += b2f_u16(t.z); run.w += b2f_u16(t.w);
    }
    if (blockIdx.x == 0) {
        float* kb = skc + (size_t)bh*NCHUNK*MM + threadIdx.x;
        float s2 = 0.f;
#pragma unroll 4
        for (int c = 0; c < NCHUNK; ++c) {
            float t = kb[(size_t)c*MM];
            kb[(size_t)c*MM] = s2;
            s2 += t;
        }
    }
}

// ---------------------------------------------------------------------------
// MFMA chunk_out (verified round 4, unchanged).
// ---------------------------------------------------------------------------
__global__ __launch_bounds__(256)
void chunk_out_kernel(const __hip_bfloat16* __restrict__ qp_b,
                      const __hip_bfloat16* __restrict__ kp_b,
                      const __hip_bfloat16* __restrict__ vT_b,
                      const __hip_bfloat16* __restrict__ ScT_b,
                      const float* __restrict__ skp,
                      __hip_bfloat16* __restrict__ attn)
{
    constexpr int LDQ = 72;
    constexpr int LDA = 72;
    __shared__ __hip_bfloat16 Qs[64*LDQ];
    __shared__ __hip_bfloat16 Ks[64*LDQ];
    __shared__ __hip_bfloat16 Ss[80*LDQ];
    __shared__ __hip_bfloat16 Al[64*LDA];
    __shared__ __hip_bfloat16 Vl[80*LDA];

    const int c = blockIdx.x, h = blockIdx.y, b = blockIdx.z;
    const size_t bh = (size_t)b*HH + h;
    const __hip_bfloat16* qpc = qp_b + (bh*LL + (size_t)c*TT) * MM;
    const __hip_bfloat16* kpc = kp_b + (bh*LL + (size_t)c*TT) * MM;
    const __hip_bfloat16* vTc = vT_b + bh*(size_t)(DD*LL) + (size_t)c*TT;
    const __hip_bfloat16* Scc = ScT_b + (bh*NCHUNK + (size_t)c) * (MM*DD);
    const float* skrow = skp + (bh*NCHUNK + (size_t)c) * MM;

    const int tid = threadIdx.x;
    const int lane = tid & 63;
    const int w = tid >> 6;
    const int l15 = lane & 15, l4 = lane >> 4;

    {
#pragma unroll
        for (int it = 0; it < 2; ++it) {
            int lin = it*256 + tid;
            int d = lin >> 3, c8 = (lin & 7)*8;
            *(uint4*)&Vl[d*LDA + c8] = *(const uint4*)(vTc + (size_t)d*LL + c8);
        }
        const __hip_bfloat16 one = __float2bfloat16(1.0f);
        const __hip_bfloat16 zero = __float2bfloat16(0.0f);
        for (int idx = tid; idx < 16*64; idx += 256) {
            int rr = idx >> 6, cc2 = idx & 63;
            Vl[(64+rr)*LDA + cc2] = (rr == 0) ? one : zero;
        }
        for (int idx = tid; idx < 15*64; idx += 256) {
            int rr = idx / 64, cc2 = idx % 64;
            Ss[(65+rr)*LDQ + cc2] = zero;
        }
    }

    f32x4 accA[4];
    f32x4 accO[5];
#pragma unroll
    for (int i = 0; i < 4; ++i) { f32x4 z = {0.f,0.f,0.f,0.f}; accA[i] = z; }
#pragma unroll
    for (int i = 0; i < 5; ++i) { f32x4 z = {0.f,0.f,0.f,0.f}; accO[i] = z; }

    for (int mq = 0; mq < MM; mq += 64) {
        __syncthreads();
#pragma unroll
        for (int it = 0; it < 2; ++it) {
            int lin = it*256 + tid;
            int r = lin >> 3, m8 = (lin & 7)*8;
            *(uint4*)&Qs[r*LDQ + m8] = *(const uint4*)(qpc + (size_t)r*MM + mq + m8);
            *(uint4*)&Ks[r*LDQ + m8] = *(const uint4*)(kpc + (size_t)r*MM + mq + m8);
            *(uint4*)&Ss[r*LDQ + m8] = *(const uint4*)(Scc + (size_t)r*MM + mq + m8);
        }
        if (tid < 64) Ss[64*LDQ + tid] = __float2bfloat16(skrow[mq + tid]);
        __syncthreads();
#pragma unroll
        for (int ks = 0; ks < 2; ++ks) {
            const int ko = ks*32 + l4*8;
            short8 aF = *(const short8*)&Qs[(w*16 + l15)*LDQ + ko];
#pragma unroll
            for (int nt = 0; nt < 4; ++nt) {
                short8 bF = *(const short8*)&Ks[(nt*16 + l15)*LDQ + ko];
                accA[nt] = __builtin_amdgcn_mfma_f32_16x16x32_bf16(aF, bF, accA[nt], 0, 0, 0);
            }
#pragma unroll
            for (int nt = 0; nt < 5; ++nt) {
                short8 sF = *(const short8*)&Ss[(nt*16 + l15)*LDQ + ko];
                accO[nt] = __builtin_amdgcn_mfma_f32_16x16x32_bf16(aF, sF, accO[nt], 0, 0, 0);
            }
        }
    }
    __syncthreads();
#pragma unroll
    for (int nt = 0; nt < 4; ++nt) {
        const int s = nt*16 + l15;
#pragma unroll
        for (int j = 0; j < 4; ++j) {
            const int t = w*16 + l4*4 + j;
            const float v = (s <= t) ? accA[nt][j] : 0.f;
            Al[t*LDA + s] = __float2bfloat16(v);
        }
    }
    __syncthreads();
#pragma unroll
    for (int ks = 0; ks < 2; ++ks) {
        const int ko = ks*32 + l4*8;
        short8 aF = *(const short8*)&Al[(w*16 + l15)*LDA + ko];
#pragma unroll
        for (int nt = 0; nt < 5; ++nt) {
            short8 vF = *(const short8*)&Vl[(nt*16 + l15)*LDA + ko];
            accO[nt] = __builtin_amdgcn_mfma_f32_16x16x32_bf16(aF, vF, accO[nt], 0, 0, 0);
        }
    }
    __hip_bfloat16* arow = attn + ((size_t)b*LL + (size_t)c*TT) * DIMM + h*DD;
#pragma unroll
    for (int j = 0; j < 4; ++j) {
        const float den = __shfl(accO[4][j], (lane & 48));
        const float inv = 1.0f / den;
        const int t = w*16 + l4*4 + j;
#pragma unroll
        for (int nt = 0; nt < 4; ++nt) {
            const int d = nt*16 + l15;
            arow[(size_t)t*DIMM + d] = __float2bfloat16(accO[nt][j] * inv);
        }
    }
}

// ---------------------------------------------------------------------------
extern "C" void kernel_launch(void* const* d_in, const int* in_sizes, int n_in,
                              void* d_out, int out_size, void* d_ws, size_t ws_size,
                              hipStream_t stream)
{
    (void)in_sizes; (void)n_in; (void)out_size; (void)ws_size;
    const float* query = (const float*)d_in[0];
    const float* key   = (const float*)d_in[1];
    const float* value = (const float*)d_in[2];
    const float* Wq = (const float*)d_in[3];
    const float* bq = (const float*)d_in[4];
    const float* Wk = (const float*)d_in[5];
    const float* bk = (const float*)d_in[6];
    const float* Wv = (const float*)d_in[7];
    const float* bv = (const float*)d_in[8];
    const float* Wo = (const float*)d_in[9];
    const float* bo = (const float*)d_in[10];
    const float* proj = (const float*)d_in[11];

    float* ws = (float*)d_ws;
    // Workspace peak ~196 MB (f32-word offsets).
    unsigned short* ddT   = (unsigned short*)ws;                 // 16.7M f16  [bh][m][l]
    __hip_bfloat16* qp_b  = (__hip_bfloat16*)(ws +  8388608);
    __hip_bfloat16* kp_b  = (__hip_bfloat16*)(ws + 16777216);
    __hip_bfloat16* ScT_b = (__hip_bfloat16*)(ws + 25165824);
    __hip_bfloat16* vw_b  = (__hip_bfloat16*)(ws + 33554432);    // [bh][l][64] bf16
    __hip_bfloat16* vT_b  = (__hip_bfloat16*)(ws + 35651584);    // [bh][d][L] bf16
    __hip_bfloat16* qsb   = (__hip_bfloat16*)(ws + 37748736);
    __hip_bfloat16* ksw_b = (__hip_bfloat16*)(ws + 39845888);
    __hip_bfloat16* qbi   = (__hip_bfloat16*)(ws + 41943040);    // bf16 input casts
    __hip_bfloat16* kbi   = (__hip_bfloat16*)(ws + 44040192);
    __hip_bfloat16* vbi   = (__hip_bfloat16*)(ws + 46137344);
    __hip_bfloat16* Wqb   = (__hip_bfloat16*)(ws + 48234496);
    __hip_bfloat16* Wkb   = (__hip_bfloat16*)(ws + 48365568);
    __hip_bfloat16* Wvb   = (__hip_bfloat16*)(ws + 48496640);
    __hip_bfloat16* Wob   = (__hip_bfloat16*)(ws + 48627712);
    float* skc            = ws + 48758784;                       // 262,144 f32
    float* part           = ws + 49020928;                       // 512
    float* gmax           = ws + 49021440;                       // 1
    __hip_bfloat16* attn_b = qsb;   // qsb dead after feat_gemm_q

    const dim3 blk(256);

    // input/weight bf16 casts (same rounding as previous in-staging converts)
    cast_qkv_kernel<<<2048, blk, 0, stream>>>(query, key, value, qbi, kbi, vbi);
    cast_w_kernel<<<256, blk, 0, stream>>>(Wq, Wk, Wv, Wo, Wqb, Wkb, Wvb, Wob);

    // merged q/k/v projections (bf16 operands, XCD-grouped tiles)
    qkv_proj_kernel<<<dim3(4,64,3), blk, 0, stream>>>(qbi, kbi, vbi,
                                                      Wqb, bq, Wkb, bk, Wvb, bv,
                                                      qsb, ksw_b, vw_b);

    // v transpose -> bf16 [B,H,D,L]
    transpose_v_kernel<<<dim3(32,32), blk, 0, stream>>>(vw_b, vT_b);

    // Q path: fused feature GEMM + softmax-map
    feat_gemm_q_kernel<<<512, dim3(512), 0, stream>>>(qsb, proj, qp_b);

    // K path: feature GEMM -> ddT f16 (diag folded, transposed) + block max
    feat_gemm_kT_kernel<<<dim3(16,32), dim3(512), 0, stream>>>(ksw_b, proj, ddT, part);
    kmax_final_kernel<<<1, blk, 0, stream>>>(part, gmax);

    // parallel per-chunk states (+ exp + kp_b emit), then in-place prefix
    chunk_state_mfma_kernel<<<dim3(NCHUNK,32), blk, 0, stream>>>(ddT, vT_b, gmax, ScT_b, skc, kp_b);
    chunk_prefix_kernel<<<dim3(16,32), blk, 0, stream>>>(ScT_b, skc);

    // chunk output
    chunk_out_kernel<<<dim3(NCHUNK,HH,BB), blk, 0, stream>>>(qp_b, kp_b, vT_b, ScT_b, skc, attn_b);

    // output projection
    gemm_wo_kernel<<<dim3(4,64), blk, 0, stream>>>(attn_b, Wob, bo, (float*)d_out);
}

// Round 9
// 168.098 us; speedup vs baseline: 4.0841x; 1.0025x over previous
//
#include <hip/hip_runtime.h>
#include <hip/hip_bf16.h>
#include <math.h>

// Problem constants
#define BB 4
#define LL 2048
#define HH 8
#define DD 64          // head dim
#define MM 256         // nb_features
#define DIMM 512
#define TT 64          // chunk length
#define NCHUNK (LL/TT) // 32

constexpr float K_SCALE = 0.35355339059327379f; // 64^-0.25
constexpr float K_RATIO = 0.0625f;              // 256^-0.5
constexpr float K_EPS   = 1e-6f;

using short8 = __attribute__((ext_vector_type(8))) short;
using f32x4  = __attribute__((ext_vector_type(4))) float;
typedef _Float16 f16_t;

__device__ inline unsigned short f2b_u16(float x) {
    __hip_bfloat16 h = __float2bfloat16(x);
    return *reinterpret_cast<unsigned short*>(&h);
}
__device__ inline ushort4 f2b4(float4 v) {
    ushort4 o; o.x = f2b_u16(v.x); o.y = f2b_u16(v.y); o.z = f2b_u16(v.z); o.w = f2b_u16(v.w);
    return o;
}
__device__ inline unsigned short f2h_u16(float x) {
    f16_t h = (f16_t)x;
    return *reinterpret_cast<unsigned short*>(&h);
}
__device__ inline float h2f(unsigned short u) {
    f16_t h = *reinterpret_cast<f16_t*>(&u);
    return (float)h;
}
__device__ inline float b2f_u16(unsigned short u) {
    __hip_bfloat16 h = *reinterpret_cast<__hip_bfloat16*>(&u);
    return __bfloat162float(h);
}

// async global->LDS, 16B per lane (m97 pattern)
#define GLOAD_LDS16(g, l)                                                              \
    __builtin_amdgcn_global_load_lds(                                                  \
        (const __attribute__((address_space(1))) unsigned int*)(g),                    \
        (__attribute__((address_space(3))) unsigned int*)(l), 16, 0, 0)

// XOR-swizzled byte offset into the chunk_state kT tile ([m][t] bf16, row
// stride 72 elems = 144B).
#define KSWZ(m, te) ((((m)*144) + ((te)*2)) ^ ((((m)>>3) & 3) << 4))

// XCD-grouping tile swizzle for 256-tile GEMM grids (gridDim (4,64)).
__device__ inline void xcd_tiles(int* rt, int* ct) {
    const int fid = blockIdx.x + (gridDim.x * blockIdx.y);  // 0..255
    const int xcd = fid & 7;
    const int g   = fid >> 3;
    *rt = xcd*8 + (g >> 2);
    *ct = g & 3;
}

// ---------------------------------------------------------------------------
// f32 -> bf16 casts
// ---------------------------------------------------------------------------
__global__ __launch_bounds__(256)
void cast_qkv_kernel(const float* __restrict__ q, const float* __restrict__ k,
                     const float* __restrict__ v,
                     __hip_bfloat16* __restrict__ qo, __hip_bfloat16* __restrict__ ko,
                     __hip_bfloat16* __restrict__ vo)
{
    const int total = 3 << 20;
    for (int i = blockIdx.x*256 + threadIdx.x; i < total; i += gridDim.x*256) {
        const int t = i >> 20, j = i & ((1 << 20) - 1);
        const float* src = (t == 0) ? q : (t == 1) ? k : v;
        __hip_bfloat16* dst = (t == 0) ? qo : (t == 1) ? ko : vo;
        float4 x = reinterpret_cast<const float4*>(src)[j];
        reinterpret_cast<ushort4*>(dst)[j] = f2b4(x);
    }
}

__global__ __launch_bounds__(256)
void cast_w_kernel(const float* __restrict__ w0, const float* __restrict__ w1,
                   const float* __restrict__ w2, const float* __restrict__ w3,
                   __hip_bfloat16* __restrict__ o0, __hip_bfloat16* __restrict__ o1,
                   __hip_bfloat16* __restrict__ o2, __hip_bfloat16* __restrict__ o3)
{
    const int total = 4 << 16;
    for (int i = blockIdx.x*256 + threadIdx.x; i < total; i += gridDim.x*256) {
        const int t = i >> 16, j = i & ((1 << 16) - 1);
        const float* src = (t == 0) ? w0 : (t == 1) ? w1 : (t == 2) ? w2 : w3;
        __hip_bfloat16* dst = (t == 0) ? o0 : (t == 1) ? o1 : (t == 2) ? o2 : o3;
        float4 x = reinterpret_cast<const float4*>(src)[j];
        reinterpret_cast<ushort4*>(dst)[j] = f2b4(x);
    }
}

// ---------------------------------------------------------------------------
// Merged q/k/v projection, bf16 operands, XCD-grouped tiles,
// global_load_lds staging into linear 128x64 LDS with XOR-swizzle
// (linear dest + inverse-swizzled SOURCE + swizzled READ — rule #21).
// ---------------------------------------------------------------------------
__global__ __launch_bounds__(256)
void qkv_proj_kernel(const __hip_bfloat16* __restrict__ Xq, const __hip_bfloat16* __restrict__ Xk,
                     const __hip_bfloat16* __restrict__ Xv,
                     const __hip_bfloat16* __restrict__ Wq, const float* __restrict__ bq,
                     const __hip_bfloat16* __restrict__ Wk, const float* __restrict__ bk,
                     const __hip_bfloat16* __restrict__ Wv, const float* __restrict__ bv,
                     __hip_bfloat16* __restrict__ qsb, __hip_bfloat16* __restrict__ ksw,
                     __hip_bfloat16* __restrict__ vw)
{
    __shared__ __hip_bfloat16 As[128*64];   // linear [r][k], 16KB
    __shared__ __hip_bfloat16 Bs[128*64];
    const int z = blockIdx.z;
    const __hip_bfloat16* X = (z == 0) ? Xq : (z == 1) ? Xk : Xv;
    const __hip_bfloat16* W = (z == 0) ? Wq : (z == 1) ? Wk : Wv;
    const float* bias = (z == 0) ? bq : (z == 1) ? bk : bv;
    const float postscale = (z == 2) ? 1.0f : K_SCALE;

    int rt, ct;
    xcd_tiles(&rt, &ct);
    const int row0 = rt*128, col0 = ct*128;

    const int tid = threadIdx.x;
    const int lane = tid & 63;
    const int w = tid >> 6;
    const int wm = (w >> 1) * 64, wn = (w & 1) * 64;
    const int l15 = lane & 15, l4 = lane >> 4;

    f32x4 acc[4][4];
#pragma unroll
    for (int mt = 0; mt < 4; ++mt)
#pragma unroll
        for (int nt = 0; nt < 4; ++nt) {
            f32x4 zf = {0.f, 0.f, 0.f, 0.f};
            acc[mt][nt] = zf;
        }

    for (int k0 = 0; k0 < DIMM; k0 += 64) {
#pragma unroll
        for (int i = 0; i < 4; ++i) {
            const int p = (i*256 + tid) * 16;            // LDS byte offset
            const int r = p >> 7;                        // tile row (128B rows)
            const int cb = (p & 127) ^ ((r & 7) << 4);   // inverse-swizzled src col-byte
            GLOAD_LDS16(X + (size_t)(row0 + r)*DIMM + k0 + (cb >> 1), (char*)As + p);
            GLOAD_LDS16(W + (size_t)(col0 + r)*DIMM + k0 + (cb >> 1), (char*)Bs + p);
        }
        __syncthreads();
#pragma unroll
        for (int ks = 0; ks < 2; ++ks) {
            short8 aF[4], bF[4];
#pragma unroll
            for (int mt = 0; mt < 4; ++mt) {
                const int row = wm + mt*16 + l15;
                const int cb = (ks*64 + l4*16) ^ ((row & 7) << 4);
                aF[mt] = *(const short8*)((const char*)As + row*128 + cb);
            }
#pragma unroll
            for (int nt = 0; nt < 4; ++nt) {
                const int row = wn + nt*16 + l15;
                const int cb = (ks*64 + l4*16) ^ ((row & 7) << 4);
                bF[nt] = *(const short8*)((const char*)Bs + row*128 + cb);
            }
#pragma unroll
            for (int mt = 0; mt < 4; ++mt)
#pragma unroll
                for (int nt = 0; nt < 4; ++nt)
                    acc[mt][nt] = __builtin_amdgcn_mfma_f32_16x16x32_bf16(aF[mt], bF[nt], acc[mt][nt], 0, 0, 0);
        }
        __syncthreads();
    }

#pragma unroll
    for (int mt = 0; mt < 4; ++mt) {
#pragma unroll
        for (int nt = 0; nt < 4; ++nt) {
            const int c = col0 + wn + nt*16 + l15;
            const float bval = bias[c];
#pragma unroll
            for (int j = 0; j < 4; ++j) {
                const int r = row0 + wm + mt*16 + l4*4 + j;
                const float val = (acc[mt][nt][j] + bval) * postscale;
                if (z == 0) {
                    qsb[(size_t)r*DIMM + c] = __float2bfloat16(val);
                } else {
                    const int b = r >> 11, l = r & 2047;
                    const int hh = c >> 6, d = c & 63;
                    const size_t idx = (((size_t)b*HH + hh)*LL + l)*DD + d;
                    if (z == 1) ksw[idx] = __float2bfloat16(val);
                    else        vw[idx] = __float2bfloat16(val);
                }
            }
        }
    }
}

// ---------------------------------------------------------------------------
// Final Wo GEMM, same m97-style staging.
// ---------------------------------------------------------------------------
__global__ __launch_bounds__(256)
void gemm_wo_kernel(const __hip_bfloat16* __restrict__ X, const __hip_bfloat16* __restrict__ W,
                    const float* __restrict__ bias, float* __restrict__ out)
{
    __shared__ __hip_bfloat16 As[128*64];
    __shared__ __hip_bfloat16 Bs[128*64];
    int rt, ct;
    xcd_tiles(&rt, &ct);
    const int row0 = rt*128, col0 = ct*128;
    const int tid = threadIdx.x;
    const int lane = tid & 63;
    const int w = tid >> 6;
    const int wm = (w >> 1) * 64, wn = (w & 1) * 64;
    const int l15 = lane & 15, l4 = lane >> 4;

    f32x4 acc[4][4];
#pragma unroll
    for (int mt = 0; mt < 4; ++mt)
#pragma unroll
        for (int nt = 0; nt < 4; ++nt) {
            f32x4 z = {0.f, 0.f, 0.f, 0.f};
            acc[mt][nt] = z;
        }

    for (int k0 = 0; k0 < DIMM; k0 += 64) {
#pragma unroll
        for (int i = 0; i < 4; ++i) {
            const int p = (i*256 + tid) * 16;
            const int r = p >> 7;
            const int cb = (p & 127) ^ ((r & 7) << 4);
            GLOAD_LDS16(X + (size_t)(row0 + r)*DIMM + k0 + (cb >> 1), (char*)As + p);
            GLOAD_LDS16(W + (size_t)(col0 + r)*DIMM + k0 + (cb >> 1), (char*)Bs + p);
        }
        __syncthreads();
#pragma unroll
        for (int ks = 0; ks < 2; ++ks) {
            short8 aF[4], bF[4];
#pragma unroll
            for (int mt = 0; mt < 4; ++mt) {
                const int row = wm + mt*16 + l15;
                const int cb = (ks*64 + l4*16) ^ ((row & 7) << 4);
                aF[mt] = *(const short8*)((const char*)As + row*128 + cb);
            }
#pragma unroll
            for (int nt = 0; nt < 4; ++nt) {
                const int row = wn + nt*16 + l15;
                const int cb = (ks*64 + l4*16) ^ ((row & 7) << 4);
                bF[nt] = *(const short8*)((const char*)Bs + row*128 + cb);
            }
#pragma unroll
            for (int mt = 0; mt < 4; ++mt)
#pragma unroll
                for (int nt = 0; nt < 4; ++nt)
                    acc[mt][nt] = __builtin_amdgcn_mfma_f32_16x16x32_bf16(aF[mt], bF[nt], acc[mt][nt], 0, 0, 0);
        }
        __syncthreads();
    }

#pragma unroll
    for (int mt = 0; mt < 4; ++mt) {
#pragma unroll
        for (int nt = 0; nt < 4; ++nt) {
            const int c = col0 + wn + nt*16 + l15;
            const float bval = bias[c];
#pragma unroll
            for (int j = 0; j < 4; ++j) {
                const int r = row0 + wm + mt*16 + l4*4 + j;
                out[(size_t)r*DIMM + c] = acc[mt][nt][j] + bval;
            }
        }
    }
}

// ---------------------------------------------------------------------------
// Fused Q feature map (verified round 5, unchanged).
// ---------------------------------------------------------------------------
__global__ __launch_bounds__(512)
void feat_gemm_q_kernel(const __hip_bfloat16* __restrict__ X, const float* __restrict__ P,
                        __hip_bfloat16* __restrict__ qp_b)
{
    constexpr int LDT = 72;
    __shared__ __hip_bfloat16 As[128*LDT];
    __shared__ __hip_bfloat16 Bs[256*LDT];
    __shared__ float rowmax[128][4];
    __shared__ float diagl[128];
    const int tid = threadIdx.x;
    const int lane = tid & 63, w = tid >> 6;
    const int wr = w >> 2, wc = w & 3;
    const int l15 = lane & 15, l4 = lane >> 4;
    const int row0 = blockIdx.x * 128;

#pragma unroll
    for (int i = 0; i < 2; ++i) {
        int lin = i*512 + tid;
        int r = lin >> 3, kc = (lin & 7)*8;
        *(uint4*)&As[r*LDT + kc] = *(const uint4*)(X + (size_t)(row0 + r)*64 + kc);
    }
#pragma unroll
    for (int i = 0; i < 8; ++i) {
        int lin = i*512 + tid;
        int r = lin >> 4, kc = (lin & 15)*4;
        float4 v = *(const float4*)(P + (size_t)r*64 + kc);
        *(ushort4*)&Bs[r*LDT + kc] = f2b4(v);
    }
    __syncthreads();

    f32x4 acc[4][4];
#pragma unroll
    for (int mt = 0; mt < 4; ++mt)
#pragma unroll
        for (int nt = 0; nt < 4; ++nt) {
            f32x4 z = {0.f,0.f,0.f,0.f};
            acc[mt][nt] = z;
        }
#pragma unroll
    for (int ks = 0; ks < 2; ++ks) {
        const int ko = ks*32 + l4*8;
        short8 aF[4], bF[4];
#pragma unroll
        for (int mt = 0; mt < 4; ++mt)
            aF[mt] = *(const short8*)&As[(wr*64 + mt*16 + l15)*LDT + ko];
#pragma unroll
        for (int nt = 0; nt < 4; ++nt)
            bF[nt] = *(const short8*)&Bs[(wc*64 + nt*16 + l15)*LDT + ko];
#pragma unroll
        for (int mt = 0; mt < 4; ++mt)
#pragma unroll
            for (int nt = 0; nt < 4; ++nt)
                acc[mt][nt] = __builtin_amdgcn_mfma_f32_16x16x32_bf16(aF[mt], bF[nt], acc[mt][nt], 0, 0, 0);
    }

    {
        const int r = tid >> 2, q = tid & 3;
        float s = 0.f;
#pragma unroll
        for (int i = 0; i < 16; ++i) {
            float x = __bfloat162float(As[r*LDT + q*16 + i]);
            s += x*x;
        }
        s += __shfl_xor(s, 1);
        s += __shfl_xor(s, 2);
        if (q == 0) diagl[r] = 0.5f * s;
    }
#pragma unroll
    for (int mt = 0; mt < 4; ++mt)
#pragma unroll
        for (int j = 0; j < 4; ++j) {
            float m = fmaxf(fmaxf(acc[mt][0][j], acc[mt][1][j]),
                            fmaxf(acc[mt][2][j], acc[mt][3][j]));
#pragma unroll
            for (int off = 8; off > 0; off >>= 1) m = fmaxf(m, __shfl_xor(m, off));
            if (l15 == 0) rowmax[wr*64 + mt*16 + l4*4 + j][wc] = m;
        }
    __syncthreads();

#pragma unroll
    for (int mt = 0; mt < 4; ++mt)
#pragma unroll
        for (int j = 0; j < 4; ++j) {
            const int r = wr*64 + mt*16 + l4*4 + j;
            const float stab = fmaxf(fmaxf(rowmax[r][0], rowmax[r][1]),
                                     fmaxf(rowmax[r][2], rowmax[r][3]));
            const float cc = diagl[r] + stab;
            const int gr = row0 + r;
            const int bl = gr >> 3, h = gr & 7;
            const int b = bl >> 11, l = bl & 2047;
            const size_t base = (((size_t)b*HH + h)*LL + l)*MM;
#pragma unroll
            for (int nt = 0; nt < 4; ++nt)
                qp_b[base + wc*64 + nt*16 + l15] =
                    __float2bfloat16(K_RATIO * (__expf(acc[mt][nt][j] - cc) + K_EPS));
        }
}

// ---------------------------------------------------------------------------
// K feature GEMM, transposed f16 output with diag folded (verified round 6).
// ---------------------------------------------------------------------------
__global__ __launch_bounds__(512)
void feat_gemm_kT_kernel(const __hip_bfloat16* __restrict__ X, const float* __restrict__ P,
                         unsigned short* __restrict__ ddT, float* __restrict__ part)
{
    constexpr int LDT = 72;
    __shared__ __hip_bfloat16 As[128*LDT];
    __shared__ __hip_bfloat16 Bs[256*LDT];
    __shared__ float diagl[128];
    __shared__ float wmx[8];
    const int tid = threadIdx.x;
    const int lane = tid & 63, w = tid >> 6;
    const int wr = w >> 2, wc = w & 3;
    const int l15 = lane & 15, l4 = lane >> 4;
    const int bh = blockIdx.y;
    const int l0 = blockIdx.x * 128;

#pragma unroll
    for (int i = 0; i < 2; ++i) {
        int lin = i*512 + tid;
        int r = lin >> 3, kc = (lin & 7)*8;
        *(uint4*)&As[r*LDT + kc] = *(const uint4*)(X + ((size_t)bh*LL + l0 + r)*64 + kc);
    }
#pragma unroll
    for (int i = 0; i < 8; ++i) {
        int lin = i*512 + tid;
        int r = lin >> 4, kc = (lin & 15)*4;
        float4 v = *(const float4*)(P + (size_t)r*64 + kc);
        *(ushort4*)&Bs[r*LDT + kc] = f2b4(v);
    }
    __syncthreads();

    f32x4 acc[4][4];
#pragma unroll
    for (int mt = 0; mt < 4; ++mt)
#pragma unroll
        for (int nt = 0; nt < 4; ++nt) {
            f32x4 z = {0.f,0.f,0.f,0.f};
            acc[mt][nt] = z;
        }
#pragma unroll
    for (int ks = 0; ks < 2; ++ks) {
        const int ko = ks*32 + l4*8;
        short8 aF[4], bF[4];
#pragma unroll
        for (int mt = 0; mt < 4; ++mt)
            aF[mt] = *(const short8*)&As[(wr*64 + mt*16 + l15)*LDT + ko];
#pragma unroll
        for (int nt = 0; nt < 4; ++nt)
            bF[nt] = *(const short8*)&Bs[(wc*64 + nt*16 + l15)*LDT + ko];
#pragma unroll
        for (int mt = 0; mt < 4; ++mt)
#pragma unroll
            for (int nt = 0; nt < 4; ++nt)
                acc[mt][nt] = __builtin_amdgcn_mfma_f32_16x16x32_bf16(aF[mt], bF[nt], acc[mt][nt], 0, 0, 0);
    }

    {
        const int r = tid >> 2, q = tid & 3;
        float s = 0.f;
#pragma unroll
        for (int i = 0; i < 16; ++i) {
            float x = __bfloat162float(As[r*LDT + q*16 + i]);
            s += x*x;
        }
        s += __shfl_xor(s, 1);
        s += __shfl_xor(s, 2);
        if (q == 0) diagl[r] = 0.5f * s;
    }
    {
        float mx = -3.0e38f;
#pragma unroll
        for (int mt = 0; mt < 4; ++mt)
#pragma unroll
            for (int nt = 0; nt < 4; ++nt)
#pragma unroll
                for (int j = 0; j < 4; ++j)
                    mx = fmaxf(mx, acc[mt][nt][j]);
#pragma unroll
        for (int off = 32; off > 0; off >>= 1) mx = fmaxf(mx, __shfl_xor(mx, off));
        if (lane == 0) wmx[w] = mx;
    }
    __syncthreads();
    if (tid == 0) {
        float mx = wmx[0];
#pragma unroll
        for (int i = 1; i < 8; ++i) mx = fmaxf(mx, wmx[i]);
        part[blockIdx.y*16 + blockIdx.x] = mx;
    }

#pragma unroll
    for (int mt = 0; mt < 4; ++mt) {
#pragma unroll
        for (int nt = 0; nt < 4; ++nt) {
            const int m = wc*64 + nt*16 + l15;
            const int rbase = wr*64 + mt*16 + l4*4;
            ushort4 o;
            o.x = f2h_u16(acc[mt][nt][0] - diagl[rbase+0]);
            o.y = f2h_u16(acc[mt][nt][1] - diagl[rbase+1]);
            o.z = f2h_u16(acc[mt][nt][2] - diagl[rbase+2]);
            o.w = f2h_u16(acc[mt][nt][3] - diagl[rbase+3]);
            *(ushort4*)(ddT + ((size_t)bh*MM + m)*LL + l0 + rbase) = o;
        }
    }
}

__global__ __launch_bounds__(256)
void kmax_final_kernel(const float* __restrict__ part, float* __restrict__ gmax)
{
    float mx = -3.0e38f;
    for (int i = threadIdx.x; i < 512; i += 256) mx = fmaxf(mx, part[i]);
#pragma unroll
    for (int off = 32; off > 0; off >>= 1) mx = fmaxf(mx, __shfl_xor(mx, off));
    __shared__ float wsm[4];
    if ((threadIdx.x & 63) == 0) wsm[threadIdx.x >> 6] = mx;
    __syncthreads();
    if (threadIdx.x == 0) gmax[0] = fmaxf(fmaxf(wsm[0], wsm[1]), fmaxf(wsm[2], wsm[3]));
}

// ---------------------------------------------------------------------------
// vw [B,H,L,D] bf16  ->  vT [B,H,D,L] bf16  (tiled LDS transpose)
// ---------------------------------------------------------------------------
__global__ __launch_bounds__(256)
void transpose_v_kernel(const __hip_bfloat16* __restrict__ vw, __hip_bfloat16* __restrict__ vT)
{
    __shared__ unsigned short vl[64][72];
    const int bh = blockIdx.y;
    const int l0 = blockIdx.x*64;
    const __hip_bfloat16* src = vw + ((size_t)bh*LL + l0)*DD;
#pragma unroll
    for (int it = 0; it < 2; ++it) {
        int lin = it*256 + threadIdx.x;
        int t = lin >> 3, c8 = (lin & 7)*8;
        *(uint4*)&vl[t][c8] = *(const uint4*)(src + (size_t)t*DD + c8);
    }
    __syncthreads();
    const int d = threadIdx.x >> 2, q = threadIdx.x & 3;
    __hip_bfloat16* dst = vT + ((size_t)bh*DD + d)*LL + l0 + q*16;
#pragma unroll
    for (int g = 0; g < 4; ++g) {
        ushort4 o;
        o.x = vl[q*16+g*4+0][d];
        o.y = vl[q*16+g*4+1][d];
        o.z = vl[q*16+g*4+2][d];
        o.w = vl[q*16+g*4+3][d];
        *(ushort4*)(dst + g*4) = o;
    }
}

// ---------------------------------------------------------------------------
// Per-chunk state (fully parallel, MFMA; verified round 7).
// ---------------------------------------------------------------------------
__global__ __launch_bounds__(256)
void chunk_state_mfma_kernel(const unsigned short* __restrict__ ddT,
                             const __hip_bfloat16* __restrict__ vT_b,
                             const float* __restrict__ gmax,
                             __hip_bfloat16* __restrict__ Sci_b,
                             float* __restrict__ skc,
                             __hip_bfloat16* __restrict__ kp_b)
{
    __shared__ __hip_bfloat16 kT[256*72];
    __shared__ __hip_bfloat16 vT[64*72];
    const int c = blockIdx.x, bh = blockIdx.y;
    const int tid = threadIdx.x, lane = tid & 63, w = tid >> 6;
    const int l15 = lane & 15, l4 = lane >> 4;
    const float gm = gmax[0];
    char* kbuf = (char*)&kT[0];
    char* vbuf = (char*)&vT[0];

    {
        const unsigned short* ksrc = ddT + ((size_t)bh*MM + tid)*LL + (size_t)c*64;
#pragma unroll
        for (int o = 0; o < 8; ++o) {
            uint4 r0 = *(const uint4*)(ksrc + o*8);
            const unsigned short* u0 = (const unsigned short*)&r0;
            unsigned short p0[8];
#pragma unroll
            for (int i = 0; i < 8; ++i)
                p0[i] = f2b_u16(K_RATIO * (__expf(h2f(u0[i]) - gm) + K_EPS));
            *(uint4*)(kbuf + KSWZ(tid, o*8)) = *(uint4*)&p0[0];
        }
        const int sr = tid >> 2, sq = tid & 3;
        const __hip_bfloat16* vsrc = vT_b + ((size_t)bh*DD + sr)*LL + (size_t)c*64 + sq*16;
        *(uint4*)(vbuf + sr*144 + sq*32)      = *(const uint4*)(vsrc);
        *(uint4*)(vbuf + sr*144 + sq*32 + 16) = *(const uint4*)(vsrc + 8);
    }
    __syncthreads();

    f32x4 accS[4][4];   // [dt][mt]
    f32x4 accK[4];
#pragma unroll
    for (int i = 0; i < 4; ++i) {
#pragma unroll
        for (int j = 0; j < 4; ++j) { f32x4 z = {0.f,0.f,0.f,0.f}; accS[i][j] = z; }
        f32x4 z = {0.f,0.f,0.f,0.f}; accK[i] = z;
    }
    short8 ones8;
    {
        const short ov = (short)0x3F80;   // bf16 1.0
#pragma unroll
        for (int i = 0; i < 8; ++i) ones8[i] = (l15 == 0) ? ov : (short)0;
    }

#pragma unroll
    for (int ks = 0; ks < 2; ++ks) {
        const int ko = ks*32 + l4*8;
        short8 bF[4], aF[4];
#pragma unroll
        for (int mt = 0; mt < 4; ++mt)
            bF[mt] = *(const short8*)(kbuf + KSWZ(w*64 + mt*16 + l15, ko));
#pragma unroll
        for (int dt = 0; dt < 4; ++dt)
            aF[dt] = *(const short8*)(vbuf + (dt*16 + l15)*144 + ko*2);
#pragma unroll
        for (int dt = 0; dt < 4; ++dt)
#pragma unroll
            for (int mt = 0; mt < 4; ++mt)
                accS[dt][mt] = __builtin_amdgcn_mfma_f32_16x16x32_bf16(aF[dt], bF[mt], accS[dt][mt], 0, 0, 0);
#pragma unroll
        for (int mt = 0; mt < 4; ++mt)
            accK[mt] = __builtin_amdgcn_mfma_f32_16x16x32_bf16(ones8, bF[mt], accK[mt], 0, 0, 0);
    }

    __hip_bfloat16* So = Sci_b + ((size_t)(bh*NCHUNK + c))*(MM*DD);
#pragma unroll
    for (int dt = 0; dt < 4; ++dt)
#pragma unroll
        for (int mt = 0; mt < 4; ++mt) {
            const int m = w*64 + mt*16 + l15;
#pragma unroll
            for (int j = 0; j < 4; ++j)
                So[(size_t)(dt*16 + l4*4 + j)*MM + m] = __float2bfloat16(accS[dt][mt][j]);
        }
    if (l4 == 0) {
#pragma unroll
        for (int mt = 0; mt < 4; ++mt)
            skc[((size_t)bh*NCHUNK + c)*MM + w*64 + mt*16 + l15] = accK[mt][0];
    }

    {
        const int t2 = w*16 + (lane >> 2);
        const int m0 = (lane & 3)*16;
        __hip_bfloat16* krow = kp_b + ((size_t)bh*LL + (size_t)c*64 + t2)*MM;
#pragma unroll
        for (int seg = 0; seg < 4; ++seg) {
            unsigned short vals[16];
#pragma unroll
            for (int i = 0; i < 16; ++i)
                vals[i] = *(const unsigned short*)(kbuf + KSWZ(seg*64 + m0 + i, t2));
            *(uint4*)(krow + seg*64 + m0)     = *(uint4*)&vals[0];
            *(uint4*)(krow + seg*64 + m0 + 8) = *(uint4*)&vals[8];
        }
    }
}

// ---------------------------------------------------------------------------
// Exclusive prefix over chunks, IN PLACE (verified round 7).
// ---------------------------------------------------------------------------
__global__ __launch_bounds__(256)
void chunk_prefix_kernel(__hip_bfloat16* __restrict__ S_b, float* __restrict__ skc)
{
    const int bh = blockIdx.y;
    const int e4 = blockIdx.x*256 + threadIdx.x;
    __hip_bfloat16* base = S_b + (size_t)bh*NCHUNK*(MM*DD) + (size_t)e4*4;
    float4 run = {0.f, 0.f, 0.f, 0.f};
#pragma unroll 4
    for (int c = 0; c < NCHUNK; ++c) {
        __hip_bfloat16* p = base + (size_t)c*(MM*DD);
        ushort4 t = *(ushort4*)p;
        ushort4 o;
        o.x = f2b_u16(run.x); o.y = f2b_u16(run.y);
        o.z = f2b_u16(run.z); o.w = f2b_u16(run.w);
        *(ushort4*)p = o;
        run.x += b2f_u16(t.x); run.y += b2f_u16(t.y);
        run.z += b2f_u16(t.z); run.w += b2f_u16(t.w);
    }
    if (blockIdx.x == 0) {
        float* kb = skc + (size_t)bh*NCHUNK*MM + threadIdx.x;
        float s2 = 0.f;
#pragma unroll 4
        for (int c = 0; c < NCHUNK; ++c) {
            float t = kb[(size_t)c*MM];
            kb[(size_t)c*MM] = s2;
            s2 += t;
        }
    }
}

// ---------------------------------------------------------------------------
// MFMA chunk_out (verified round 4, unchanged).
// ---------------------------------------------------------------------------
__global__ __launch_bounds__(256)
void chunk_out_kernel(const __hip_bfloat16* __restrict__ qp_b,
                      const __hip_bfloat16* __restrict__ kp_b,
                      const __hip_bfloat16* __restrict__ vT_b,
                      const __hip_bfloat16* __restrict__ ScT_b,
                      const float* __restrict__ skp,
                      __hip_bfloat16* __restrict__ attn)
{
    constexpr int LDQ = 72;
    constexpr int LDA = 72;
    __shared__ __hip_bfloat16 Qs[64*LDQ];
    __shared__ __hip_bfloat16 Ks[64*LDQ];
    __shared__ __hip_bfloat16 Ss[80*LDQ];
    __shared__ __hip_bfloat16 Al[64*LDA];
    __shared__ __hip_bfloat16 Vl[80*LDA];

    const int c = blockIdx.x, h = blockIdx.y, b = blockIdx.z;
    const size_t bh = (size_t)b*HH + h;
    const __hip_bfloat16* qpc = qp_b + (bh*LL + (size_t)c*TT) * MM;
    const __hip_bfloat16* kpc = kp_b + (bh*LL + (size_t)c*TT) * MM;
    const __hip_bfloat16* vTc = vT_b + bh*(size_t)(DD*LL) + (size_t)c*TT;
    const __hip_bfloat16* Scc = ScT_b + (bh*NCHUNK + (size_t)c) * (MM*DD);
    const float* skrow = skp + (bh*NCHUNK + (size_t)c) * MM;

    const int tid = threadIdx.x;
    const int lane = tid & 63;
    const int w = tid >> 6;
    const int l15 = lane & 15, l4 = lane >> 4;

    {
#pragma unroll
        for (int it = 0; it < 2; ++it) {
            int lin = it*256 + tid;
            int d = lin >> 3, c8 = (lin & 7)*8;
            *(uint4*)&Vl[d*LDA + c8] = *(const uint4*)(vTc + (size_t)d*LL + c8);
        }
        const __hip_bfloat16 one = __float2bfloat16(1.0f);
        const __hip_bfloat16 zero = __float2bfloat16(0.0f);
        for (int idx = tid; idx < 16*64; idx += 256) {
            int rr = idx >> 6, cc2 = idx & 63;
            Vl[(64+rr)*LDA + cc2] = (rr == 0) ? one : zero;
        }
        for (int idx = tid; idx < 15*64; idx += 256) {
            int rr = idx / 64, cc2 = idx % 64;
            Ss[(65+rr)*LDQ + cc2] = zero;
        }
    }

    f32x4 accA[4];
    f32x4 accO[5];
#pragma unroll
    for (int i = 0; i < 4; ++i) { f32x4 z = {0.f,0.f,0.f,0.f}; accA[i] = z; }
#pragma unroll
    for (int i = 0; i < 5; ++i) { f32x4 z = {0.f,0.f,0.f,0.f}; accO[i] = z; }

    for (int mq = 0; mq < MM; mq += 64) {
        __syncthreads();
#pragma unroll
        for (int it = 0; it < 2; ++it) {
            int lin = it*256 + tid;
            int r = lin >> 3, m8 = (lin & 7)*8;
            *(uint4*)&Qs[r*LDQ + m8] = *(const uint4*)(qpc + (size_t)r*MM + mq + m8);
            *(uint4*)&Ks[r*LDQ + m8] = *(const uint4*)(kpc + (size_t)r*MM + mq + m8);
            *(uint4*)&Ss[r*LDQ + m8] = *(const uint4*)(Scc + (size_t)r*MM + mq + m8);
        }
        if (tid < 64) Ss[64*LDQ + tid] = __float2bfloat16(skrow[mq + tid]);
        __syncthreads();
#pragma unroll
        for (int ks = 0; ks < 2; ++ks) {
            const int ko = ks*32 + l4*8;
            short8 aF = *(const short8*)&Qs[(w*16 + l15)*LDQ + ko];
#pragma unroll
            for (int nt = 0; nt < 4; ++nt) {
                short8 bF = *(const short8*)&Ks[(nt*16 + l15)*LDQ + ko];
                accA[nt] = __builtin_amdgcn_mfma_f32_16x16x32_bf16(aF, bF, accA[nt], 0, 0, 0);
            }
#pragma unroll
            for (int nt = 0; nt < 5; ++nt) {
                short8 sF = *(const short8*)&Ss[(nt*16 + l15)*LDQ + ko];
                accO[nt] = __builtin_amdgcn_mfma_f32_16x16x32_bf16(aF, sF, accO[nt], 0, 0, 0);
            }
        }
    }
    __syncthreads();
#pragma unroll
    for (int nt = 0; nt < 4; ++nt) {
        const int s = nt*16 + l15;
#pragma unroll
        for (int j = 0; j < 4; ++j) {
            const int t = w*16 + l4*4 + j;
            const float v = (s <= t) ? accA[nt][j] : 0.f;
            Al[t*LDA + s] = __float2bfloat16(v);
        }
    }
    __syncthreads();
#pragma unroll
    for (int ks = 0; ks < 2; ++ks) {
        const int ko = ks*32 + l4*8;
        short8 aF = *(const short8*)&Al[(w*16 + l15)*LDA + ko];
#pragma unroll
        for (int nt = 0; nt < 5; ++nt) {
            short8 vF = *(const short8*)&Vl[(nt*16 + l15)*LDA + ko];
            accO[nt] = __builtin_amdgcn_mfma_f32_16x16x32_bf16(aF, vF, accO[nt], 0, 0, 0);
        }
    }
    __hip_bfloat16* arow = attn + ((size_t)b*LL + (size_t)c*TT) * DIMM + h*DD;
#pragma unroll
    for (int j = 0; j < 4; ++j) {
        const float den = __shfl(accO[4][j], (lane & 48));
        const float inv = 1.0f / den;
        const int t = w*16 + l4*4 + j;
#pragma unroll
        for (int nt = 0; nt < 4; ++nt) {
            const int d = nt*16 + l15;
            arow[(size_t)t*DIMM + d] = __float2bfloat16(accO[nt][j] * inv);
        }
    }
}

// ---------------------------------------------------------------------------
extern "C" void kernel_launch(void* const* d_in, const int* in_sizes, int n_in,
                              void* d_out, int out_size, void* d_ws, size_t ws_size,
                              hipStream_t stream)
{
    (void)in_sizes; (void)n_in; (void)out_size; (void)ws_size;
    const float* query = (const float*)d_in[0];
    const float* key   = (const float*)d_in[1];
    const float* value = (const float*)d_in[2];
    const float* Wq = (const float*)d_in[3];
    const float* bq = (const float*)d_in[4];
    const float* Wk = (const float*)d_in[5];
    const float* bk = (const float*)d_in[6];
    const float* Wv = (const float*)d_in[7];
    const float* bv = (const float*)d_in[8];
    const float* Wo = (const float*)d_in[9];
    const float* bo = (const float*)d_in[10];
    const float* proj = (const float*)d_in[11];

    float* ws = (float*)d_ws;
    unsigned short* ddT   = (unsigned short*)ws;                 // 16.7M f16  [bh][m][l]
    __hip_bfloat16* qp_b  = (__hip_bfloat16*)(ws +  8388608);
    __hip_bfloat16* kp_b  = (__hip_bfloat16*)(ws + 16777216);
    __hip_bfloat16* ScT_b = (__hip_bfloat16*)(ws + 25165824);
    __hip_bfloat16* vw_b  = (__hip_bfloat16*)(ws + 33554432);
    __hip_bfloat16* vT_b  = (__hip_bfloat16*)(ws + 35651584);
    __hip_bfloat16* qsb   = (__hip_bfloat16*)(ws + 37748736);
    __hip_bfloat16* ksw_b = (__hip_bfloat16*)(ws + 39845888);
    __hip_bfloat16* qbi   = (__hip_bfloat16*)(ws + 41943040);
    __hip_bfloat16* kbi   = (__hip_bfloat16*)(ws + 44040192);
    __hip_bfloat16* vbi   = (__hip_bfloat16*)(ws + 46137344);
    __hip_bfloat16* Wqb   = (__hip_bfloat16*)(ws + 48234496);
    __hip_bfloat16* Wkb   = (__hip_bfloat16*)(ws + 48365568);
    __hip_bfloat16* Wvb   = (__hip_bfloat16*)(ws + 48496640);
    __hip_bfloat16* Wob   = (__hip_bfloat16*)(ws + 48627712);
    float* skc            = ws + 48758784;
    float* part           = ws + 49020928;
    float* gmax           = ws + 49021440;
    __hip_bfloat16* attn_b = qsb;   // qsb dead after feat_gemm_q

    const dim3 blk(256);

    cast_qkv_kernel<<<2048, blk, 0, stream>>>(query, key, value, qbi, kbi, vbi);
    cast_w_kernel<<<256, blk, 0, stream>>>(Wq, Wk, Wv, Wo, Wqb, Wkb, Wvb, Wob);

    qkv_proj_kernel<<<dim3(4,64,3), blk, 0, stream>>>(qbi, kbi, vbi,
                                                      Wqb, bq, Wkb, bk, Wvb, bv,
                                                      qsb, ksw_b, vw_b);

    transpose_v_kernel<<<dim3(32,32), blk, 0, stream>>>(vw_b, vT_b);

    feat_gemm_q_kernel<<<512, dim3(512), 0, stream>>>(qsb, proj, qp_b);

    feat_gemm_kT_kernel<<<dim3(16,32), dim3(512), 0, stream>>>(ksw_b, proj, ddT, part);
    kmax_final_kernel<<<1, blk, 0, stream>>>(part, gmax);

    chunk_state_mfma_kernel<<<dim3(NCHUNK,32), blk, 0, stream>>>(ddT, vT_b, gmax, ScT_b, skc, kp_b);
    chunk_prefix_kernel<<<dim3(16,32), blk, 0, stream>>>(ScT_b, skc);

    chunk_out_kernel<<<dim3(NCHUNK,HH,BB), blk, 0, stream>>>(qp_b, kp_b, vT_b, ScT_b, skc, attn_b);

    gemm_wo_kernel<<<dim3(4,64), blk, 0, stream>>>(attn_b, Wob, bo, (float*)d_out);
}